// Round 5
// baseline (2527.438 us; speedup 1.0000x reference)
//
#include <hip/hip_runtime.h>
#include <hip/hip_bf16.h>

// ---------------------------------------------------------------------------
// SimpleGeoFormerModel: 4-layer transformer encoder. FP32 compute, FP32 out.
// B=8 N=256 E=512 V=512 L=4 H=8 FF=2048, dh=64.
// Round 5: output dtype fixed to float32 (x ++ pad_mask). Tiled fp32 GEMMs.
// ---------------------------------------------------------------------------

namespace {
constexpr int Bn  = 8;
constexpr int Nn  = 256;
constexpr int En  = 512;
constexpr int Ln  = 4;
constexpr int Hn  = 8;
constexpr int FFn = 2048;
constexpr int DHn = 64;
constexpr int Mn  = Bn * Nn;        // 2048 rows
constexpr int QKV_LD = 3 * En;      // 1536
}

// ---------------- embedding gather ----------------
__global__ __launch_bounds__(256) void k_embed(const int* __restrict__ tok,
                                               const float* __restrict__ emb,
                                               float* __restrict__ x) {
    int i = blockIdx.x * 256 + threadIdx.x;   // over Mn*En
    int m = i >> 9;                           // /512
    int e = i & 511;
    x[i] = emb[tok[m] * En + e];
}

// ---------------- distance bias: f(d) = sum_e w2[e]*tanh(d*w1[e]+b1[e]) + b2
__global__ __launch_bounds__(256) void k_distbias(const float* __restrict__ dist,
                                                  const int* __restrict__ tok,
                                                  const float* __restrict__ w1,
                                                  const float* __restrict__ b1,
                                                  const float* __restrict__ w2,
                                                  const float* __restrict__ b2,
                                                  float* __restrict__ biasmat) {
    __shared__ float sw1[En], sb1[En], sw2[En];
    for (int e = threadIdx.x; e < En; e += 256) {
        sw1[e] = w1[e]; sb1[e] = b1[e]; sw2[e] = w2[e];
    }
    __syncthreads();
    int i = blockIdx.x * 256 + threadIdx.x;   // b*N*N + q*N + k
    float d = dist[i];
    int k = i & (Nn - 1);
    int q = (i >> 8) & (Nn - 1);
    int b = i >> 16;
    float acc = 0.f;
#pragma unroll 4
    for (int e = 0; e < En; ++e) {
        float s = fmaf(d, sw1[e], sb1[e]);
        float t = 1.f - 2.f / (__expf(2.f * s) + 1.f);   // tanh(s)
        acc = fmaf(t, sw2[e], acc);
    }
    acc += b2[0];
    bool pad = (tok[b * Nn + k] == 0) || (tok[b * Nn + q] == 0);
    biasmat[i] = pad ? -1e30f : acc;
}

// ---------------- tiled GEMM: C[m,n] = sum_k A[m,k]*Bw[n,k] + bias[n]  (B^T)
// ACT: 0 = none, 1 = exact GELU
template <int BM, int BN, int ACT>
__global__ __launch_bounds__(256) void k_gemm_bt(const float* __restrict__ A, int lda,
                                                 const float* __restrict__ Bw, int ldb,
                                                 const float* __restrict__ biasv,
                                                 float* __restrict__ C, int ldc,
                                                 int K) {
    constexpr int BK = 16;
    constexpr int TM = BM / 16;
    constexpr int TN = BN / 16;
    __shared__ float As[BK][BM + 4];
    __shared__ float Bs[BK][BN + 4];
    const int tid = threadIdx.x;
    const int tx = tid & 15, ty = tid >> 4;
    const int m0 = blockIdx.x * BM;
    const int n0 = blockIdx.y * BN;

    float acc[TM][TN];
#pragma unroll
    for (int i = 0; i < TM; ++i)
#pragma unroll
        for (int j = 0; j < TN; ++j) acc[i][j] = 0.f;

    for (int k0 = 0; k0 < K; k0 += BK) {
#pragma unroll
        for (int i = tid; i < BM * BK; i += 256) {
            int r = i >> 4, c = i & 15;
            As[c][r] = A[(size_t)(m0 + r) * lda + k0 + c];
        }
#pragma unroll
        for (int i = tid; i < BN * BK; i += 256) {
            int r = i >> 4, c = i & 15;
            Bs[c][r] = Bw[(size_t)(n0 + r) * ldb + k0 + c];
        }
        __syncthreads();
#pragma unroll
        for (int kk = 0; kk < BK; ++kk) {
            float a[TM], bb[TN];
            const float4* ap = reinterpret_cast<const float4*>(&As[kk][ty * TM]);
            const float4* bp = reinterpret_cast<const float4*>(&Bs[kk][tx * TN]);
#pragma unroll
            for (int i4 = 0; i4 < TM / 4; ++i4) {
                float4 t = ap[i4];
                a[i4*4+0]=t.x; a[i4*4+1]=t.y; a[i4*4+2]=t.z; a[i4*4+3]=t.w;
            }
#pragma unroll
            for (int j4 = 0; j4 < TN / 4; ++j4) {
                float4 t = bp[j4];
                bb[j4*4+0]=t.x; bb[j4*4+1]=t.y; bb[j4*4+2]=t.z; bb[j4*4+3]=t.w;
            }
#pragma unroll
            for (int i = 0; i < TM; ++i)
#pragma unroll
                for (int j = 0; j < TN; ++j)
                    acc[i][j] = fmaf(a[i], bb[j], acc[i][j]);
        }
        __syncthreads();
    }

#pragma unroll
    for (int i = 0; i < TM; ++i) {
        int m = m0 + ty * TM + i;
#pragma unroll
        for (int j = 0; j < TN; ++j) {
            int n = n0 + tx * TN + j;
            float v = acc[i][j] + biasv[n];
            if constexpr (ACT == 1)
                v = 0.5f * v * (1.f + erff(v * 0.70710678118654752f));
            C[(size_t)m * ldc + n] = v;
        }
    }
}

// ---------------- attention scores: S[bh,q,k] = 0.125*Q.K + bias[b,q,k]
__global__ __launch_bounds__(256) void k_scores(const float* __restrict__ qkv,
                                                const float* __restrict__ biasmat,
                                                float* __restrict__ S) {
    __shared__ float Qs[DHn][64 + 1];   // [d][q]
    __shared__ float Ks[DHn][64 + 1];
    const int bh = blockIdx.z;
    const int b = bh >> 3, h = bh & 7;
    const int q0 = blockIdx.x * 64, k0 = blockIdx.y * 64;
    const int tid = threadIdx.x;
    const int tx = tid & 15, ty = tid >> 4;
    const float* Qbase = qkv + (size_t)(b * Nn) * QKV_LD + h * DHn;
    const float* Kbase = Qbase + En;

    for (int i = tid; i < 64 * 64; i += 256) {
        int r = i >> 6, d = i & 63;
        Qs[d][r] = Qbase[(size_t)(q0 + r) * QKV_LD + d];
        Ks[d][r] = Kbase[(size_t)(k0 + r) * QKV_LD + d];
    }
    __syncthreads();

    float acc[4][4] = {};
#pragma unroll 4
    for (int d = 0; d < DHn; ++d) {
        float a[4], bb[4];
#pragma unroll
        for (int i = 0; i < 4; ++i) a[i] = Qs[d][ty * 4 + i];
#pragma unroll
        for (int j = 0; j < 4; ++j) bb[j] = Ks[d][tx * 4 + j];
#pragma unroll
        for (int i = 0; i < 4; ++i)
#pragma unroll
            for (int j = 0; j < 4; ++j)
                acc[i][j] = fmaf(a[i], bb[j], acc[i][j]);
    }
    const float scale = 0.125f;  // 1/sqrt(64)
#pragma unroll
    for (int i = 0; i < 4; ++i) {
        int q = q0 + ty * 4 + i;
#pragma unroll
        for (int j = 0; j < 4; ++j) {
            int k = k0 + tx * 4 + j;
            float bmat = biasmat[((size_t)b * Nn + q) * Nn + k];
            S[((size_t)bh * Nn + q) * Nn + k] = fmaf(acc[i][j], scale, bmat);
        }
    }
}

// ---------------- row softmax over k (row length 256), one wave per row
__global__ __launch_bounds__(64) void k_softmax(float* __restrict__ S) {
    const size_t row = blockIdx.x;
    float4* p = reinterpret_cast<float4*>(S + row * Nn) + threadIdx.x;
    float4 v = *p;
    float mx = fmaxf(fmaxf(v.x, v.y), fmaxf(v.z, v.w));
#pragma unroll
    for (int o = 32; o; o >>= 1) mx = fmaxf(mx, __shfl_xor(mx, o));
    float e0 = __expf(v.x - mx), e1 = __expf(v.y - mx);
    float e2 = __expf(v.z - mx), e3 = __expf(v.w - mx);
    float sum = (e0 + e1) + (e2 + e3);
#pragma unroll
    for (int o = 32; o; o >>= 1) sum += __shfl_xor(sum, o);
    float r = 1.f / sum;
    *p = make_float4(e0 * r, e1 * r, e2 * r, e3 * r);
}

// ---------------- PV: attn[b,q,h*64+d] = sum_k P[bh,q,k]*V[b,k,2E+h*64+d]
__global__ __launch_bounds__(256) void k_pv(const float* __restrict__ P,
                                            const float* __restrict__ qkv,
                                            float* __restrict__ attn) {
    const int bh = blockIdx.z;
    const int b = bh >> 3, h = bh & 7;
    const int d = threadIdx.x & 63;
    const int q = blockIdx.x * 4 + (threadIdx.x >> 6);
    const float* Vbase = qkv + (size_t)(b * Nn) * QKV_LD + 2 * En + h * DHn;
    const float* Prow = P + ((size_t)bh * Nn + q) * Nn;
    float acc = 0.f;
#pragma unroll 8
    for (int k = 0; k < Nn; ++k)
        acc = fmaf(Prow[k], Vbase[(size_t)k * QKV_LD + d], acc);
    attn[((size_t)(b * Nn + q)) * En + h * DHn + d] = acc;
}

// ---------------- residual add + LayerNorm (row = 512, block = 256)
__global__ __launch_bounds__(256) void k_addln(const float* __restrict__ xin,
                                               const float* __restrict__ y,
                                               const float* __restrict__ g,
                                               const float* __restrict__ bb,
                                               float* __restrict__ xout) {
    const int row = blockIdx.x;
    const int tid = threadIdx.x;
    const size_t base = (size_t)row * En;
    float v0 = xin[base + tid] + y[base + tid];
    float v1 = xin[base + tid + 256] + y[base + tid + 256];
    float s1 = v0 + v1;
    float s2 = v0 * v0 + v1 * v1;
#pragma unroll
    for (int o = 32; o; o >>= 1) {
        s1 += __shfl_xor(s1, o);
        s2 += __shfl_xor(s2, o);
    }
    __shared__ float ws1[4], ws2[4];
    int w = tid >> 6;
    if ((tid & 63) == 0) { ws1[w] = s1; ws2[w] = s2; }
    __syncthreads();
    s1 = (ws1[0] + ws1[1]) + (ws1[2] + ws1[3]);
    s2 = (ws2[0] + ws2[1]) + (ws2[2] + ws2[3]);
    const float rE = 1.f / (float)En;
    float mean = s1 * rE;
    float var = s2 * rE - mean * mean;
    float inv = rsqrtf(var + 1e-5f);
    xout[base + tid]       = (v0 - mean) * inv * g[tid] + bb[tid];
    xout[base + tid + 256] = (v1 - mean) * inv * g[tid + 256] + bb[tid + 256];
}

// ---------------- final: fp32 x ++ fp32 pad_mask (reference output is fp32)
__global__ __launch_bounds__(256) void k_out(const float* __restrict__ x,
                                             const int* __restrict__ tok,
                                             float* __restrict__ out) {
    int i = blockIdx.x * 256 + threadIdx.x;
    const int total = Mn * En + Mn;
    if (i >= total) return;
    if (i < Mn * En) {
        out[i] = x[i];
    } else {
        int m = i - Mn * En;
        out[i] = (tok[m] == 0) ? 1.f : 0.f;
    }
}

// ---------------------------------------------------------------------------
extern "C" void kernel_launch(void* const* d_in, const int* in_sizes, int n_in,
                              void* d_out, int out_size, void* d_ws, size_t ws_size,
                              hipStream_t stream) {
    const int*   tok   = (const int*)  d_in[0];
    const float* dist  = (const float*)d_in[2];
    const float* emb   = (const float*)d_in[4];
    const float* dp_w1 = (const float*)d_in[5];
    const float* dp_b1 = (const float*)d_in[6];
    const float* dp_w2 = (const float*)d_in[7];
    const float* dp_b2 = (const float*)d_in[8];
    const float* Wqkv  = (const float*)d_in[9];
    const float* bqkv  = (const float*)d_in[10];
    const float* Wo    = (const float*)d_in[11];
    const float* bo    = (const float*)d_in[12];
    const float* ln1g  = (const float*)d_in[13];
    const float* ln1b  = (const float*)d_in[14];
    const float* W1    = (const float*)d_in[15];
    const float* b1    = (const float*)d_in[16];
    const float* W2    = (const float*)d_in[17];
    const float* b2    = (const float*)d_in[18];
    const float* ln2g  = (const float*)d_in[19];
    const float* ln2b  = (const float*)d_in[20];

    float* ws = (float*)d_ws;
    float* biasmat = ws;                         // 524288
    float* x       = biasmat + (size_t)Bn*Nn*Nn; // 1048576
    float* qkv     = x    + (size_t)Mn*En;       // 3145728
    float* Sff     = qkv  + (size_t)Mn*QKV_LD;   // 4194304 (scores / FF shared)
    float* attn    = Sff  + (size_t)Bn*Hn*Nn*Nn; // 1048576
    float* y       = attn + (size_t)Mn*En;       // 1048576

    k_embed<<<Mn * En / 256, 256, 0, stream>>>(tok, emb, x);
    k_distbias<<<Bn * Nn * Nn / 256, 256, 0, stream>>>(dist, tok, dp_w1, dp_b1,
                                                       dp_w2, dp_b2, biasmat);

    for (int l = 0; l < Ln; ++l) {
        const float* Wqkv_l = Wqkv + (size_t)l * 3 * En * En;
        const float* bqkv_l = bqkv + (size_t)l * 3 * En;
        const float* Wo_l   = Wo   + (size_t)l * En * En;
        const float* bo_l   = bo   + (size_t)l * En;
        const float* W1_l   = W1   + (size_t)l * FFn * En;
        const float* b1_l   = b1   + (size_t)l * FFn;
        const float* W2_l   = W2   + (size_t)l * En * FFn;
        const float* b2_l   = b2   + (size_t)l * En;

        // QKV projection: [2048,512] x [1536,512]^T -> [2048,1536]
        k_gemm_bt<128, 128, 0><<<dim3(Mn / 128, QKV_LD / 128), 256, 0, stream>>>(
            x, En, Wqkv_l, En, bqkv_l, qkv, QKV_LD, En);

        // attention
        k_scores<<<dim3(Nn / 64, Nn / 64, Bn * Hn), 256, 0, stream>>>(qkv, biasmat, Sff);
        k_softmax<<<Bn * Hn * Nn, 64, 0, stream>>>(Sff);
        k_pv<<<dim3(Nn / 4, 1, Bn * Hn), 256, 0, stream>>>(Sff, qkv, attn);

        // O projection: [2048,512] x [512,512]^T
        k_gemm_bt<64, 64, 0><<<dim3(Mn / 64, En / 64), 256, 0, stream>>>(
            attn, En, Wo_l, En, bo_l, y, En, En);
        k_addln<<<Mn, 256, 0, stream>>>(x, y, ln1g + (size_t)l * En, ln1b + (size_t)l * En, x);

        // FF1 + GELU: [2048,512] x [2048,512]^T -> [2048,2048]
        k_gemm_bt<128, 128, 1><<<dim3(Mn / 128, FFn / 128), 256, 0, stream>>>(
            x, En, W1_l, En, b1_l, Sff, FFn, En);

        // FF2: [2048,2048] x [512,2048]^T -> [2048,512]
        k_gemm_bt<64, 64, 0><<<dim3(Mn / 64, En / 64), 256, 0, stream>>>(
            Sff, FFn, W2_l, FFn, b2_l, y, En, FFn);
        k_addln<<<Mn, 256, 0, stream>>>(x, y, ln2g + (size_t)l * En, ln2b + (size_t)l * En, x);
    }

    k_out<<<(Mn * En + Mn + 255) / 256, 256, 0, stream>>>(x, tok, (float*)d_out);
}

// Round 6
// 889.446 us; speedup vs baseline: 2.8416x; 2.8416x over previous
//
#include <hip/hip_runtime.h>
#include <hip/hip_bf16.h>

// ---------------------------------------------------------------------------
// SimpleGeoFormerModel: 4-layer transformer encoder. FP32 in/out, bf16 MFMA
// GEMMs (fp32 accumulate). B=8 N=256 E=512 V=512 L=4 H=8 FF=2048, dh=64.
// Round 6: k_gemm_bt (fp32 SIMD) -> k_gemm_mfma (bf16 MFMA). Rest unchanged.
// ---------------------------------------------------------------------------

namespace {
constexpr int Bn  = 8;
constexpr int Nn  = 256;
constexpr int En  = 512;
constexpr int Ln  = 4;
constexpr int Hn  = 8;
constexpr int FFn = 2048;
constexpr int DHn = 64;
constexpr int Mn  = Bn * Nn;        // 2048 rows
constexpr int QKV_LD = 3 * En;      // 1536
}

typedef float f32x4 __attribute__((ext_vector_type(4)));
typedef short bf16x8 __attribute__((ext_vector_type(8)));

// fp32 -> bf16 round-to-nearest-even (inputs are finite; no NaN handling)
__device__ __forceinline__ unsigned short f2bs(float f) {
    union { float f; unsigned u; } v; v.f = f;
    unsigned r = v.u + 0x7FFFu + ((v.u >> 16) & 1u);
    return (unsigned short)(r >> 16);
}

__device__ __forceinline__ bf16x8 cvt8(f32x4 a, f32x4 b) {
    bf16x8 r;
    r[0] = (short)f2bs(a[0]); r[1] = (short)f2bs(a[1]);
    r[2] = (short)f2bs(a[2]); r[3] = (short)f2bs(a[3]);
    r[4] = (short)f2bs(b[0]); r[5] = (short)f2bs(b[1]);
    r[6] = (short)f2bs(b[2]); r[7] = (short)f2bs(b[3]);
    return r;
}

// ---------------- embedding gather ----------------
__global__ __launch_bounds__(256) void k_embed(const int* __restrict__ tok,
                                               const float* __restrict__ emb,
                                               float* __restrict__ x) {
    int i = blockIdx.x * 256 + threadIdx.x;   // over Mn*En
    int m = i >> 9;                           // /512
    int e = i & 511;
    x[i] = emb[tok[m] * En + e];
}

// ---------------- distance bias: f(d) = sum_e w2[e]*tanh(d*w1[e]+b1[e]) + b2
__global__ __launch_bounds__(256) void k_distbias(const float* __restrict__ dist,
                                                  const int* __restrict__ tok,
                                                  const float* __restrict__ w1,
                                                  const float* __restrict__ b1,
                                                  const float* __restrict__ w2,
                                                  const float* __restrict__ b2,
                                                  float* __restrict__ biasmat) {
    __shared__ float sw1[En], sb1[En], sw2[En];
    for (int e = threadIdx.x; e < En; e += 256) {
        sw1[e] = w1[e]; sb1[e] = b1[e]; sw2[e] = w2[e];
    }
    __syncthreads();
    int i = blockIdx.x * 256 + threadIdx.x;   // b*N*N + q*N + k
    float d = dist[i];
    int k = i & (Nn - 1);
    int q = (i >> 8) & (Nn - 1);
    int b = i >> 16;
    float acc = 0.f;
#pragma unroll 4
    for (int e = 0; e < En; ++e) {
        float s = fmaf(d, sw1[e], sb1[e]);
        float t = 1.f - 2.f / (__expf(2.f * s) + 1.f);   // tanh(s)
        acc = fmaf(t, sw2[e], acc);
    }
    acc += b2[0];
    bool pad = (tok[b * Nn + k] == 0) || (tok[b * Nn + q] == 0);
    biasmat[i] = pad ? -1e30f : acc;
}

// ---------------- MFMA GEMM: C[m,n] = sum_k A[m,k]*Bw[n,k] + bias[n]  (B^T)
// fp32 inputs, on-the-fly bf16 conversion, mfma_f32_16x16x32_bf16, fp32 out.
// 256 threads = 4 waves in 2x2 grid; each wave computes (BM/2)x(BN/2).
// ACT: 0 = none, 1 = exact GELU.
template <int BM, int BN, int ACT>
__global__ __launch_bounds__(256) void k_gemm_mfma(const float* __restrict__ A, int lda,
                                                   const float* __restrict__ Bw, int ldb,
                                                   const float* __restrict__ biasv,
                                                   float* __restrict__ C, int ldc,
                                                   int K) {
    static_assert(BM == BN, "square tiles only");
    constexpr int BK    = 32;
    constexpr int LDS_S = BK + 8;       // 40 shorts = 80B row stride (16B-aligned,
                                        // uniform 8-deep bank spread on b128 ops)
    constexpr int WM = BM / 2, WN = BN / 2;
    constexpr int FM = WM / 16, FN = WN / 16;
    constexpr int GR = 256 / BM;        // threads per staged row (2 or 4)
    constexpr int TC = BK / GR;         // cols per thread (16 or 8)
    constexpr int NV = TC / 4;          // f32x4 loads per operand (4 or 2)

    __shared__ short As[BM * LDS_S];
    __shared__ short Bs[BM * LDS_S];

    const int tid  = threadIdx.x;
    const int lane = tid & 63;
    const int wv   = tid >> 6;
    const int wr   = wv >> 1, wc = wv & 1;
    const int m0 = blockIdx.x * BM, n0 = blockIdx.y * BN;

    const int arow = tid / GR;
    const int acol = (tid % GR) * TC;

    const float* Abase = A  + (size_t)(m0 + arow) * lda + acol;
    const float* Bbase = Bw + (size_t)(n0 + arow) * ldb + acol;

    // prefetch tile 0
    f32x4 pa[NV], pb[NV];
#pragma unroll
    for (int i = 0; i < NV; ++i) pa[i] = *(const f32x4*)(Abase + i * 4);
#pragma unroll
    for (int i = 0; i < NV; ++i) pb[i] = *(const f32x4*)(Bbase + i * 4);

    f32x4 acc[FM][FN];
#pragma unroll
    for (int i = 0; i < FM; ++i)
#pragma unroll
        for (int j = 0; j < FN; ++j) acc[i][j] = {0.f, 0.f, 0.f, 0.f};

    const int fk   = (lane >> 4) * 8;   // frag k-offset
    const int frow = lane & 15;         // frag row within 16-block
    short* awp = &As[arow * LDS_S + acol];
    short* bwp = &Bs[arow * LDS_S + acol];

    const int nt = K / BK;
    for (int t = 0; t < nt; ++t) {
        // LDS write (cvt fp32 pair -> bf16x8, one/two ds_write_b128)
#pragma unroll
        for (int i = 0; i < NV / 2; ++i)
            *(bf16x8*)(awp + i * 8) = cvt8(pa[2 * i], pa[2 * i + 1]);
#pragma unroll
        for (int i = 0; i < NV / 2; ++i)
            *(bf16x8*)(bwp + i * 8) = cvt8(pb[2 * i], pb[2 * i + 1]);
        __syncthreads();

        // issue next tile's global loads (overlap with MFMA below)
        if (t + 1 < nt) {
            const float* An = Abase + (t + 1) * BK;
            const float* Bn = Bbase + (t + 1) * BK;
#pragma unroll
            for (int i = 0; i < NV; ++i) pa[i] = *(const f32x4*)(An + i * 4);
#pragma unroll
            for (int i = 0; i < NV; ++i) pb[i] = *(const f32x4*)(Bn + i * 4);
        }

        // fragment reads + MFMA
        bf16x8 af[FM], bfr[FN];
#pragma unroll
        for (int i = 0; i < FM; ++i)
            af[i] = *(const bf16x8*)&As[(wr * WM + i * 16 + frow) * LDS_S + fk];
#pragma unroll
        for (int j = 0; j < FN; ++j)
            bfr[j] = *(const bf16x8*)&Bs[(wc * WN + j * 16 + frow) * LDS_S + fk];
#pragma unroll
        for (int i = 0; i < FM; ++i)
#pragma unroll
            for (int j = 0; j < FN; ++j)
                acc[i][j] = __builtin_amdgcn_mfma_f32_16x16x32_bf16(
                    af[i], bfr[j], acc[i][j], 0, 0, 0);
        __syncthreads();
    }

    // epilogue: bias (+GELU), fp32 store
#pragma unroll
    for (int i = 0; i < FM; ++i) {
#pragma unroll
        for (int j = 0; j < FN; ++j) {
            const int n = n0 + wc * WN + j * 16 + (lane & 15);
            const float bias = biasv[n];
#pragma unroll
            for (int r = 0; r < 4; ++r) {
                const int m = m0 + wr * WM + i * 16 + (lane >> 4) * 4 + r;
                float v = acc[i][j][r] + bias;
                if constexpr (ACT == 1)
                    v = 0.5f * v * (1.f + erff(v * 0.70710678118654752f));
                C[(size_t)m * ldc + n] = v;
            }
        }
    }
}

// ---------------- attention scores: S[bh,q,k] = 0.125*Q.K + bias[b,q,k]
__global__ __launch_bounds__(256) void k_scores(const float* __restrict__ qkv,
                                                const float* __restrict__ biasmat,
                                                float* __restrict__ S) {
    __shared__ float Qs[DHn][64 + 1];   // [d][q]
    __shared__ float Ks[DHn][64 + 1];
    const int bh = blockIdx.z;
    const int b = bh >> 3, h = bh & 7;
    const int q0 = blockIdx.x * 64, k0 = blockIdx.y * 64;
    const int tid = threadIdx.x;
    const int tx = tid & 15, ty = tid >> 4;
    const float* Qbase = qkv + (size_t)(b * Nn) * QKV_LD + h * DHn;
    const float* Kbase = Qbase + En;

    for (int i = tid; i < 64 * 64; i += 256) {
        int r = i >> 6, d = i & 63;
        Qs[d][r] = Qbase[(size_t)(q0 + r) * QKV_LD + d];
        Ks[d][r] = Kbase[(size_t)(k0 + r) * QKV_LD + d];
    }
    __syncthreads();

    float acc[4][4] = {};
#pragma unroll 4
    for (int d = 0; d < DHn; ++d) {
        float a[4], bb[4];
#pragma unroll
        for (int i = 0; i < 4; ++i) a[i] = Qs[d][ty * 4 + i];
#pragma unroll
        for (int j = 0; j < 4; ++j) bb[j] = Ks[d][tx * 4 + j];
#pragma unroll
        for (int i = 0; i < 4; ++i)
#pragma unroll
            for (int j = 0; j < 4; ++j)
                acc[i][j] = fmaf(a[i], bb[j], acc[i][j]);
    }
    const float scale = 0.125f;  // 1/sqrt(64)
#pragma unroll
    for (int i = 0; i < 4; ++i) {
        int q = q0 + ty * 4 + i;
#pragma unroll
        for (int j = 0; j < 4; ++j) {
            int k = k0 + tx * 4 + j;
            float bmat = biasmat[((size_t)b * Nn + q) * Nn + k];
            S[((size_t)bh * Nn + q) * Nn + k] = fmaf(acc[i][j], scale, bmat);
        }
    }
}

// ---------------- row softmax over k (row length 256), one wave per row
__global__ __launch_bounds__(64) void k_softmax(float* __restrict__ S) {
    const size_t row = blockIdx.x;
    float4* p = reinterpret_cast<float4*>(S + row * Nn) + threadIdx.x;
    float4 v = *p;
    float mx = fmaxf(fmaxf(v.x, v.y), fmaxf(v.z, v.w));
#pragma unroll
    for (int o = 32; o; o >>= 1) mx = fmaxf(mx, __shfl_xor(mx, o));
    float e0 = __expf(v.x - mx), e1 = __expf(v.y - mx);
    float e2 = __expf(v.z - mx), e3 = __expf(v.w - mx);
    float sum = (e0 + e1) + (e2 + e3);
#pragma unroll
    for (int o = 32; o; o >>= 1) sum += __shfl_xor(sum, o);
    float r = 1.f / sum;
    *p = make_float4(e0 * r, e1 * r, e2 * r, e3 * r);
}

// ---------------- PV: attn[b,q,h*64+d] = sum_k P[bh,q,k]*V[b,k,2E+h*64+d]
__global__ __launch_bounds__(256) void k_pv(const float* __restrict__ P,
                                            const float* __restrict__ qkv,
                                            float* __restrict__ attn) {
    const int bh = blockIdx.z;
    const int b = bh >> 3, h = bh & 7;
    const int d = threadIdx.x & 63;
    const int q = blockIdx.x * 4 + (threadIdx.x >> 6);
    const float* Vbase = qkv + (size_t)(b * Nn) * QKV_LD + 2 * En + h * DHn;
    const float* Prow = P + ((size_t)bh * Nn + q) * Nn;
    float acc = 0.f;
#pragma unroll 8
    for (int k = 0; k < Nn; ++k)
        acc = fmaf(Prow[k], Vbase[(size_t)k * QKV_LD + d], acc);
    attn[((size_t)(b * Nn + q)) * En + h * DHn + d] = acc;
}

// ---------------- residual add + LayerNorm (row = 512, block = 256)
__global__ __launch_bounds__(256) void k_addln(const float* __restrict__ xin,
                                               const float* __restrict__ y,
                                               const float* __restrict__ g,
                                               const float* __restrict__ bb,
                                               float* __restrict__ xout) {
    const int row = blockIdx.x;
    const int tid = threadIdx.x;
    const size_t base = (size_t)row * En;
    float v0 = xin[base + tid] + y[base + tid];
    float v1 = xin[base + tid + 256] + y[base + tid + 256];
    float s1 = v0 + v1;
    float s2 = v0 * v0 + v1 * v1;
#pragma unroll
    for (int o = 32; o; o >>= 1) {
        s1 += __shfl_xor(s1, o);
        s2 += __shfl_xor(s2, o);
    }
    __shared__ float ws1[4], ws2[4];
    int w = tid >> 6;
    if ((tid & 63) == 0) { ws1[w] = s1; ws2[w] = s2; }
    __syncthreads();
    s1 = (ws1[0] + ws1[1]) + (ws1[2] + ws1[3]);
    s2 = (ws2[0] + ws2[1]) + (ws2[2] + ws2[3]);
    const float rE = 1.f / (float)En;
    float mean = s1 * rE;
    float var = s2 * rE - mean * mean;
    float inv = rsqrtf(var + 1e-5f);
    xout[base + tid]       = (v0 - mean) * inv * g[tid] + bb[tid];
    xout[base + tid + 256] = (v1 - mean) * inv * g[tid + 256] + bb[tid + 256];
}

// ---------------- final: fp32 x ++ fp32 pad_mask
__global__ __launch_bounds__(256) void k_out(const float* __restrict__ x,
                                             const int* __restrict__ tok,
                                             float* __restrict__ out) {
    int i = blockIdx.x * 256 + threadIdx.x;
    const int total = Mn * En + Mn;
    if (i >= total) return;
    if (i < Mn * En) {
        out[i] = x[i];
    } else {
        int m = i - Mn * En;
        out[i] = (tok[m] == 0) ? 1.f : 0.f;
    }
}

// ---------------------------------------------------------------------------
extern "C" void kernel_launch(void* const* d_in, const int* in_sizes, int n_in,
                              void* d_out, int out_size, void* d_ws, size_t ws_size,
                              hipStream_t stream) {
    const int*   tok   = (const int*)  d_in[0];
    const float* dist  = (const float*)d_in[2];
    const float* emb   = (const float*)d_in[4];
    const float* dp_w1 = (const float*)d_in[5];
    const float* dp_b1 = (const float*)d_in[6];
    const float* dp_w2 = (const float*)d_in[7];
    const float* dp_b2 = (const float*)d_in[8];
    const float* Wqkv  = (const float*)d_in[9];
    const float* bqkv  = (const float*)d_in[10];
    const float* Wo    = (const float*)d_in[11];
    const float* bo    = (const float*)d_in[12];
    const float* ln1g  = (const float*)d_in[13];
    const float* ln1b  = (const float*)d_in[14];
    const float* W1    = (const float*)d_in[15];
    const float* b1    = (const float*)d_in[16];
    const float* W2    = (const float*)d_in[17];
    const float* b2    = (const float*)d_in[18];
    const float* ln2g  = (const float*)d_in[19];
    const float* ln2b  = (const float*)d_in[20];

    float* ws = (float*)d_ws;
    float* biasmat = ws;                         // 524288
    float* x       = biasmat + (size_t)Bn*Nn*Nn; // 1048576
    float* qkv     = x    + (size_t)Mn*En;       // 3145728
    float* Sff     = qkv  + (size_t)Mn*QKV_LD;   // 4194304 (scores / FF shared)
    float* attn    = Sff  + (size_t)Bn*Hn*Nn*Nn; // 1048576
    float* y       = attn + (size_t)Mn*En;       // 1048576

    k_embed<<<Mn * En / 256, 256, 0, stream>>>(tok, emb, x);
    k_distbias<<<Bn * Nn * Nn / 256, 256, 0, stream>>>(dist, tok, dp_w1, dp_b1,
                                                       dp_w2, dp_b2, biasmat);

    for (int l = 0; l < Ln; ++l) {
        const float* Wqkv_l = Wqkv + (size_t)l * 3 * En * En;
        const float* bqkv_l = bqkv + (size_t)l * 3 * En;
        const float* Wo_l   = Wo   + (size_t)l * En * En;
        const float* bo_l   = bo   + (size_t)l * En;
        const float* W1_l   = W1   + (size_t)l * FFn * En;
        const float* b1_l   = b1   + (size_t)l * FFn;
        const float* W2_l   = W2   + (size_t)l * En * FFn;
        const float* b2_l   = b2   + (size_t)l * En;

        // QKV projection: [2048,512] x [1536,512]^T -> [2048,1536]
        k_gemm_mfma<128, 128, 0><<<dim3(Mn / 128, QKV_LD / 128), 256, 0, stream>>>(
            x, En, Wqkv_l, En, bqkv_l, qkv, QKV_LD, En);

        // attention
        k_scores<<<dim3(Nn / 64, Nn / 64, Bn * Hn), 256, 0, stream>>>(qkv, biasmat, Sff);
        k_softmax<<<Bn * Hn * Nn, 64, 0, stream>>>(Sff);
        k_pv<<<dim3(Nn / 4, 1, Bn * Hn), 256, 0, stream>>>(Sff, qkv, attn);

        // O projection: [2048,512] x [512,512]^T
        k_gemm_mfma<64, 64, 0><<<dim3(Mn / 64, En / 64), 256, 0, stream>>>(
            attn, En, Wo_l, En, bo_l, y, En, En);
        k_addln<<<Mn, 256, 0, stream>>>(x, y, ln1g + (size_t)l * En, ln1b + (size_t)l * En, x);

        // FF1 + GELU: [2048,512] x [2048,512]^T -> [2048,2048]
        k_gemm_mfma<128, 128, 1><<<dim3(Mn / 128, FFn / 128), 256, 0, stream>>>(
            x, En, W1_l, En, b1_l, Sff, FFn, En);

        // FF2: [2048,2048] x [512,2048]^T -> [2048,512]
        k_gemm_mfma<64, 64, 0><<<dim3(Mn / 64, En / 64), 256, 0, stream>>>(
            Sff, FFn, W2_l, FFn, b2_l, y, En, FFn);
        k_addln<<<Mn, 256, 0, stream>>>(x, y, ln2g + (size_t)l * En, ln2b + (size_t)l * En, x);
    }

    k_out<<<(Mn * En + Mn + 255) / 256, 256, 0, stream>>>(x, tok, (float*)d_out);
}

// Round 7
// 798.415 us; speedup vs baseline: 3.1656x; 1.1140x over previous
//
#include <hip/hip_runtime.h>
#include <hip/hip_bf16.h>

// ---------------------------------------------------------------------------
// SimpleGeoFormerModel: 4-layer transformer encoder. FP32 in/out, bf16 MFMA
// GEMMs (fp32 accumulate). B=8 N=256 E=512 V=512 L=4 H=8 FF=2048, dh=64.
// Round 7: distance-bias via on-device LUT (tanh sum is a scalar fn of d).
// ---------------------------------------------------------------------------

namespace {
constexpr int Bn  = 8;
constexpr int Nn  = 256;
constexpr int En  = 512;
constexpr int Ln  = 4;
constexpr int Hn  = 8;
constexpr int FFn = 2048;
constexpr int DHn = 64;
constexpr int Mn  = Bn * Nn;        // 2048 rows
constexpr int QKV_LD = 3 * En;      // 1536
constexpr int LUT_N = 4096;         // nodes at d = i * 10/4096, i in [0,4096]
}

typedef float f32x4 __attribute__((ext_vector_type(4)));
typedef short bf16x8 __attribute__((ext_vector_type(8)));

// fp32 -> bf16 round-to-nearest-even (inputs are finite; no NaN handling)
__device__ __forceinline__ unsigned short f2bs(float f) {
    union { float f; unsigned u; } v; v.f = f;
    unsigned r = v.u + 0x7FFFu + ((v.u >> 16) & 1u);
    return (unsigned short)(r >> 16);
}

__device__ __forceinline__ bf16x8 cvt8(f32x4 a, f32x4 b) {
    bf16x8 r;
    r[0] = (short)f2bs(a[0]); r[1] = (short)f2bs(a[1]);
    r[2] = (short)f2bs(a[2]); r[3] = (short)f2bs(a[3]);
    r[4] = (short)f2bs(b[0]); r[5] = (short)f2bs(b[1]);
    r[6] = (short)f2bs(b[2]); r[7] = (short)f2bs(b[3]);
    return r;
}

// ---------------- embedding gather ----------------
__global__ __launch_bounds__(256) void k_embed(const int* __restrict__ tok,
                                               const float* __restrict__ emb,
                                               float* __restrict__ x) {
    int i = blockIdx.x * 256 + threadIdx.x;   // over Mn*En
    int m = i >> 9;                           // /512
    int e = i & 511;
    x[i] = emb[tok[m] * En + e];
}

// ---------------- LUT build: lut[i] = sum_e w2[e]*tanh(d_i*w1[e]+b1[e]),
// d_i = i * 10/4096, i in [0, 4096]
__global__ __launch_bounds__(256) void k_lutbuild(const float* __restrict__ w1,
                                                  const float* __restrict__ b1,
                                                  const float* __restrict__ w2,
                                                  float* __restrict__ lut) {
    __shared__ float sw1[En], sb1[En], sw2[En];
    for (int e = threadIdx.x; e < En; e += 256) {
        sw1[e] = w1[e]; sb1[e] = b1[e]; sw2[e] = w2[e];
    }
    __syncthreads();
    int i = blockIdx.x * 256 + threadIdx.x;
    if (i > LUT_N) return;
    float d = (float)i * (10.0f / (float)LUT_N);
    float acc = 0.f;
#pragma unroll 4
    for (int e = 0; e < En; ++e) {
        float s = fmaf(d, sw1[e], sb1[e]);
        float t = 1.f - 2.f / (__expf(2.f * s) + 1.f);   // tanh(s)
        acc = fmaf(t, sw2[e], acc);
    }
    lut[i] = acc;
}

// ---------------- distance bias via LUT (memory-bound map) ----------------
__global__ __launch_bounds__(256) void k_distbias_lut(const float* __restrict__ dist,
                                                      const int* __restrict__ tok,
                                                      const float* __restrict__ lut,
                                                      const float* __restrict__ b2,
                                                      float* __restrict__ biasmat) {
    int i = blockIdx.x * 256 + threadIdx.x;   // b*N*N + q*N + k
    float d = dist[i];
    float idx = d * ((float)LUT_N / 10.0f);
    int ii = (int)idx;
    ii = ii < 0 ? 0 : (ii > LUT_N - 1 ? LUT_N - 1 : ii);
    float frac = idx - (float)ii;
    float v0 = lut[ii], v1 = lut[ii + 1];
    float acc = fmaf(v1 - v0, frac, v0) + b2[0];
    int k = i & (Nn - 1);
    int q = (i >> 8) & (Nn - 1);
    int b = i >> 16;
    bool pad = (tok[b * Nn + k] == 0) || (tok[b * Nn + q] == 0);
    biasmat[i] = pad ? -1e30f : acc;
}

// ---------------- MFMA GEMM: C[m,n] = sum_k A[m,k]*Bw[n,k] + bias[n]  (B^T)
// fp32 inputs, on-the-fly bf16 conversion, mfma_f32_16x16x32_bf16, fp32 out.
// 256 threads = 4 waves in 2x2 grid; each wave computes (BM/2)x(BN/2).
// ACT: 0 = none, 1 = exact GELU.
template <int BM, int BN, int ACT>
__global__ __launch_bounds__(256) void k_gemm_mfma(const float* __restrict__ A, int lda,
                                                   const float* __restrict__ Bw, int ldb,
                                                   const float* __restrict__ biasv,
                                                   float* __restrict__ C, int ldc,
                                                   int K) {
    static_assert(BM == BN, "square tiles only");
    constexpr int BK    = 32;
    constexpr int LDS_S = BK + 8;       // 40 shorts = 80B row stride
    constexpr int WM = BM / 2, WN = BN / 2;
    constexpr int FM = WM / 16, FN = WN / 16;
    constexpr int GR = 256 / BM;        // threads per staged row (2 or 4)
    constexpr int TC = BK / GR;         // cols per thread (16 or 8)
    constexpr int NV = TC / 4;          // f32x4 loads per operand (4 or 2)

    __shared__ short As[BM * LDS_S];
    __shared__ short Bs[BM * LDS_S];

    const int tid  = threadIdx.x;
    const int lane = tid & 63;
    const int wv   = tid >> 6;
    const int wr   = wv >> 1, wc = wv & 1;
    const int m0 = blockIdx.x * BM, n0 = blockIdx.y * BN;

    const int arow = tid / GR;
    const int acol = (tid % GR) * TC;

    const float* Abase = A  + (size_t)(m0 + arow) * lda + acol;
    const float* Bbase = Bw + (size_t)(n0 + arow) * ldb + acol;

    // prefetch tile 0
    f32x4 pa[NV], pb[NV];
#pragma unroll
    for (int i = 0; i < NV; ++i) pa[i] = *(const f32x4*)(Abase + i * 4);
#pragma unroll
    for (int i = 0; i < NV; ++i) pb[i] = *(const f32x4*)(Bbase + i * 4);

    f32x4 acc[FM][FN];
#pragma unroll
    for (int i = 0; i < FM; ++i)
#pragma unroll
        for (int j = 0; j < FN; ++j) acc[i][j] = {0.f, 0.f, 0.f, 0.f};

    const int fk   = (lane >> 4) * 8;   // frag k-offset
    const int frow = lane & 15;         // frag row within 16-block
    short* awp = &As[arow * LDS_S + acol];
    short* bwp = &Bs[arow * LDS_S + acol];

    const int nt = K / BK;
    for (int t = 0; t < nt; ++t) {
#pragma unroll
        for (int i = 0; i < NV / 2; ++i)
            *(bf16x8*)(awp + i * 8) = cvt8(pa[2 * i], pa[2 * i + 1]);
#pragma unroll
        for (int i = 0; i < NV / 2; ++i)
            *(bf16x8*)(bwp + i * 8) = cvt8(pb[2 * i], pb[2 * i + 1]);
        __syncthreads();

        if (t + 1 < nt) {
            const float* An = Abase + (t + 1) * BK;
            const float* Bn = Bbase + (t + 1) * BK;
#pragma unroll
            for (int i = 0; i < NV; ++i) pa[i] = *(const f32x4*)(An + i * 4);
#pragma unroll
            for (int i = 0; i < NV; ++i) pb[i] = *(const f32x4*)(Bn + i * 4);
        }

        bf16x8 af[FM], bfr[FN];
#pragma unroll
        for (int i = 0; i < FM; ++i)
            af[i] = *(const bf16x8*)&As[(wr * WM + i * 16 + frow) * LDS_S + fk];
#pragma unroll
        for (int j = 0; j < FN; ++j)
            bfr[j] = *(const bf16x8*)&Bs[(wc * WN + j * 16 + frow) * LDS_S + fk];
#pragma unroll
        for (int i = 0; i < FM; ++i)
#pragma unroll
            for (int j = 0; j < FN; ++j)
                acc[i][j] = __builtin_amdgcn_mfma_f32_16x16x32_bf16(
                    af[i], bfr[j], acc[i][j], 0, 0, 0);
        __syncthreads();
    }

#pragma unroll
    for (int i = 0; i < FM; ++i) {
#pragma unroll
        for (int j = 0; j < FN; ++j) {
            const int n = n0 + wc * WN + j * 16 + (lane & 15);
            const float bias = biasv[n];
#pragma unroll
            for (int r = 0; r < 4; ++r) {
                const int m = m0 + wr * WM + i * 16 + (lane >> 4) * 4 + r;
                float v = acc[i][j][r] + bias;
                if constexpr (ACT == 1)
                    v = 0.5f * v * (1.f + erff(v * 0.70710678118654752f));
                C[(size_t)m * ldc + n] = v;
            }
        }
    }
}

// ---------------- attention scores: S[bh,q,k] = 0.125*Q.K + bias[b,q,k]
__global__ __launch_bounds__(256) void k_scores(const float* __restrict__ qkv,
                                                const float* __restrict__ biasmat,
                                                float* __restrict__ S) {
    __shared__ float Qs[DHn][64 + 1];   // [d][q]
    __shared__ float Ks[DHn][64 + 1];
    const int bh = blockIdx.z;
    const int b = bh >> 3, h = bh & 7;
    const int q0 = blockIdx.x * 64, k0 = blockIdx.y * 64;
    const int tid = threadIdx.x;
    const int tx = tid & 15, ty = tid >> 4;
    const float* Qbase = qkv + (size_t)(b * Nn) * QKV_LD + h * DHn;
    const float* Kbase = Qbase + En;

    for (int i = tid; i < 64 * 64; i += 256) {
        int r = i >> 6, d = i & 63;
        Qs[d][r] = Qbase[(size_t)(q0 + r) * QKV_LD + d];
        Ks[d][r] = Kbase[(size_t)(k0 + r) * QKV_LD + d];
    }
    __syncthreads();

    float acc[4][4] = {};
#pragma unroll 4
    for (int d = 0; d < DHn; ++d) {
        float a[4], bb[4];
#pragma unroll
        for (int i = 0; i < 4; ++i) a[i] = Qs[d][ty * 4 + i];
#pragma unroll
        for (int j = 0; j < 4; ++j) bb[j] = Ks[d][tx * 4 + j];
#pragma unroll
        for (int i = 0; i < 4; ++i)
#pragma unroll
            for (int j = 0; j < 4; ++j)
                acc[i][j] = fmaf(a[i], bb[j], acc[i][j]);
    }
    const float scale = 0.125f;  // 1/sqrt(64)
#pragma unroll
    for (int i = 0; i < 4; ++i) {
        int q = q0 + ty * 4 + i;
#pragma unroll
        for (int j = 0; j < 4; ++j) {
            int k = k0 + tx * 4 + j;
            float bmat = biasmat[((size_t)b * Nn + q) * Nn + k];
            S[((size_t)bh * Nn + q) * Nn + k] = fmaf(acc[i][j], scale, bmat);
        }
    }
}

// ---------------- row softmax over k (row length 256), one wave per row
__global__ __launch_bounds__(64) void k_softmax(float* __restrict__ S) {
    const size_t row = blockIdx.x;
    float4* p = reinterpret_cast<float4*>(S + row * Nn) + threadIdx.x;
    float4 v = *p;
    float mx = fmaxf(fmaxf(v.x, v.y), fmaxf(v.z, v.w));
#pragma unroll
    for (int o = 32; o; o >>= 1) mx = fmaxf(mx, __shfl_xor(mx, o));
    float e0 = __expf(v.x - mx), e1 = __expf(v.y - mx);
    float e2 = __expf(v.z - mx), e3 = __expf(v.w - mx);
    float sum = (e0 + e1) + (e2 + e3);
#pragma unroll
    for (int o = 32; o; o >>= 1) sum += __shfl_xor(sum, o);
    float r = 1.f / sum;
    *p = make_float4(e0 * r, e1 * r, e2 * r, e3 * r);
}

// ---------------- PV: attn[b,q,h*64+d] = sum_k P[bh,q,k]*V[b,k,2E+h*64+d]
__global__ __launch_bounds__(256) void k_pv(const float* __restrict__ P,
                                            const float* __restrict__ qkv,
                                            float* __restrict__ attn) {
    const int bh = blockIdx.z;
    const int b = bh >> 3, h = bh & 7;
    const int d = threadIdx.x & 63;
    const int q = blockIdx.x * 4 + (threadIdx.x >> 6);
    const float* Vbase = qkv + (size_t)(b * Nn) * QKV_LD + 2 * En + h * DHn;
    const float* Prow = P + ((size_t)bh * Nn + q) * Nn;
    float acc = 0.f;
#pragma unroll 8
    for (int k = 0; k < Nn; ++k)
        acc = fmaf(Prow[k], Vbase[(size_t)k * QKV_LD + d], acc);
    attn[((size_t)(b * Nn + q)) * En + h * DHn + d] = acc;
}

// ---------------- residual add + LayerNorm (row = 512, block = 256)
__global__ __launch_bounds__(256) void k_addln(const float* __restrict__ xin,
                                               const float* __restrict__ y,
                                               const float* __restrict__ g,
                                               const float* __restrict__ bb,
                                               float* __restrict__ xout) {
    const int row = blockIdx.x;
    const int tid = threadIdx.x;
    const size_t base = (size_t)row * En;
    float v0 = xin[base + tid] + y[base + tid];
    float v1 = xin[base + tid + 256] + y[base + tid + 256];
    float s1 = v0 + v1;
    float s2 = v0 * v0 + v1 * v1;
#pragma unroll
    for (int o = 32; o; o >>= 1) {
        s1 += __shfl_xor(s1, o);
        s2 += __shfl_xor(s2, o);
    }
    __shared__ float ws1[4], ws2[4];
    int w = tid >> 6;
    if ((tid & 63) == 0) { ws1[w] = s1; ws2[w] = s2; }
    __syncthreads();
    s1 = (ws1[0] + ws1[1]) + (ws1[2] + ws1[3]);
    s2 = (ws2[0] + ws2[1]) + (ws2[2] + ws2[3]);
    const float rE = 1.f / (float)En;
    float mean = s1 * rE;
    float var = s2 * rE - mean * mean;
    float inv = rsqrtf(var + 1e-5f);
    xout[base + tid]       = (v0 - mean) * inv * g[tid] + bb[tid];
    xout[base + tid + 256] = (v1 - mean) * inv * g[tid + 256] + bb[tid + 256];
}

// ---------------- final: fp32 x ++ fp32 pad_mask
__global__ __launch_bounds__(256) void k_out(const float* __restrict__ x,
                                             const int* __restrict__ tok,
                                             float* __restrict__ out) {
    int i = blockIdx.x * 256 + threadIdx.x;
    const int total = Mn * En + Mn;
    if (i >= total) return;
    if (i < Mn * En) {
        out[i] = x[i];
    } else {
        int m = i - Mn * En;
        out[i] = (tok[m] == 0) ? 1.f : 0.f;
    }
}

// ---------------------------------------------------------------------------
extern "C" void kernel_launch(void* const* d_in, const int* in_sizes, int n_in,
                              void* d_out, int out_size, void* d_ws, size_t ws_size,
                              hipStream_t stream) {
    const int*   tok   = (const int*)  d_in[0];
    const float* dist  = (const float*)d_in[2];
    const float* emb   = (const float*)d_in[4];
    const float* dp_w1 = (const float*)d_in[5];
    const float* dp_b1 = (const float*)d_in[6];
    const float* dp_w2 = (const float*)d_in[7];
    const float* dp_b2 = (const float*)d_in[8];
    const float* Wqkv  = (const float*)d_in[9];
    const float* bqkv  = (const float*)d_in[10];
    const float* Wo    = (const float*)d_in[11];
    const float* bo    = (const float*)d_in[12];
    const float* ln1g  = (const float*)d_in[13];
    const float* ln1b  = (const float*)d_in[14];
    const float* W1    = (const float*)d_in[15];
    const float* b1    = (const float*)d_in[16];
    const float* W2    = (const float*)d_in[17];
    const float* b2    = (const float*)d_in[18];
    const float* ln2g  = (const float*)d_in[19];
    const float* ln2b  = (const float*)d_in[20];

    float* ws = (float*)d_ws;
    float* biasmat = ws;                         // 524288
    float* x       = biasmat + (size_t)Bn*Nn*Nn; // 1048576
    float* qkv     = x    + (size_t)Mn*En;       // 3145728
    float* Sff     = qkv  + (size_t)Mn*QKV_LD;   // 4194304 (scores / FF shared)
    float* attn    = Sff  + (size_t)Bn*Hn*Nn*Nn; // 1048576
    float* y       = attn + (size_t)Mn*En;       // 1048576
    float* lut     = y    + (size_t)Mn*En;       // 4097 (+pad)

    k_embed<<<Mn * En / 256, 256, 0, stream>>>(tok, emb, x);
    k_lutbuild<<<(LUT_N + 256) / 256, 256, 0, stream>>>(dp_w1, dp_b1, dp_w2, lut);
    k_distbias_lut<<<Bn * Nn * Nn / 256, 256, 0, stream>>>(dist, tok, lut, dp_b2,
                                                           biasmat);

    for (int l = 0; l < Ln; ++l) {
        const float* Wqkv_l = Wqkv + (size_t)l * 3 * En * En;
        const float* bqkv_l = bqkv + (size_t)l * 3 * En;
        const float* Wo_l   = Wo   + (size_t)l * En * En;
        const float* bo_l   = bo   + (size_t)l * En;
        const float* W1_l   = W1   + (size_t)l * FFn * En;
        const float* b1_l   = b1   + (size_t)l * FFn;
        const float* W2_l   = W2   + (size_t)l * En * FFn;
        const float* b2_l   = b2   + (size_t)l * En;

        // QKV projection: [2048,512] x [1536,512]^T -> [2048,1536]
        k_gemm_mfma<128, 128, 0><<<dim3(Mn / 128, QKV_LD / 128), 256, 0, stream>>>(
            x, En, Wqkv_l, En, bqkv_l, qkv, QKV_LD, En);

        // attention
        k_scores<<<dim3(Nn / 64, Nn / 64, Bn * Hn), 256, 0, stream>>>(qkv, biasmat, Sff);
        k_softmax<<<Bn * Hn * Nn, 64, 0, stream>>>(Sff);
        k_pv<<<dim3(Nn / 4, 1, Bn * Hn), 256, 0, stream>>>(Sff, qkv, attn);

        // O projection: [2048,512] x [512,512]^T
        k_gemm_mfma<64, 64, 0><<<dim3(Mn / 64, En / 64), 256, 0, stream>>>(
            attn, En, Wo_l, En, bo_l, y, En, En);
        k_addln<<<Mn, 256, 0, stream>>>(x, y, ln1g + (size_t)l * En, ln1b + (size_t)l * En, x);

        // FF1 + GELU: [2048,512] x [2048,512]^T -> [2048,2048]
        k_gemm_mfma<128, 128, 1><<<dim3(Mn / 128, FFn / 128), 256, 0, stream>>>(
            x, En, W1_l, En, b1_l, Sff, FFn, En);

        // FF2: [2048,2048] x [512,2048]^T -> [2048,512]
        k_gemm_mfma<64, 64, 0><<<dim3(Mn / 64, En / 64), 256, 0, stream>>>(
            Sff, FFn, W2_l, FFn, b2_l, y, En, FFn);
        k_addln<<<Mn, 256, 0, stream>>>(x, y, ln2g + (size_t)l * En, ln2b + (size_t)l * En, x);
    }

    k_out<<<(Mn * En + Mn + 255) / 256, 256, 0, stream>>>(x, tok, (float*)d_out);
}

// Round 8
// 555.553 us; speedup vs baseline: 4.5494x; 1.4372x over previous
//
#include <hip/hip_runtime.h>
#include <hip/hip_bf16.h>

// ---------------------------------------------------------------------------
// SimpleGeoFormerModel: 4-layer transformer encoder. FP32 in/out, bf16 MFMA
// GEMMs (fp32 accumulate). B=8 N=256 E=512 V=512 L=4 H=8 FF=2048, dh=64.
// Round 8: attention scores + PV moved to batched MFMA GEMMs (+V^T transpose).
// ---------------------------------------------------------------------------

namespace {
constexpr int Bn  = 8;
constexpr int Nn  = 256;
constexpr int En  = 512;
constexpr int Ln  = 4;
constexpr int Hn  = 8;
constexpr int FFn = 2048;
constexpr int DHn = 64;
constexpr int Mn  = Bn * Nn;        // 2048 rows
constexpr int QKV_LD = 3 * En;      // 1536
constexpr int LUT_N = 4096;         // nodes at d = i * 10/4096, i in [0,4096]
}

typedef float f32x4 __attribute__((ext_vector_type(4)));
typedef short bf16x8 __attribute__((ext_vector_type(8)));

// fp32 -> bf16 round-to-nearest-even (inputs are finite; no NaN handling)
__device__ __forceinline__ unsigned short f2bs(float f) {
    union { float f; unsigned u; } v; v.f = f;
    unsigned r = v.u + 0x7FFFu + ((v.u >> 16) & 1u);
    return (unsigned short)(r >> 16);
}

__device__ __forceinline__ bf16x8 cvt8(f32x4 a, f32x4 b) {
    bf16x8 r;
    r[0] = (short)f2bs(a[0]); r[1] = (short)f2bs(a[1]);
    r[2] = (short)f2bs(a[2]); r[3] = (short)f2bs(a[3]);
    r[4] = (short)f2bs(b[0]); r[5] = (short)f2bs(b[1]);
    r[6] = (short)f2bs(b[2]); r[7] = (short)f2bs(b[3]);
    return r;
}

// ---------------- embedding gather ----------------
__global__ __launch_bounds__(256) void k_embed(const int* __restrict__ tok,
                                               const float* __restrict__ emb,
                                               float* __restrict__ x) {
    int i = blockIdx.x * 256 + threadIdx.x;   // over Mn*En
    int m = i >> 9;
    int e = i & 511;
    x[i] = emb[tok[m] * En + e];
}

// ---------------- LUT build: lut[i] = sum_e w2[e]*tanh(d_i*w1[e]+b1[e])
__global__ __launch_bounds__(256) void k_lutbuild(const float* __restrict__ w1,
                                                  const float* __restrict__ b1,
                                                  const float* __restrict__ w2,
                                                  float* __restrict__ lut) {
    __shared__ float sw1[En], sb1[En], sw2[En];
    for (int e = threadIdx.x; e < En; e += 256) {
        sw1[e] = w1[e]; sb1[e] = b1[e]; sw2[e] = w2[e];
    }
    __syncthreads();
    int i = blockIdx.x * 256 + threadIdx.x;
    if (i > LUT_N) return;
    float d = (float)i * (10.0f / (float)LUT_N);
    float acc = 0.f;
#pragma unroll 4
    for (int e = 0; e < En; ++e) {
        float s = fmaf(d, sw1[e], sb1[e]);
        float t = 1.f - 2.f / (__expf(2.f * s) + 1.f);   // tanh(s)
        acc = fmaf(t, sw2[e], acc);
    }
    lut[i] = acc;
}

// ---------------- distance bias via LUT (memory-bound map) ----------------
__global__ __launch_bounds__(256) void k_distbias_lut(const float* __restrict__ dist,
                                                      const int* __restrict__ tok,
                                                      const float* __restrict__ lut,
                                                      const float* __restrict__ b2,
                                                      float* __restrict__ biasmat) {
    int i = blockIdx.x * 256 + threadIdx.x;   // b*N*N + q*N + k
    float d = dist[i];
    float idx = d * ((float)LUT_N / 10.0f);
    int ii = (int)idx;
    ii = ii < 0 ? 0 : (ii > LUT_N - 1 ? LUT_N - 1 : ii);
    float frac = idx - (float)ii;
    float v0 = lut[ii], v1 = lut[ii + 1];
    float acc = fmaf(v1 - v0, frac, v0) + b2[0];
    int k = i & (Nn - 1);
    int q = (i >> 8) & (Nn - 1);
    int b = i >> 16;
    bool pad = (tok[b * Nn + k] == 0) || (tok[b * Nn + q] == 0);
    biasmat[i] = pad ? -1e30f : acc;
}

// ---------------- V^T per head: vT[bh][d][k] = qkv[b*256+k][2E + h*64 + d]
__global__ __launch_bounds__(256) void k_vt(const float* __restrict__ qkv,
                                            float* __restrict__ vT) {
    __shared__ float t[64][65];
    const int tid = threadIdx.x;
    const int bh = blockIdx.y, b = bh >> 3, h = bh & 7;
    const int k0 = blockIdx.x * 64;
    const float* src = qkv + ((size_t)(b * Nn + k0)) * QKV_LD + 2 * En + h * DHn;
    for (int idx = tid; idx < 64 * 64; idx += 256) {
        int r = idx >> 6, c = idx & 63;                 // r=k-local, c=d
        t[r][c] = src[(size_t)r * QKV_LD + c];
    }
    __syncthreads();
    float* dst = vT + ((size_t)bh * DHn) * Nn + k0;
    for (int idx = tid; idx < 64 * 64; idx += 256) {
        int d = idx >> 6, kk = idx & 63;
        dst[(size_t)d * Nn + kk] = t[kk][d];
    }
}

// ---------------- MFMA GEMM: C[m,n] = sum_k A[m,k]*Bw[n,k] (+ epilogue)
// MODE 0: +bias[n]; MODE 1: gelu(+bias[n]); MODE 2: 0.125*acc + biasmat[b][m][n];
// MODE 3: none. Batched over blockIdx.z with (b = z>>3, h = z&7) strides.
template <int BM, int BN, int MODE>
__global__ __launch_bounds__(256) void k_gemm_mfma(
        const float* __restrict__ A, int lda, long long sAb, long long sAh,
        const float* __restrict__ Bw, int ldb, long long sBb, long long sBh,
        const float* __restrict__ bias,
        float* __restrict__ C, int ldc, long long sCb, long long sCh,
        int K) {
    static_assert(BM == BN, "square tiles only");
    constexpr int BK    = 32;
    constexpr int LDS_S = BK + 8;       // 40 shorts = 80B row stride
    constexpr int WM = BM / 2, WN = BN / 2;
    constexpr int FM = WM / 16, FN = WN / 16;
    constexpr int GR = 256 / BM;        // threads per staged row
    constexpr int TC = BK / GR;         // cols per thread
    constexpr int NV = TC / 4;          // f32x4 loads per operand

    __shared__ short As[BM * LDS_S];
    __shared__ short Bs[BM * LDS_S];

    const int tid  = threadIdx.x;
    const int lane = tid & 63;
    const int wv   = tid >> 6;
    const int wr   = wv >> 1, wc = wv & 1;
    const int m0 = blockIdx.x * BM, n0 = blockIdx.y * BN;
    const int z  = blockIdx.z;
    const int zb = z >> 3, zh = z & 7;

    A  += (size_t)zb * sAb + (size_t)zh * sAh;
    Bw += (size_t)zb * sBb + (size_t)zh * sBh;
    C  += (size_t)zb * sCb + (size_t)zh * sCh;

    const int arow = tid / GR;
    const int acol = (tid % GR) * TC;

    const float* Abase = A  + (size_t)(m0 + arow) * lda + acol;
    const float* Bbase = Bw + (size_t)(n0 + arow) * ldb + acol;

    f32x4 pa[NV], pb[NV];
#pragma unroll
    for (int i = 0; i < NV; ++i) pa[i] = *(const f32x4*)(Abase + i * 4);
#pragma unroll
    for (int i = 0; i < NV; ++i) pb[i] = *(const f32x4*)(Bbase + i * 4);

    f32x4 acc[FM][FN];
#pragma unroll
    for (int i = 0; i < FM; ++i)
#pragma unroll
        for (int j = 0; j < FN; ++j) acc[i][j] = {0.f, 0.f, 0.f, 0.f};

    const int fk   = (lane >> 4) * 8;
    const int frow = lane & 15;
    short* awp = &As[arow * LDS_S + acol];
    short* bwp = &Bs[arow * LDS_S + acol];

    const int nt = K / BK;
    for (int t = 0; t < nt; ++t) {
#pragma unroll
        for (int i = 0; i < NV / 2; ++i)
            *(bf16x8*)(awp + i * 8) = cvt8(pa[2 * i], pa[2 * i + 1]);
#pragma unroll
        for (int i = 0; i < NV / 2; ++i)
            *(bf16x8*)(bwp + i * 8) = cvt8(pb[2 * i], pb[2 * i + 1]);
        __syncthreads();

        if (t + 1 < nt) {
            const float* An = Abase + (t + 1) * BK;
            const float* Bn = Bbase + (t + 1) * BK;
#pragma unroll
            for (int i = 0; i < NV; ++i) pa[i] = *(const f32x4*)(An + i * 4);
#pragma unroll
            for (int i = 0; i < NV; ++i) pb[i] = *(const f32x4*)(Bn + i * 4);
        }

        bf16x8 af[FM], bfr[FN];
#pragma unroll
        for (int i = 0; i < FM; ++i)
            af[i] = *(const bf16x8*)&As[(wr * WM + i * 16 + frow) * LDS_S + fk];
#pragma unroll
        for (int j = 0; j < FN; ++j)
            bfr[j] = *(const bf16x8*)&Bs[(wc * WN + j * 16 + frow) * LDS_S + fk];
#pragma unroll
        for (int i = 0; i < FM; ++i)
#pragma unroll
            for (int j = 0; j < FN; ++j)
                acc[i][j] = __builtin_amdgcn_mfma_f32_16x16x32_bf16(
                    af[i], bfr[j], acc[i][j], 0, 0, 0);
        __syncthreads();
    }

    const float* bmat = (MODE == 2) ? bias + (size_t)zb * Nn * Nn : nullptr;
#pragma unroll
    for (int i = 0; i < FM; ++i) {
#pragma unroll
        for (int j = 0; j < FN; ++j) {
            const int n = n0 + wc * WN + j * 16 + (lane & 15);
            float bv = 0.f;
            if constexpr (MODE == 0 || MODE == 1) bv = bias[n];
#pragma unroll
            for (int r = 0; r < 4; ++r) {
                const int m = m0 + wr * WM + i * 16 + (lane >> 4) * 4 + r;
                float v = acc[i][j][r];
                if constexpr (MODE == 0) v += bv;
                else if constexpr (MODE == 1) {
                    v += bv;
                    v = 0.5f * v * (1.f + erff(v * 0.70710678118654752f));
                } else if constexpr (MODE == 2) {
                    v = fmaf(v, 0.125f, bmat[(size_t)m * Nn + n]);
                }
                C[(size_t)m * ldc + n] = v;
            }
        }
    }
}

// ---------------- row softmax over k (row length 256), one wave per row
__global__ __launch_bounds__(64) void k_softmax(float* __restrict__ S) {
    const size_t row = blockIdx.x;
    float4* p = reinterpret_cast<float4*>(S + row * Nn) + threadIdx.x;
    float4 v = *p;
    float mx = fmaxf(fmaxf(v.x, v.y), fmaxf(v.z, v.w));
#pragma unroll
    for (int o = 32; o; o >>= 1) mx = fmaxf(mx, __shfl_xor(mx, o));
    float e0 = __expf(v.x - mx), e1 = __expf(v.y - mx);
    float e2 = __expf(v.z - mx), e3 = __expf(v.w - mx);
    float sum = (e0 + e1) + (e2 + e3);
#pragma unroll
    for (int o = 32; o; o >>= 1) sum += __shfl_xor(sum, o);
    float r = 1.f / sum;
    *p = make_float4(e0 * r, e1 * r, e2 * r, e3 * r);
}

// ---------------- residual add + LayerNorm (row = 512, block = 256)
__global__ __launch_bounds__(256) void k_addln(const float* __restrict__ xin,
                                               const float* __restrict__ y,
                                               const float* __restrict__ g,
                                               const float* __restrict__ bb,
                                               float* __restrict__ xout) {
    const int row = blockIdx.x;
    const int tid = threadIdx.x;
    const size_t base = (size_t)row * En;
    float v0 = xin[base + tid] + y[base + tid];
    float v1 = xin[base + tid + 256] + y[base + tid + 256];
    float s1 = v0 + v1;
    float s2 = v0 * v0 + v1 * v1;
#pragma unroll
    for (int o = 32; o; o >>= 1) {
        s1 += __shfl_xor(s1, o);
        s2 += __shfl_xor(s2, o);
    }
    __shared__ float ws1[4], ws2[4];
    int w = tid >> 6;
    if ((tid & 63) == 0) { ws1[w] = s1; ws2[w] = s2; }
    __syncthreads();
    s1 = (ws1[0] + ws1[1]) + (ws1[2] + ws1[3]);
    s2 = (ws2[0] + ws2[1]) + (ws2[2] + ws2[3]);
    const float rE = 1.f / (float)En;
    float mean = s1 * rE;
    float var = s2 * rE - mean * mean;
    float inv = rsqrtf(var + 1e-5f);
    xout[base + tid]       = (v0 - mean) * inv * g[tid] + bb[tid];
    xout[base + tid + 256] = (v1 - mean) * inv * g[tid + 256] + bb[tid + 256];
}

// ---------------- final: fp32 x ++ fp32 pad_mask
__global__ __launch_bounds__(256) void k_out(const float* __restrict__ x,
                                             const int* __restrict__ tok,
                                             float* __restrict__ out) {
    int i = blockIdx.x * 256 + threadIdx.x;
    const int total = Mn * En + Mn;
    if (i >= total) return;
    if (i < Mn * En) {
        out[i] = x[i];
    } else {
        int m = i - Mn * En;
        out[i] = (tok[m] == 0) ? 1.f : 0.f;
    }
}

// ---------------------------------------------------------------------------
extern "C" void kernel_launch(void* const* d_in, const int* in_sizes, int n_in,
                              void* d_out, int out_size, void* d_ws, size_t ws_size,
                              hipStream_t stream) {
    const int*   tok   = (const int*)  d_in[0];
    const float* dist  = (const float*)d_in[2];
    const float* emb   = (const float*)d_in[4];
    const float* dp_w1 = (const float*)d_in[5];
    const float* dp_b1 = (const float*)d_in[6];
    const float* dp_w2 = (const float*)d_in[7];
    const float* dp_b2 = (const float*)d_in[8];
    const float* Wqkv  = (const float*)d_in[9];
    const float* bqkv  = (const float*)d_in[10];
    const float* Wo    = (const float*)d_in[11];
    const float* bo    = (const float*)d_in[12];
    const float* ln1g  = (const float*)d_in[13];
    const float* ln1b  = (const float*)d_in[14];
    const float* W1    = (const float*)d_in[15];
    const float* b1    = (const float*)d_in[16];
    const float* W2    = (const float*)d_in[17];
    const float* b2    = (const float*)d_in[18];
    const float* ln2g  = (const float*)d_in[19];
    const float* ln2b  = (const float*)d_in[20];

    float* ws = (float*)d_ws;
    float* biasmat = ws;                         // 524288
    float* x       = biasmat + (size_t)Bn*Nn*Nn; // 1048576
    float* qkv     = x    + (size_t)Mn*En;       // 3145728
    float* Sff     = qkv  + (size_t)Mn*QKV_LD;   // 4194304 (scores / FF shared)
    float* attn    = Sff  + (size_t)Bn*Hn*Nn*Nn; // 1048576
    float* y       = attn + (size_t)Mn*En;       // 1048576 (Wo/FF2 out; vT scratch)
    float* lut     = y    + (size_t)Mn*En;       // 4097

    k_embed<<<Mn * En / 256, 256, 0, stream>>>(tok, emb, x);
    k_lutbuild<<<(LUT_N + 256) / 256, 256, 0, stream>>>(dp_w1, dp_b1, dp_w2, lut);
    k_distbias_lut<<<Bn * Nn * Nn / 256, 256, 0, stream>>>(dist, tok, lut, dp_b2,
                                                           biasmat);

    const long long sQKb = (long long)Nn * QKV_LD;   // per-b stride in qkv rows
    for (int l = 0; l < Ln; ++l) {
        const float* Wqkv_l = Wqkv + (size_t)l * 3 * En * En;
        const float* bqkv_l = bqkv + (size_t)l * 3 * En;
        const float* Wo_l   = Wo   + (size_t)l * En * En;
        const float* bo_l   = bo   + (size_t)l * En;
        const float* W1_l   = W1   + (size_t)l * FFn * En;
        const float* b1_l   = b1   + (size_t)l * FFn;
        const float* W2_l   = W2   + (size_t)l * En * FFn;
        const float* b2_l   = b2   + (size_t)l * En;

        // QKV projection: [2048,512] x [1536,512]^T -> [2048,1536]
        k_gemm_mfma<128, 128, 0><<<dim3(Mn / 128, QKV_LD / 128, 1), 256, 0, stream>>>(
            x, En, 0, 0, Wqkv_l, En, 0, 0, bqkv_l, qkv, QKV_LD, 0, 0, En);

        // V^T per head into y (dead during attention)
        k_vt<<<dim3(Nn / 64, Bn * Hn), 256, 0, stream>>>(qkv, y);

        // scores: S[bh][q][k] = 0.125*Q.K^T + biasmat[b][q][k]
        k_gemm_mfma<64, 64, 2><<<dim3(Nn / 64, Nn / 64, Bn * Hn), 256, 0, stream>>>(
            qkv, QKV_LD, sQKb, DHn,
            qkv + En, QKV_LD, sQKb, DHn,
            biasmat, Sff, Nn, (long long)Hn * Nn * Nn, (long long)Nn * Nn, DHn);

        k_softmax<<<Bn * Hn * Nn, 64, 0, stream>>>(Sff);

        // PV: attn[b*256+q][h*64+d] = sum_k P[bh][q][k] * vT[bh][d][k]
        k_gemm_mfma<64, 64, 3><<<dim3(Nn / 64, 1, Bn * Hn), 256, 0, stream>>>(
            Sff, Nn, (long long)Hn * Nn * Nn, (long long)Nn * Nn,
            y, Nn, (long long)Hn * DHn * Nn, (long long)DHn * Nn,
            nullptr, attn, En, (long long)Nn * En, (long long)DHn, Nn);

        // O projection: [2048,512] x [512,512]^T
        k_gemm_mfma<64, 64, 0><<<dim3(Mn / 64, En / 64, 1), 256, 0, stream>>>(
            attn, En, 0, 0, Wo_l, En, 0, 0, bo_l, y, En, 0, 0, En);
        k_addln<<<Mn, 256, 0, stream>>>(x, y, ln1g + (size_t)l * En,
                                        ln1b + (size_t)l * En, x);

        // FF1 + GELU: [2048,512] x [2048,512]^T -> [2048,2048]
        k_gemm_mfma<128, 128, 1><<<dim3(Mn / 128, FFn / 128, 1), 256, 0, stream>>>(
            x, En, 0, 0, W1_l, En, 0, 0, b1_l, Sff, FFn, 0, 0, En);

        // FF2: [2048,2048] x [512,2048]^T -> [2048,512]
        k_gemm_mfma<64, 64, 0><<<dim3(Mn / 64, En / 64, 1), 256, 0, stream>>>(
            Sff, FFn, 0, 0, W2_l, FFn, 0, 0, b2_l, y, En, 0, 0, FFn);
        k_addln<<<Mn, 256, 0, stream>>>(x, y, ln2g + (size_t)l * En,
                                        ln2b + (size_t)l * En, x);
    }

    k_out<<<(Mn * En + Mn + 255) / 256, 256, 0, stream>>>(x, tok, (float*)d_out);
}

// Round 9
// 503.372 us; speedup vs baseline: 5.0210x; 1.1037x over previous
//
#include <hip/hip_runtime.h>
#include <hip/hip_bf16.h>

// ---------------------------------------------------------------------------
// SimpleGeoFormerModel: 4-layer transformer encoder. FP32 in/out; bf16
// activations + bf16 MFMA GEMMs (fp32 accumulate) everywhere.
// B=8 N=256 E=512 V=512 L=4 H=8 FF=2048, dh=64.
// Round 9: bf16 activation buffers (x,qkv,attn,Sff), BK=128 for 64^2 tiles.
// ---------------------------------------------------------------------------

namespace {
constexpr int Bn  = 8;
constexpr int Nn  = 256;
constexpr int En  = 512;
constexpr int Ln  = 4;
constexpr int Hn  = 8;
constexpr int FFn = 2048;
constexpr int DHn = 64;
constexpr int Mn  = Bn * Nn;        // 2048 rows
constexpr int QKV_LD = 3 * En;      // 1536
constexpr int LUT_N = 4096;
}

typedef float f32x4 __attribute__((ext_vector_type(4)));
typedef short bf16x8 __attribute__((ext_vector_type(8)));

// fp32 -> bf16 round-to-nearest-even (finite inputs)
__device__ __forceinline__ unsigned short f2bs(float f) {
    union { float f; unsigned u; } v; v.f = f;
    unsigned r = v.u + 0x7FFFu + ((v.u >> 16) & 1u);
    return (unsigned short)(r >> 16);
}

__device__ __forceinline__ bf16x8 cvt8(f32x4 a, f32x4 b) {
    bf16x8 r;
    r[0] = (short)f2bs(a[0]); r[1] = (short)f2bs(a[1]);
    r[2] = (short)f2bs(a[2]); r[3] = (short)f2bs(a[3]);
    r[4] = (short)f2bs(b[0]); r[5] = (short)f2bs(b[1]);
    r[6] = (short)f2bs(b[2]); r[7] = (short)f2bs(b[3]);
    return r;
}

// ---------------- embedding gather (fp32 x + bf16 shadow) ----------------
__global__ __launch_bounds__(256) void k_embed(const int* __restrict__ tok,
                                               const float* __restrict__ emb,
                                               float* __restrict__ x,
                                               unsigned short* __restrict__ xb) {
    int i = blockIdx.x * 256 + threadIdx.x;
    int m = i >> 9;
    int e = i & 511;
    float v = emb[tok[m] * En + e];
    x[i] = v;
    xb[i] = f2bs(v);
}

// ---------------- LUT build: lut[i] = sum_e w2[e]*tanh(d_i*w1[e]+b1[e])
__global__ __launch_bounds__(256) void k_lutbuild(const float* __restrict__ w1,
                                                  const float* __restrict__ b1,
                                                  const float* __restrict__ w2,
                                                  float* __restrict__ lut) {
    __shared__ float sw1[En], sb1[En], sw2[En];
    for (int e = threadIdx.x; e < En; e += 256) {
        sw1[e] = w1[e]; sb1[e] = b1[e]; sw2[e] = w2[e];
    }
    __syncthreads();
    int i = blockIdx.x * 256 + threadIdx.x;
    if (i > LUT_N) return;
    float d = (float)i * (10.0f / (float)LUT_N);
    float acc = 0.f;
#pragma unroll 4
    for (int e = 0; e < En; ++e) {
        float s = fmaf(d, sw1[e], sb1[e]);
        float t = 1.f - 2.f / (__expf(2.f * s) + 1.f);
        acc = fmaf(t, sw2[e], acc);
    }
    lut[i] = acc;
}

// ---------------- distance bias via LUT ----------------
__global__ __launch_bounds__(256) void k_distbias_lut(const float* __restrict__ dist,
                                                      const int* __restrict__ tok,
                                                      const float* __restrict__ lut,
                                                      const float* __restrict__ b2,
                                                      float* __restrict__ biasmat) {
    int i = blockIdx.x * 256 + threadIdx.x;
    float d = dist[i];
    float idx = d * ((float)LUT_N / 10.0f);
    int ii = (int)idx;
    ii = ii < 0 ? 0 : (ii > LUT_N - 1 ? LUT_N - 1 : ii);
    float frac = idx - (float)ii;
    float v0 = lut[ii], v1 = lut[ii + 1];
    float acc = fmaf(v1 - v0, frac, v0) + b2[0];
    int k = i & (Nn - 1);
    int q = (i >> 8) & (Nn - 1);
    int b = i >> 16;
    bool pad = (tok[b * Nn + k] == 0) || (tok[b * Nn + q] == 0);
    biasmat[i] = pad ? -1e30f : acc;
}

// ---------------- V^T per head (bf16): vT[bh][d][k] = qkv[b*N+k][2E+h*64+d]
__global__ __launch_bounds__(256) void k_vt(const unsigned short* __restrict__ qkv,
                                            unsigned short* __restrict__ vT) {
    __shared__ unsigned short t[64][66];
    const int tid = threadIdx.x;
    const int bh = blockIdx.y, b = bh >> 3, h = bh & 7;
    const int k0 = blockIdx.x * 64;
    const unsigned short* src = qkv + ((size_t)(b * Nn + k0)) * QKV_LD + 2 * En + h * DHn;
    for (int idx = tid; idx < 64 * 64; idx += 256) {
        int r = idx >> 6, c = idx & 63;
        t[r][c] = src[(size_t)r * QKV_LD + c];
    }
    __syncthreads();
    unsigned short* dst = vT + ((size_t)bh * DHn) * Nn + k0;
    for (int idx = tid; idx < 64 * 64; idx += 256) {
        int d = idx >> 6, kk = idx & 63;
        dst[(size_t)d * Nn + kk] = t[kk][d];
    }
}

// ---------------- unified MFMA GEMM: C[m,n] = sum_k A[m,k]*B[n,k] (+epilogue)
// ABF/BBF/CBF: operand/output dtype is bf16 (else fp32). LDS always bf16.
// MODE 0: +bias[n]; 1: gelu(+bias[n]); 2: 0.125*acc + biasmat[b][m][n]; 3: none.
// Batched over blockIdx.z: zb = z>>3, zh = z&7 with per-operand strides (elems).
template <int BM, int BN, int BK, int MODE, int ABF, int BBF, int CBF>
__global__ __launch_bounds__(256) void k_gemm(
        const void* __restrict__ Ap, int lda, long long sAb, long long sAh,
        const void* __restrict__ Bp, int ldb, long long sBb, long long sBh,
        const float* __restrict__ bias,
        void* __restrict__ Cp, int ldc, long long sCb, long long sCh,
        int K) {
    static_assert(BM == BN, "square tiles only");
    constexpr int LDS_S = BK + 8;       // short stride; +8 keeps 16B align, 2-way banks
    constexpr int WM = BM / 2, WN = BN / 2;
    constexpr int FM = WM / 16, FN = WN / 16;
    constexpr int GR = 256 / BM;        // threads per staged row
    constexpr int TC = BK / GR;         // elements per thread per tile
    constexpr int ESA = ABF ? 2 : 4;
    constexpr int ESB = BBF ? 2 : 4;

    __shared__ short As[BM * LDS_S];
    __shared__ short Bs[BM * LDS_S];

    const int tid  = threadIdx.x;
    const int lane = tid & 63;
    const int wv   = tid >> 6;
    const int wr   = wv >> 1, wc = wv & 1;
    const int m0 = blockIdx.x * BM, n0 = blockIdx.y * BN;
    const int zb = blockIdx.z >> 3, zh = blockIdx.z & 7;

    const int arow = tid / GR;
    const int acol = (tid % GR) * TC;

    const char* Abase = (const char*)Ap +
        ((size_t)zb * sAb + (size_t)zh * sAh + (size_t)(m0 + arow) * lda + acol) * ESA;
    const char* Bbase = (const char*)Bp +
        ((size_t)zb * sBb + (size_t)zh * sBh + (size_t)(n0 + arow) * ldb + acol) * ESB;

    bf16x8 pab[ABF ? TC / 8 : 1];  f32x4 paf[ABF ? 1 : TC / 4];
    bf16x8 pbb[BBF ? TC / 8 : 1];  f32x4 pbf[BBF ? 1 : TC / 4];

    auto loadA = [&](int t) {
        const char* p = Abase + (size_t)t * BK * ESA;
        if constexpr (ABF) {
#pragma unroll
            for (int i = 0; i < TC / 8; ++i) pab[i] = *(const bf16x8*)(p + 16 * i);
        } else {
#pragma unroll
            for (int i = 0; i < TC / 4; ++i) paf[i] = *(const f32x4*)(p + 16 * i);
        }
    };
    auto loadB = [&](int t) {
        const char* p = Bbase + (size_t)t * BK * ESB;
        if constexpr (BBF) {
#pragma unroll
            for (int i = 0; i < TC / 8; ++i) pbb[i] = *(const bf16x8*)(p + 16 * i);
        } else {
#pragma unroll
            for (int i = 0; i < TC / 4; ++i) pbf[i] = *(const f32x4*)(p + 16 * i);
        }
    };

    f32x4 acc[FM][FN];
#pragma unroll
    for (int i = 0; i < FM; ++i)
#pragma unroll
        for (int j = 0; j < FN; ++j) acc[i][j] = {0.f, 0.f, 0.f, 0.f};

    loadA(0); loadB(0);

    const int fk   = (lane >> 4) * 8;
    const int frow = lane & 15;
    short* awp = &As[arow * LDS_S + acol];
    short* bwp = &Bs[arow * LDS_S + acol];

    const int nt = K / BK;
    for (int t = 0; t < nt; ++t) {
        if constexpr (ABF) {
#pragma unroll
            for (int i = 0; i < TC / 8; ++i) *(bf16x8*)(awp + i * 8) = pab[i];
        } else {
#pragma unroll
            for (int i = 0; i < TC / 8; ++i)
                *(bf16x8*)(awp + i * 8) = cvt8(paf[2 * i], paf[2 * i + 1]);
        }
        if constexpr (BBF) {
#pragma unroll
            for (int i = 0; i < TC / 8; ++i) *(bf16x8*)(bwp + i * 8) = pbb[i];
        } else {
#pragma unroll
            for (int i = 0; i < TC / 8; ++i)
                *(bf16x8*)(bwp + i * 8) = cvt8(pbf[2 * i], pbf[2 * i + 1]);
        }
        __syncthreads();

        if (t + 1 < nt) { loadA(t + 1); loadB(t + 1); }

#pragma unroll
        for (int ks = 0; ks < BK / 32; ++ks) {
            bf16x8 af[FM], bfr[FN];
#pragma unroll
            for (int i = 0; i < FM; ++i)
                af[i] = *(const bf16x8*)&As[(wr * WM + i * 16 + frow) * LDS_S + ks * 32 + fk];
#pragma unroll
            for (int j = 0; j < FN; ++j)
                bfr[j] = *(const bf16x8*)&Bs[(wc * WN + j * 16 + frow) * LDS_S + ks * 32 + fk];
#pragma unroll
            for (int i = 0; i < FM; ++i)
#pragma unroll
                for (int j = 0; j < FN; ++j)
                    acc[i][j] = __builtin_amdgcn_mfma_f32_16x16x32_bf16(
                        af[i], bfr[j], acc[i][j], 0, 0, 0);
        }
        __syncthreads();
    }

    char* Cc = (char*)Cp + ((size_t)zb * sCb + (size_t)zh * sCh) * (CBF ? 2 : 4);
    const float* bmat = (MODE == 2) ? bias + (size_t)zb * Nn * Nn : nullptr;
#pragma unroll
    for (int i = 0; i < FM; ++i) {
#pragma unroll
        for (int j = 0; j < FN; ++j) {
            const int n = n0 + wc * WN + j * 16 + (lane & 15);
            float bv = 0.f;
            if constexpr (MODE == 0 || MODE == 1) bv = bias[n];
#pragma unroll
            for (int r = 0; r < 4; ++r) {
                const int m = m0 + wr * WM + i * 16 + (lane >> 4) * 4 + r;
                float v = acc[i][j][r];
                if constexpr (MODE == 0) v += bv;
                else if constexpr (MODE == 1) {
                    v += bv;
                    v = 0.5f * v * (1.f + erff(v * 0.70710678118654752f));
                } else if constexpr (MODE == 2) {
                    v = fmaf(v, 0.125f, bmat[(size_t)m * Nn + n]);
                }
                if constexpr (CBF)
                    ((unsigned short*)Cc)[(size_t)m * ldc + n] = f2bs(v);
                else
                    ((float*)Cc)[(size_t)m * ldc + n] = v;
            }
        }
    }
}

// ---------------- row softmax over k (row length 256), one wave per row
__global__ __launch_bounds__(64) void k_softmax(float* __restrict__ S) {
    const size_t row = blockIdx.x;
    float4* p = reinterpret_cast<float4*>(S + row * Nn) + threadIdx.x;
    float4 v = *p;
    float mx = fmaxf(fmaxf(v.x, v.y), fmaxf(v.z, v.w));
#pragma unroll
    for (int o = 32; o; o >>= 1) mx = fmaxf(mx, __shfl_xor(mx, o));
    float e0 = __expf(v.x - mx), e1 = __expf(v.y - mx);
    float e2 = __expf(v.z - mx), e3 = __expf(v.w - mx);
    float sum = (e0 + e1) + (e2 + e3);
#pragma unroll
    for (int o = 32; o; o >>= 1) sum += __shfl_xor(sum, o);
    float r = 1.f / sum;
    *p = make_float4(e0 * r, e1 * r, e2 * r, e3 * r);
}

// ---------------- residual add + LayerNorm (row = 512, block = 256)
__global__ __launch_bounds__(256) void k_addln(const float* __restrict__ xin,
                                               const float* __restrict__ y,
                                               const float* __restrict__ g,
                                               const float* __restrict__ bb,
                                               float* __restrict__ xout,
                                               unsigned short* __restrict__ xbf) {
    const int row = blockIdx.x;
    const int tid = threadIdx.x;
    const size_t base = (size_t)row * En;
    float v0 = xin[base + tid] + y[base + tid];
    float v1 = xin[base + tid + 256] + y[base + tid + 256];
    float s1 = v0 + v1;
    float s2 = v0 * v0 + v1 * v1;
#pragma unroll
    for (int o = 32; o; o >>= 1) {
        s1 += __shfl_xor(s1, o);
        s2 += __shfl_xor(s2, o);
    }
    __shared__ float ws1[4], ws2[4];
    int w = tid >> 6;
    if ((tid & 63) == 0) { ws1[w] = s1; ws2[w] = s2; }
    __syncthreads();
    s1 = (ws1[0] + ws1[1]) + (ws1[2] + ws1[3]);
    s2 = (ws2[0] + ws2[1]) + (ws2[2] + ws2[3]);
    const float rE = 1.f / (float)En;
    float mean = s1 * rE;
    float var = s2 * rE - mean * mean;
    float inv = rsqrtf(var + 1e-5f);
    float o0 = (v0 - mean) * inv * g[tid] + bb[tid];
    float o1 = (v1 - mean) * inv * g[tid + 256] + bb[tid + 256];
    xout[base + tid]       = o0;
    xout[base + tid + 256] = o1;
    xbf[base + tid]        = f2bs(o0);
    xbf[base + tid + 256]  = f2bs(o1);
}

// ---------------- final: fp32 x ++ fp32 pad_mask
__global__ __launch_bounds__(256) void k_out(const float* __restrict__ x,
                                             const int* __restrict__ tok,
                                             float* __restrict__ out) {
    int i = blockIdx.x * 256 + threadIdx.x;
    const int total = Mn * En + Mn;
    if (i >= total) return;
    if (i < Mn * En) {
        out[i] = x[i];
    } else {
        int m = i - Mn * En;
        out[i] = (tok[m] == 0) ? 1.f : 0.f;
    }
}

// ---------------------------------------------------------------------------
extern "C" void kernel_launch(void* const* d_in, const int* in_sizes, int n_in,
                              void* d_out, int out_size, void* d_ws, size_t ws_size,
                              hipStream_t stream) {
    const int*   tok   = (const int*)  d_in[0];
    const float* dist  = (const float*)d_in[2];
    const float* emb   = (const float*)d_in[4];
    const float* dp_w1 = (const float*)d_in[5];
    const float* dp_b1 = (const float*)d_in[6];
    const float* dp_w2 = (const float*)d_in[7];
    const float* dp_b2 = (const float*)d_in[8];
    const float* Wqkv  = (const float*)d_in[9];
    const float* bqkv  = (const float*)d_in[10];
    const float* Wo    = (const float*)d_in[11];
    const float* bo    = (const float*)d_in[12];
    const float* ln1g  = (const float*)d_in[13];
    const float* ln1b  = (const float*)d_in[14];
    const float* W1    = (const float*)d_in[15];
    const float* b1    = (const float*)d_in[16];
    const float* W2    = (const float*)d_in[17];
    const float* b2    = (const float*)d_in[18];
    const float* ln2g  = (const float*)d_in[19];
    const float* ln2b  = (const float*)d_in[20];

    // workspace layout (bytes; total ~36 MB, < proven 44 MB)
    char* p = (char*)d_ws;
    float*          biasmat = (float*)p;          p += (size_t)Bn*Nn*Nn*4;   // 2 MB
    float*          x       = (float*)p;          p += (size_t)Mn*En*4;      // 4 MB
    unsigned short* xb      = (unsigned short*)p; p += (size_t)Mn*En*2;      // 2 MB
    unsigned short* qkvb    = (unsigned short*)p; p += (size_t)Mn*QKV_LD*2;  // 6 MB
    float*          Sff     = (float*)p;          p += (size_t)Bn*Hn*Nn*Nn*4;// 16 MB (fp32 S / bf16 FF)
    unsigned short* attnb   = (unsigned short*)p; p += (size_t)Mn*En*2;      // 2 MB
    float*          y       = (float*)p;          p += (size_t)Mn*En*4;      // 4 MB (also vT bf16)
    float*          lut     = (float*)p;
    unsigned short* Sffb = (unsigned short*)Sff;
    unsigned short* vTb  = (unsigned short*)y;

    k_embed<<<Mn * En / 256, 256, 0, stream>>>(tok, emb, x, xb);
    k_lutbuild<<<(LUT_N + 256) / 256, 256, 0, stream>>>(dp_w1, dp_b1, dp_w2, lut);
    k_distbias_lut<<<Bn * Nn * Nn / 256, 256, 0, stream>>>(dist, tok, lut, dp_b2,
                                                           biasmat);

    const long long sQKb = (long long)Nn * QKV_LD;
    for (int l = 0; l < Ln; ++l) {
        const float* Wqkv_l = Wqkv + (size_t)l * 3 * En * En;
        const float* bqkv_l = bqkv + (size_t)l * 3 * En;
        const float* Wo_l   = Wo   + (size_t)l * En * En;
        const float* bo_l   = bo   + (size_t)l * En;
        const float* W1_l   = W1   + (size_t)l * FFn * En;
        const float* b1_l   = b1   + (size_t)l * FFn;
        const float* W2_l   = W2   + (size_t)l * En * FFn;
        const float* b2_l   = b2   + (size_t)l * En;

        // QKV: [2048,512]bf16 x [1536,512]^T fp32 -> [2048,1536]bf16
        k_gemm<128, 128, 64, 0, 1, 0, 1>
            <<<dim3(Mn / 128, QKV_LD / 128, 1), 256, 0, stream>>>(
            xb, En, 0, 0, Wqkv_l, En, 0, 0, bqkv_l, qkvb, QKV_LD, 0, 0, En);

        // V^T per head (bf16) into y
        k_vt<<<dim3(Nn / 64, Bn * Hn), 256, 0, stream>>>(qkvb, vTb);

        // scores: S = 0.125*Q.K^T + biasmat  (bf16 x bf16 -> fp32)
        k_gemm<64, 64, 64, 2, 1, 1, 0>
            <<<dim3(Nn / 64, Nn / 64, Bn * Hn), 256, 0, stream>>>(
            qkvb, QKV_LD, sQKb, DHn,
            qkvb + En, QKV_LD, sQKb, DHn,
            biasmat, Sff, Nn, (long long)Hn * Nn * Nn, (long long)Nn * Nn, DHn);

        k_softmax<<<Bn * Hn * Nn, 64, 0, stream>>>(Sff);

        // PV: attn = P(fp32) x vT(bf16)^T -> bf16
        k_gemm<64, 64, 128, 3, 0, 1, 1>
            <<<dim3(Nn / 64, 1, Bn * Hn), 256, 0, stream>>>(
            Sff, Nn, (long long)Hn * Nn * Nn, (long long)Nn * Nn,
            vTb, Nn, (long long)Hn * DHn * Nn, (long long)DHn * Nn,
            nullptr, attnb, En, (long long)Nn * En, (long long)DHn, Nn);

        // O projection: [2048,512]bf16 x [512,512]^T fp32 -> fp32 y
        k_gemm<64, 64, 128, 0, 1, 0, 0>
            <<<dim3(Mn / 64, En / 64, 1), 256, 0, stream>>>(
            attnb, En, 0, 0, Wo_l, En, 0, 0, bo_l, y, En, 0, 0, En);
        k_addln<<<Mn, 256, 0, stream>>>(x, y, ln1g + (size_t)l * En,
                                        ln1b + (size_t)l * En, x, xb);

        // FF1 + GELU: [2048,512]bf16 x [2048,512]^T fp32 -> [2048,2048]bf16
        k_gemm<128, 128, 64, 1, 1, 0, 1>
            <<<dim3(Mn / 128, FFn / 128, 1), 256, 0, stream>>>(
            xb, En, 0, 0, W1_l, En, 0, 0, b1_l, Sffb, FFn, 0, 0, En);

        // FF2: [2048,2048]bf16 x [512,2048]^T fp32 -> fp32 y
        k_gemm<64, 64, 128, 0, 1, 0, 0>
            <<<dim3(Mn / 64, En / 64, 1), 256, 0, stream>>>(
            Sffb, FFn, 0, 0, W2_l, FFn, 0, 0, b2_l, y, En, 0, 0, FFn);
        k_addln<<<Mn, 256, 0, stream>>>(x, y, ln2g + (size_t)l * En,
                                        ln2b + (size_t)l * En, x, xb);
    }

    k_out<<<(Mn * En + Mn + 255) / 256, 256, 0, stream>>>(x, tok, (float*)d_out);
}

// Round 10
// 464.728 us; speedup vs baseline: 5.4385x; 1.0832x over previous
//
#include <hip/hip_runtime.h>
#include <hip/hip_bf16.h>

// ---------------------------------------------------------------------------
// SimpleGeoFormerModel: 4-layer transformer encoder. FP32 in/out; bf16
// activations + bf16 MFMA GEMMs (fp32 accumulate) everywhere.
// B=8 N=256 E=512 V=512 L=4 H=8 FF=2048, dh=64.
// Round 10: fused attention kernel (QK^T+bias -> softmax -> PV) per (bh,q64).
// ---------------------------------------------------------------------------

namespace {
constexpr int Bn  = 8;
constexpr int Nn  = 256;
constexpr int En  = 512;
constexpr int Ln  = 4;
constexpr int Hn  = 8;
constexpr int FFn = 2048;
constexpr int DHn = 64;
constexpr int Mn  = Bn * Nn;        // 2048 rows
constexpr int QKV_LD = 3 * En;      // 1536
constexpr int LUT_N = 4096;
}

typedef float f32x4 __attribute__((ext_vector_type(4)));
typedef short bf16x8 __attribute__((ext_vector_type(8)));

// fp32 -> bf16 round-to-nearest-even (finite inputs)
__device__ __forceinline__ unsigned short f2bs(float f) {
    union { float f; unsigned u; } v; v.f = f;
    unsigned r = v.u + 0x7FFFu + ((v.u >> 16) & 1u);
    return (unsigned short)(r >> 16);
}
__device__ __forceinline__ float bf2f(short s) {
    union { unsigned u; float f; } v;
    v.u = ((unsigned)(unsigned short)s) << 16;
    return v.f;
}

__device__ __forceinline__ bf16x8 cvt8(f32x4 a, f32x4 b) {
    bf16x8 r;
    r[0] = (short)f2bs(a[0]); r[1] = (short)f2bs(a[1]);
    r[2] = (short)f2bs(a[2]); r[3] = (short)f2bs(a[3]);
    r[4] = (short)f2bs(b[0]); r[5] = (short)f2bs(b[1]);
    r[6] = (short)f2bs(b[2]); r[7] = (short)f2bs(b[3]);
    return r;
}

// swizzled byte address within a row-major bf16 LDS tile (16B-unit XOR)
__device__ __forceinline__ int swz(int row, int byte_in_row, int stride_b) {
    return row * stride_b + (byte_in_row ^ ((row & 7) << 4));
}

// ---------------- embedding gather (fp32 x + bf16 shadow) ----------------
__global__ __launch_bounds__(256) void k_embed(const int* __restrict__ tok,
                                               const float* __restrict__ emb,
                                               float* __restrict__ x,
                                               unsigned short* __restrict__ xb) {
    int i = blockIdx.x * 256 + threadIdx.x;
    int m = i >> 9;
    int e = i & 511;
    float v = emb[tok[m] * En + e];
    x[i] = v;
    xb[i] = f2bs(v);
}

// ---------------- LUT build ----------------
__global__ __launch_bounds__(256) void k_lutbuild(const float* __restrict__ w1,
                                                  const float* __restrict__ b1,
                                                  const float* __restrict__ w2,
                                                  float* __restrict__ lut) {
    __shared__ float sw1[En], sb1[En], sw2[En];
    for (int e = threadIdx.x; e < En; e += 256) {
        sw1[e] = w1[e]; sb1[e] = b1[e]; sw2[e] = w2[e];
    }
    __syncthreads();
    int i = blockIdx.x * 256 + threadIdx.x;
    if (i > LUT_N) return;
    float d = (float)i * (10.0f / (float)LUT_N);
    float acc = 0.f;
#pragma unroll 4
    for (int e = 0; e < En; ++e) {
        float s = fmaf(d, sw1[e], sb1[e]);
        float t = 1.f - 2.f / (__expf(2.f * s) + 1.f);
        acc = fmaf(t, sw2[e], acc);
    }
    lut[i] = acc;
}

// ---------------- distance bias via LUT ----------------
__global__ __launch_bounds__(256) void k_distbias_lut(const float* __restrict__ dist,
                                                      const int* __restrict__ tok,
                                                      const float* __restrict__ lut,
                                                      const float* __restrict__ b2,
                                                      float* __restrict__ biasmat) {
    int i = blockIdx.x * 256 + threadIdx.x;
    float d = dist[i];
    float idx = d * ((float)LUT_N / 10.0f);
    int ii = (int)idx;
    ii = ii < 0 ? 0 : (ii > LUT_N - 1 ? LUT_N - 1 : ii);
    float frac = idx - (float)ii;
    float v0 = lut[ii], v1 = lut[ii + 1];
    float acc = fmaf(v1 - v0, frac, v0) + b2[0];
    int k = i & (Nn - 1);
    int q = (i >> 8) & (Nn - 1);
    int b = i >> 16;
    bool pad = (tok[b * Nn + k] == 0) || (tok[b * Nn + q] == 0);
    biasmat[i] = pad ? -1e30f : acc;
}

// ---------------- V^T per head (bf16): vT[bh][d][k] ----------------
__global__ __launch_bounds__(256) void k_vt(const unsigned short* __restrict__ qkv,
                                            unsigned short* __restrict__ vT) {
    __shared__ unsigned short t[64][66];
    const int tid = threadIdx.x;
    const int bh = blockIdx.y, b = bh >> 3, h = bh & 7;
    const int k0 = blockIdx.x * 64;
    const unsigned short* src = qkv + ((size_t)(b * Nn + k0)) * QKV_LD + 2 * En + h * DHn;
    for (int idx = tid; idx < 64 * 64; idx += 256) {
        int r = idx >> 6, c = idx & 63;
        t[r][c] = src[(size_t)r * QKV_LD + c];
    }
    __syncthreads();
    unsigned short* dst = vT + ((size_t)bh * DHn) * Nn + k0;
    for (int idx = tid; idx < 64 * 64; idx += 256) {
        int d = idx >> 6, kk = idx & 63;
        dst[(size_t)d * Nn + kk] = t[kk][d];
    }
}

// ---------------- fused attention: per (q-tile 64, bh) block -----------------
// S = 0.125*Q.K^T + bias (MFMA, bias as C-init); in-register softmax;
// P->bf16 LDS; PV MFMA; bf16 out. 4 waves x 16 q-rows each.
__global__ __launch_bounds__(256, 1) void k_attn(
        const unsigned short* __restrict__ qkvb,
        const unsigned short* __restrict__ vTb,
        const float* __restrict__ biasmat,
        unsigned short* __restrict__ attnb) {
    __shared__ short Qs[64 * 64];     // [q][d] bf16, stride 128B, swizzled
    __shared__ short Ks[256 * 64];    // [k][d] bf16, stride 128B, swizzled
    __shared__ short Vs[64 * 256];    // [d][k] bf16 (V^T), stride 512B, swizzled
    __shared__ short Ps[64 * 256];    // [q][k] bf16, stride 512B, swizzled

    const int tid = threadIdx.x;
    const int lane = tid & 63;
    const int wv = tid >> 6;
    const int q0 = blockIdx.x * 64;
    const int bh = blockIdx.y;
    const int b = bh >> 3, h = bh & 7;

    const unsigned short* Qg = qkvb + ((size_t)(b * Nn + q0)) * QKV_LD + h * DHn;
    const unsigned short* Kg = qkvb + ((size_t)(b * Nn)) * QKV_LD + En + h * DHn;
    const unsigned short* Vg = vTb + (size_t)bh * DHn * Nn;

    // ---- stage K: 256 rows x 128B; thread -> one row
    {
        const char* src = (const char*)(Kg + (size_t)tid * QKV_LD);
#pragma unroll
        for (int c = 0; c < 8; ++c)
            *(bf16x8*)((char*)Ks + swz(tid, c * 16, 128)) =
                *(const bf16x8*)(src + c * 16);
    }
    // ---- stage V^T: 64 rows x 512B; thread -> quarter row
    {
        int d = tid >> 2;
        int cb = (tid & 3) * 128;
        const char* src = (const char*)(Vg + (size_t)d * Nn) + cb;
#pragma unroll
        for (int c = 0; c < 8; ++c)
            *(bf16x8*)((char*)Vs + swz(d, cb + c * 16, 512)) =
                *(const bf16x8*)(src + c * 16);
    }
    // ---- stage Q scaled by 0.125 (exact): 64 rows x 128B; thread -> 2 chunks
    {
        int r = tid & 63;
        const char* src = (const char*)(Qg + (size_t)r * QKV_LD);
#pragma unroll
        for (int i = 0; i < 2; ++i) {
            int cb = ((tid >> 6) * 2 + i) * 16;
            bf16x8 v = *(const bf16x8*)(src + cb);
            bf16x8 o;
#pragma unroll
            for (int j = 0; j < 8; ++j) o[j] = (short)f2bs(bf2f(v[j]) * 0.125f);
            *(bf16x8*)((char*)Qs + swz(r, cb, 128)) = o;
        }
    }

    // ---- bias preload into accumulator (C-init), overlaps staging
    const int qw = wv * 16;          // wave's q base within the 64-row tile
    const int g  = lane >> 4;        // 4-row group
    const int c  = lane & 15;        // col within frag
    f32x4 acc[16];
    {
        const float* bb = biasmat + ((size_t)b * Nn + (q0 + qw + g * 4)) * Nn;
#pragma unroll
        for (int f = 0; f < 16; ++f)
#pragma unroll
            for (int r = 0; r < 4; ++r)
                acc[f][r] = bb[(size_t)r * Nn + f * 16 + c];
    }

    __syncthreads();

    // ---- S = 0.125*Q.K^T + bias
    bf16x8 qa[2];
#pragma unroll
    for (int ks = 0; ks < 2; ++ks)
        qa[ks] = *(const bf16x8*)((const char*)Qs + swz(qw + c, ks * 64 + g * 16, 128));
#pragma unroll
    for (int f = 0; f < 16; ++f) {
#pragma unroll
        for (int ks = 0; ks < 2; ++ks) {
            bf16x8 kb = *(const bf16x8*)((const char*)Ks +
                         swz(f * 16 + c, ks * 64 + g * 16, 128));
            acc[f] = __builtin_amdgcn_mfma_f32_16x16x32_bf16(qa[ks], kb, acc[f], 0, 0, 0);
        }
    }

    // ---- in-register softmax: 16-lane group (fixed g) owns each row
    float rcp[4];
#pragma unroll
    for (int r = 0; r < 4; ++r) {
        float m = acc[0][r];
#pragma unroll
        for (int f = 1; f < 16; ++f) m = fmaxf(m, acc[f][r]);
#pragma unroll
        for (int o = 1; o < 16; o <<= 1) m = fmaxf(m, __shfl_xor(m, o));
        float s = 0.f;
#pragma unroll
        for (int f = 0; f < 16; ++f) {
            float e = __expf(acc[f][r] - m);
            acc[f][r] = e;
            s += e;
        }
#pragma unroll
        for (int o = 1; o < 16; o <<= 1) s += __shfl_xor(s, o);
        rcp[r] = 1.f / s;
    }

    // ---- P -> bf16 LDS (each wave writes only its own 16 rows)
#pragma unroll
    for (int f = 0; f < 16; ++f)
#pragma unroll
        for (int r = 0; r < 4; ++r) {
            int q = qw + g * 4 + r;
            int kx = f * 16 + c;
            *(unsigned short*)((char*)Ps + (q * 512 + ((kx * 2) ^ ((q & 7) << 4)))) =
                f2bs(acc[f][r] * rcp[r]);
        }

    // ---- PV: attn[q][d] = sum_k P[q,k] * V^T[d,k]  (reads own rows only)
    f32x4 acc2[4];
#pragma unroll
    for (int fd = 0; fd < 4; ++fd) acc2[fd] = {0.f, 0.f, 0.f, 0.f};
#pragma unroll
    for (int ks2 = 0; ks2 < 8; ++ks2) {
        bf16x8 pa = *(const bf16x8*)((const char*)Ps +
                      swz(qw + c, ks2 * 64 + g * 16, 512));
#pragma unroll
        for (int fd = 0; fd < 4; ++fd) {
            bf16x8 vb = *(const bf16x8*)((const char*)Vs +
                          swz(fd * 16 + c, ks2 * 64 + g * 16, 512));
            acc2[fd] = __builtin_amdgcn_mfma_f32_16x16x32_bf16(pa, vb, acc2[fd], 0, 0, 0);
        }
    }

    // ---- epilogue: bf16 store
    unsigned short* Cg = attnb + ((size_t)(b * Nn + q0 + qw)) * En + h * DHn;
#pragma unroll
    for (int fd = 0; fd < 4; ++fd)
#pragma unroll
        for (int r = 0; r < 4; ++r)
            Cg[(size_t)(g * 4 + r) * En + fd * 16 + c] = f2bs(acc2[fd][r]);
}

// ---------------- unified MFMA GEMM (see round 9) ----------------
template <int BM, int BN, int BK, int MODE, int ABF, int BBF, int CBF>
__global__ __launch_bounds__(256) void k_gemm(
        const void* __restrict__ Ap, int lda,
        const void* __restrict__ Bp, int ldb,
        const float* __restrict__ bias,
        void* __restrict__ Cp, int ldc,
        int K) {
    static_assert(BM == BN, "square tiles only");
    constexpr int LDS_S = BK + 8;
    constexpr int WM = BM / 2, WN = BN / 2;
    constexpr int FM = WM / 16, FN = WN / 16;
    constexpr int GR = 256 / BM;
    constexpr int TC = BK / GR;
    constexpr int ESA = ABF ? 2 : 4;
    constexpr int ESB = BBF ? 2 : 4;

    __shared__ short As[BM * LDS_S];
    __shared__ short Bs[BM * LDS_S];

    const int tid  = threadIdx.x;
    const int lane = tid & 63;
    const int wv   = tid >> 6;
    const int wr   = wv >> 1, wc = wv & 1;
    const int m0 = blockIdx.x * BM, n0 = blockIdx.y * BN;

    const int arow = tid / GR;
    const int acol = (tid % GR) * TC;

    const char* Abase = (const char*)Ap + ((size_t)(m0 + arow) * lda + acol) * ESA;
    const char* Bbase = (const char*)Bp + ((size_t)(n0 + arow) * ldb + acol) * ESB;

    bf16x8 pab[ABF ? TC / 8 : 1];  f32x4 paf[ABF ? 1 : TC / 4];
    bf16x8 pbb[BBF ? TC / 8 : 1];  f32x4 pbf[BBF ? 1 : TC / 4];

    auto loadA = [&](int t) {
        const char* p = Abase + (size_t)t * BK * ESA;
        if constexpr (ABF) {
#pragma unroll
            for (int i = 0; i < TC / 8; ++i) pab[i] = *(const bf16x8*)(p + 16 * i);
        } else {
#pragma unroll
            for (int i = 0; i < TC / 4; ++i) paf[i] = *(const f32x4*)(p + 16 * i);
        }
    };
    auto loadB = [&](int t) {
        const char* p = Bbase + (size_t)t * BK * ESB;
        if constexpr (BBF) {
#pragma unroll
            for (int i = 0; i < TC / 8; ++i) pbb[i] = *(const bf16x8*)(p + 16 * i);
        } else {
#pragma unroll
            for (int i = 0; i < TC / 4; ++i) pbf[i] = *(const f32x4*)(p + 16 * i);
        }
    };

    f32x4 acc[FM][FN];
#pragma unroll
    for (int i = 0; i < FM; ++i)
#pragma unroll
        for (int j = 0; j < FN; ++j) acc[i][j] = {0.f, 0.f, 0.f, 0.f};

    loadA(0); loadB(0);

    const int fk   = (lane >> 4) * 8;
    const int frow = lane & 15;
    short* awp = &As[arow * LDS_S + acol];
    short* bwp = &Bs[arow * LDS_S + acol];

    const int nt = K / BK;
    for (int t = 0; t < nt; ++t) {
        if constexpr (ABF) {
#pragma unroll
            for (int i = 0; i < TC / 8; ++i) *(bf16x8*)(awp + i * 8) = pab[i];
        } else {
#pragma unroll
            for (int i = 0; i < TC / 8; ++i)
                *(bf16x8*)(awp + i * 8) = cvt8(paf[2 * i], paf[2 * i + 1]);
        }
        if constexpr (BBF) {
#pragma unroll
            for (int i = 0; i < TC / 8; ++i) *(bf16x8*)(bwp + i * 8) = pbb[i];
        } else {
#pragma unroll
            for (int i = 0; i < TC / 8; ++i)
                *(bf16x8*)(bwp + i * 8) = cvt8(pbf[2 * i], pbf[2 * i + 1]);
        }
        __syncthreads();

        if (t + 1 < nt) { loadA(t + 1); loadB(t + 1); }

#pragma unroll
        for (int ks = 0; ks < BK / 32; ++ks) {
            bf16x8 af[FM], bfr[FN];
#pragma unroll
            for (int i = 0; i < FM; ++i)
                af[i] = *(const bf16x8*)&As[(wr * WM + i * 16 + frow) * LDS_S + ks * 32 + fk];
#pragma unroll
            for (int j = 0; j < FN; ++j)
                bfr[j] = *(const bf16x8*)&Bs[(wc * WN + j * 16 + frow) * LDS_S + ks * 32 + fk];
#pragma unroll
            for (int i = 0; i < FM; ++i)
#pragma unroll
                for (int j = 0; j < FN; ++j)
                    acc[i][j] = __builtin_amdgcn_mfma_f32_16x16x32_bf16(
                        af[i], bfr[j], acc[i][j], 0, 0, 0);
        }
        __syncthreads();
    }

#pragma unroll
    for (int i = 0; i < FM; ++i) {
#pragma unroll
        for (int j = 0; j < FN; ++j) {
            const int n = n0 + wc * WN + j * 16 + (lane & 15);
            float bv = bias ? bias[n] : 0.f;
#pragma unroll
            for (int r = 0; r < 4; ++r) {
                const int m = m0 + wr * WM + i * 16 + (lane >> 4) * 4 + r;
                float v = acc[i][j][r] + bv;
                if constexpr (MODE == 1)
                    v = 0.5f * v * (1.f + erff(v * 0.70710678118654752f));
                if constexpr (CBF)
                    ((unsigned short*)Cp)[(size_t)m * ldc + n] = f2bs(v);
                else
                    ((float*)Cp)[(size_t)m * ldc + n] = v;
            }
        }
    }
}

// ---------------- residual add + LayerNorm ----------------
__global__ __launch_bounds__(256) void k_addln(const float* __restrict__ xin,
                                               const float* __restrict__ y,
                                               const float* __restrict__ g,
                                               const float* __restrict__ bb,
                                               float* __restrict__ xout,
                                               unsigned short* __restrict__ xbf) {
    const int row = blockIdx.x;
    const int tid = threadIdx.x;
    const size_t base = (size_t)row * En;
    float v0 = xin[base + tid] + y[base + tid];
    float v1 = xin[base + tid + 256] + y[base + tid + 256];
    float s1 = v0 + v1;
    float s2 = v0 * v0 + v1 * v1;
#pragma unroll
    for (int o = 32; o; o >>= 1) {
        s1 += __shfl_xor(s1, o);
        s2 += __shfl_xor(s2, o);
    }
    __shared__ float ws1[4], ws2[4];
    int w = tid >> 6;
    if ((tid & 63) == 0) { ws1[w] = s1; ws2[w] = s2; }
    __syncthreads();
    s1 = (ws1[0] + ws1[1]) + (ws1[2] + ws1[3]);
    s2 = (ws2[0] + ws2[1]) + (ws2[2] + ws2[3]);
    const float rE = 1.f / (float)En;
    float mean = s1 * rE;
    float var = s2 * rE - mean * mean;
    float inv = rsqrtf(var + 1e-5f);
    float o0 = (v0 - mean) * inv * g[tid] + bb[tid];
    float o1 = (v1 - mean) * inv * g[tid + 256] + bb[tid + 256];
    xout[base + tid]       = o0;
    xout[base + tid + 256] = o1;
    xbf[base + tid]        = f2bs(o0);
    xbf[base + tid + 256]  = f2bs(o1);
}

// ---------------- final: fp32 x ++ fp32 pad_mask ----------------
__global__ __launch_bounds__(256) void k_out(const float* __restrict__ x,
                                             const int* __restrict__ tok,
                                             float* __restrict__ out) {
    int i = blockIdx.x * 256 + threadIdx.x;
    const int total = Mn * En + Mn;
    if (i >= total) return;
    if (i < Mn * En) {
        out[i] = x[i];
    } else {
        int m = i - Mn * En;
        out[i] = (tok[m] == 0) ? 1.f : 0.f;
    }
}

// ---------------------------------------------------------------------------
extern "C" void kernel_launch(void* const* d_in, const int* in_sizes, int n_in,
                              void* d_out, int out_size, void* d_ws, size_t ws_size,
                              hipStream_t stream) {
    const int*   tok   = (const int*)  d_in[0];
    const float* dist  = (const float*)d_in[2];
    const float* emb   = (const float*)d_in[4];
    const float* dp_w1 = (const float*)d_in[5];
    const float* dp_b1 = (const float*)d_in[6];
    const float* dp_w2 = (const float*)d_in[7];
    const float* dp_b2 = (const float*)d_in[8];
    const float* Wqkv  = (const float*)d_in[9];
    const float* bqkv  = (const float*)d_in[10];
    const float* Wo    = (const float*)d_in[11];
    const float* bo    = (const float*)d_in[12];
    const float* ln1g  = (const float*)d_in[13];
    const float* ln1b  = (const float*)d_in[14];
    const float* W1    = (const float*)d_in[15];
    const float* b1    = (const float*)d_in[16];
    const float* W2    = (const float*)d_in[17];
    const float* b2    = (const float*)d_in[18];
    const float* ln2g  = (const float*)d_in[19];
    const float* ln2b  = (const float*)d_in[20];

    char* p = (char*)d_ws;
    float*          biasmat = (float*)p;          p += (size_t)Bn*Nn*Nn*4;   // 2 MB
    float*          x       = (float*)p;          p += (size_t)Mn*En*4;      // 4 MB
    unsigned short* xb      = (unsigned short*)p; p += (size_t)Mn*En*2;      // 2 MB
    unsigned short* qkvb    = (unsigned short*)p; p += (size_t)Mn*QKV_LD*2;  // 6 MB
    unsigned short* Sffb    = (unsigned short*)p; p += (size_t)Mn*FFn*2;     // 8 MB
    unsigned short* attnb   = (unsigned short*)p; p += (size_t)Mn*En*2;      // 2 MB
    float*          y       = (float*)p;          p += (size_t)Mn*En*4;      // 4 MB
    float*          lut     = (float*)p;
    unsigned short* vTb  = (unsigned short*)y;    // y dead during attention

    k_embed<<<Mn * En / 256, 256, 0, stream>>>(tok, emb, x, xb);
    k_lutbuild<<<(LUT_N + 256) / 256, 256, 0, stream>>>(dp_w1, dp_b1, dp_w2, lut);
    k_distbias_lut<<<Bn * Nn * Nn / 256, 256, 0, stream>>>(dist, tok, lut, dp_b2,
                                                           biasmat);

    for (int l = 0; l < Ln; ++l) {
        const float* Wqkv_l = Wqkv + (size_t)l * 3 * En * En;
        const float* bqkv_l = bqkv + (size_t)l * 3 * En;
        const float* Wo_l   = Wo   + (size_t)l * En * En;
        const float* bo_l   = bo   + (size_t)l * En;
        const float* W1_l   = W1   + (size_t)l * FFn * En;
        const float* b1_l   = b1   + (size_t)l * FFn;
        const float* W2_l   = W2   + (size_t)l * En * FFn;
        const float* b2_l   = b2   + (size_t)l * En;

        // QKV: [2048,512]bf16 x [1536,512]^T fp32 -> [2048,1536]bf16
        k_gemm<128, 128, 64, 0, 1, 0, 1>
            <<<dim3(Mn / 128, QKV_LD / 128), 256, 0, stream>>>(
            xb, En, Wqkv_l, En, bqkv_l, qkvb, QKV_LD, En);

        // V^T per head (bf16) into y region
        k_vt<<<dim3(Nn / 64, Bn * Hn), 256, 0, stream>>>(qkvb, vTb);

        // fused attention -> attnb
        k_attn<<<dim3(Nn / 64, Bn * Hn), 256, 0, stream>>>(qkvb, vTb, biasmat, attnb);

        // O projection: [2048,512]bf16 x [512,512]^T fp32 -> fp32 y
        k_gemm<64, 64, 128, 0, 1, 0, 0>
            <<<dim3(Mn / 64, En / 64), 256, 0, stream>>>(
            attnb, En, Wo_l, En, bo_l, y, En, En);
        k_addln<<<Mn, 256, 0, stream>>>(x, y, ln1g + (size_t)l * En,
                                        ln1b + (size_t)l * En, x, xb);

        // FF1 + GELU: [2048,512]bf16 x [2048,512]^T fp32 -> [2048,2048]bf16
        k_gemm<128, 128, 64, 1, 1, 0, 1>
            <<<dim3(Mn / 128, FFn / 128), 256, 0, stream>>>(
            xb, En, W1_l, En, b1_l, Sffb, FFn, En);

        // FF2: [2048,2048]bf16 x [512,2048]^T fp32 -> fp32 y
        k_gemm<64, 64, 128, 0, 1, 0, 0>
            <<<dim3(Mn / 64, En / 64), 256, 0, stream>>>(
            Sffb, FFn, W2_l, FFn, b2_l, y, En, FFn);
        k_addln<<<Mn, 256, 0, stream>>>(x, y, ln2g + (size_t)l * En,
                                        ln2b + (size_t)l * En, x, xb);
    }

    k_out<<<(Mn * En + Mn + 255) / 256, 256, 0, stream>>>(x, tok, (float*)d_out);
}

// Round 11
// 337.403 us; speedup vs baseline: 7.4909x; 1.3774x over previous
//
#include <hip/hip_runtime.h>
#include <hip/hip_bf16.h>

// ---------------------------------------------------------------------------
// SimpleGeoFormerModel: 4-layer transformer encoder. FP32 in/out; bf16
// activations + pre-converted bf16 weights; bf16 MFMA (fp32 accumulate).
// B=8 N=256 E=512 V=512 L=4 H=8 FF=2048, dh=64.
// Round 11: 64^2/BK=128 GEMM tiles everywhere (3-4 blocks/CU), split-K for
// Wo (x2) and FF2 (x4) with reduction fused into addln; bf16 weight precvt.
// ---------------------------------------------------------------------------

namespace {
constexpr int Bn  = 8;
constexpr int Nn  = 256;
constexpr int En  = 512;
constexpr int Ln  = 4;
constexpr int Hn  = 8;
constexpr int FFn = 2048;
constexpr int DHn = 64;
constexpr int Mn  = Bn * Nn;        // 2048 rows
constexpr int QKV_LD = 3 * En;      // 1536
constexpr int LUT_N = 4096;
}

typedef float f32x4 __attribute__((ext_vector_type(4)));
typedef short bf16x8 __attribute__((ext_vector_type(8)));

// fp32 -> bf16 round-to-nearest-even (finite inputs)
__device__ __forceinline__ unsigned short f2bs(float f) {
    union { float f; unsigned u; } v; v.f = f;
    unsigned r = v.u + 0x7FFFu + ((v.u >> 16) & 1u);
    return (unsigned short)(r >> 16);
}
__device__ __forceinline__ float bf2f(short s) {
    union { unsigned u; float f; } v;
    v.u = ((unsigned)(unsigned short)s) << 16;
    return v.f;
}

// swizzled byte address within a row-major bf16 LDS tile (16B-unit XOR)
__device__ __forceinline__ int swz(int row, int byte_in_row, int stride_b) {
    return row * stride_b + (byte_in_row ^ ((row & 7) << 4));
}

// ---------------- fp32 -> bf16 weight conversion (x4 vectorized) ----------
__global__ __launch_bounds__(256) void k_cvt(const float* __restrict__ in,
                                             unsigned short* __restrict__ out,
                                             int n4) {
    int i = blockIdx.x * 256 + threadIdx.x;
    if (i >= n4) return;
    f32x4 v = *(const f32x4*)(in + (size_t)i * 4);
    unsigned short o[4] = {f2bs(v[0]), f2bs(v[1]), f2bs(v[2]), f2bs(v[3])};
    *(unsigned long long*)(out + (size_t)i * 4) = *(unsigned long long*)o;
}

// ---------------- embedding gather (fp32 x + bf16 shadow) ----------------
__global__ __launch_bounds__(256) void k_embed(const int* __restrict__ tok,
                                               const float* __restrict__ emb,
                                               float* __restrict__ x,
                                               unsigned short* __restrict__ xb) {
    int i = blockIdx.x * 256 + threadIdx.x;
    int m = i >> 9;
    int e = i & 511;
    float v = emb[tok[m] * En + e];
    x[i] = v;
    xb[i] = f2bs(v);
}

// ---------------- LUT build ----------------
__global__ __launch_bounds__(256) void k_lutbuild(const float* __restrict__ w1,
                                                  const float* __restrict__ b1,
                                                  const float* __restrict__ w2,
                                                  float* __restrict__ lut) {
    __shared__ float sw1[En], sb1[En], sw2[En];
    for (int e = threadIdx.x; e < En; e += 256) {
        sw1[e] = w1[e]; sb1[e] = b1[e]; sw2[e] = w2[e];
    }
    __syncthreads();
    int i = blockIdx.x * 256 + threadIdx.x;
    if (i > LUT_N) return;
    float d = (float)i * (10.0f / (float)LUT_N);
    float acc = 0.f;
#pragma unroll 4
    for (int e = 0; e < En; ++e) {
        float s = fmaf(d, sw1[e], sb1[e]);
        float t = 1.f - 2.f / (__expf(2.f * s) + 1.f);
        acc = fmaf(t, sw2[e], acc);
    }
    lut[i] = acc;
}

// ---------------- distance bias via LUT ----------------
__global__ __launch_bounds__(256) void k_distbias_lut(const float* __restrict__ dist,
                                                      const int* __restrict__ tok,
                                                      const float* __restrict__ lut,
                                                      const float* __restrict__ b2,
                                                      float* __restrict__ biasmat) {
    int i = blockIdx.x * 256 + threadIdx.x;
    float d = dist[i];
    float idx = d * ((float)LUT_N / 10.0f);
    int ii = (int)idx;
    ii = ii < 0 ? 0 : (ii > LUT_N - 1 ? LUT_N - 1 : ii);
    float frac = idx - (float)ii;
    float v0 = lut[ii], v1 = lut[ii + 1];
    float acc = fmaf(v1 - v0, frac, v0) + b2[0];
    int k = i & (Nn - 1);
    int q = (i >> 8) & (Nn - 1);
    int b = i >> 16;
    bool pad = (tok[b * Nn + k] == 0) || (tok[b * Nn + q] == 0);
    biasmat[i] = pad ? -1e30f : acc;
}

// ---------------- V^T per head (bf16): vT[bh][d][k] ----------------
__global__ __launch_bounds__(256) void k_vt(const unsigned short* __restrict__ qkv,
                                            unsigned short* __restrict__ vT) {
    __shared__ unsigned short t[64][66];
    const int tid = threadIdx.x;
    const int bh = blockIdx.y, b = bh >> 3, h = bh & 7;
    const int k0 = blockIdx.x * 64;
    const unsigned short* src = qkv + ((size_t)(b * Nn + k0)) * QKV_LD + 2 * En + h * DHn;
    for (int idx = tid; idx < 64 * 64; idx += 256) {
        int r = idx >> 6, c = idx & 63;
        t[r][c] = src[(size_t)r * QKV_LD + c];
    }
    __syncthreads();
    unsigned short* dst = vT + ((size_t)bh * DHn) * Nn + k0;
    for (int idx = tid; idx < 64 * 64; idx += 256) {
        int d = idx >> 6, kk = idx & 63;
        dst[(size_t)d * Nn + kk] = t[kk][d];
    }
}

// ---------------- fused attention (unchanged from round 10) ----------------
__global__ __launch_bounds__(256, 1) void k_attn(
        const unsigned short* __restrict__ qkvb,
        const unsigned short* __restrict__ vTb,
        const float* __restrict__ biasmat,
        unsigned short* __restrict__ attnb) {
    __shared__ short Qs[64 * 64];
    __shared__ short Ks[256 * 64];
    __shared__ short Vs[64 * 256];
    __shared__ short Ps[64 * 256];

    const int tid = threadIdx.x;
    const int lane = tid & 63;
    const int wv = tid >> 6;
    const int q0 = blockIdx.x * 64;
    const int bh = blockIdx.y;
    const int b = bh >> 3, h = bh & 7;

    const unsigned short* Qg = qkvb + ((size_t)(b * Nn + q0)) * QKV_LD + h * DHn;
    const unsigned short* Kg = qkvb + ((size_t)(b * Nn)) * QKV_LD + En + h * DHn;
    const unsigned short* Vg = vTb + (size_t)bh * DHn * Nn;

    {
        const char* src = (const char*)(Kg + (size_t)tid * QKV_LD);
#pragma unroll
        for (int c = 0; c < 8; ++c)
            *(bf16x8*)((char*)Ks + swz(tid, c * 16, 128)) =
                *(const bf16x8*)(src + c * 16);
    }
    {
        int d = tid >> 2;
        int cb = (tid & 3) * 128;
        const char* src = (const char*)(Vg + (size_t)d * Nn) + cb;
#pragma unroll
        for (int c = 0; c < 8; ++c)
            *(bf16x8*)((char*)Vs + swz(d, cb + c * 16, 512)) =
                *(const bf16x8*)(src + c * 16);
    }
    {
        int r = tid & 63;
        const char* src = (const char*)(Qg + (size_t)r * QKV_LD);
#pragma unroll
        for (int i = 0; i < 2; ++i) {
            int cb = ((tid >> 6) * 2 + i) * 16;
            bf16x8 v = *(const bf16x8*)(src + cb);
            bf16x8 o;
#pragma unroll
            for (int j = 0; j < 8; ++j) o[j] = (short)f2bs(bf2f(v[j]) * 0.125f);
            *(bf16x8*)((char*)Qs + swz(r, cb, 128)) = o;
        }
    }

    const int qw = wv * 16;
    const int g  = lane >> 4;
    const int c  = lane & 15;
    f32x4 acc[16];
    {
        const float* bb = biasmat + ((size_t)b * Nn + (q0 + qw + g * 4)) * Nn;
#pragma unroll
        for (int f = 0; f < 16; ++f)
#pragma unroll
            for (int r = 0; r < 4; ++r)
                acc[f][r] = bb[(size_t)r * Nn + f * 16 + c];
    }

    __syncthreads();

    bf16x8 qa[2];
#pragma unroll
    for (int ks = 0; ks < 2; ++ks)
        qa[ks] = *(const bf16x8*)((const char*)Qs + swz(qw + c, ks * 64 + g * 16, 128));
#pragma unroll
    for (int f = 0; f < 16; ++f) {
#pragma unroll
        for (int ks = 0; ks < 2; ++ks) {
            bf16x8 kb = *(const bf16x8*)((const char*)Ks +
                         swz(f * 16 + c, ks * 64 + g * 16, 128));
            acc[f] = __builtin_amdgcn_mfma_f32_16x16x32_bf16(qa[ks], kb, acc[f], 0, 0, 0);
        }
    }

    float rcp[4];
#pragma unroll
    for (int r = 0; r < 4; ++r) {
        float m = acc[0][r];
#pragma unroll
        for (int f = 1; f < 16; ++f) m = fmaxf(m, acc[f][r]);
#pragma unroll
        for (int o = 1; o < 16; o <<= 1) m = fmaxf(m, __shfl_xor(m, o));
        float s = 0.f;
#pragma unroll
        for (int f = 0; f < 16; ++f) {
            float e = __expf(acc[f][r] - m);
            acc[f][r] = e;
            s += e;
        }
#pragma unroll
        for (int o = 1; o < 16; o <<= 1) s += __shfl_xor(s, o);
        rcp[r] = 1.f / s;
    }

#pragma unroll
    for (int f = 0; f < 16; ++f)
#pragma unroll
        for (int r = 0; r < 4; ++r) {
            int q = qw + g * 4 + r;
            int kx = f * 16 + c;
            *(unsigned short*)((char*)Ps + (q * 512 + ((kx * 2) ^ ((q & 7) << 4)))) =
                f2bs(acc[f][r] * rcp[r]);
        }

    f32x4 acc2[4];
#pragma unroll
    for (int fd = 0; fd < 4; ++fd) acc2[fd] = {0.f, 0.f, 0.f, 0.f};
#pragma unroll
    for (int ks2 = 0; ks2 < 8; ++ks2) {
        bf16x8 pa = *(const bf16x8*)((const char*)Ps +
                      swz(qw + c, ks2 * 64 + g * 16, 512));
#pragma unroll
        for (int fd = 0; fd < 4; ++fd) {
            bf16x8 vb = *(const bf16x8*)((const char*)Vs +
                          swz(fd * 16 + c, ks2 * 64 + g * 16, 512));
            acc2[fd] = __builtin_amdgcn_mfma_f32_16x16x32_bf16(pa, vb, acc2[fd], 0, 0, 0);
        }
    }

    unsigned short* Cg = attnb + ((size_t)(b * Nn + q0 + qw)) * En + h * DHn;
#pragma unroll
    for (int fd = 0; fd < 4; ++fd)
#pragma unroll
        for (int r = 0; r < 4; ++r)
            Cg[(size_t)(g * 4 + r) * En + fd * 16 + c] = f2bs(acc2[fd][r]);
}

// ---------------- MFMA GEMM, all-bf16 operands: C = A*B^T (+epilogue)
// MODE 0: +bias[n] ; 1: gelu(+bias[n]) ; 3: raw partial (split-K via blockIdx.z)
// CBF: bf16 output, else fp32. K = per-split depth; z selects the K slice.
template <int BM, int BN, int BK, int MODE, int CBF>
__global__ __launch_bounds__(256) void k_gemm(
        const unsigned short* __restrict__ A, int lda,
        const unsigned short* __restrict__ Bw, int ldb,
        const float* __restrict__ bias,
        void* __restrict__ Cp, int ldc, long long sCz,
        int K) {
    static_assert(BM == BN, "square tiles only");
    constexpr int LDS_S = BK + 8;
    constexpr int WM = BM / 2, WN = BN / 2;
    constexpr int FM = WM / 16, FN = WN / 16;
    constexpr int GR = 256 / BM;
    constexpr int TC = BK / GR;
    constexpr int NR = TC / 8;

    __shared__ short As[BM * LDS_S];
    __shared__ short Bs[BM * LDS_S];

    const int tid  = threadIdx.x;
    const int lane = tid & 63;
    const int wv   = tid >> 6;
    const int wr   = wv >> 1, wc = wv & 1;
    const int m0 = blockIdx.x * BM, n0 = blockIdx.y * BN;
    const int z  = blockIdx.z;

    const int arow = tid / GR;
    const int acol = (tid % GR) * TC;

    const unsigned short* Abase = A  + (size_t)(m0 + arow) * lda + (size_t)z * K + acol;
    const unsigned short* Bbase = Bw + (size_t)(n0 + arow) * ldb + (size_t)z * K + acol;

    bf16x8 pa[NR], pb[NR];
#pragma unroll
    for (int i = 0; i < NR; ++i) pa[i] = *(const bf16x8*)(Abase + 8 * i);
#pragma unroll
    for (int i = 0; i < NR; ++i) pb[i] = *(const bf16x8*)(Bbase + 8 * i);

    f32x4 acc[FM][FN];
#pragma unroll
    for (int i = 0; i < FM; ++i)
#pragma unroll
        for (int j = 0; j < FN; ++j) acc[i][j] = {0.f, 0.f, 0.f, 0.f};

    const int fk   = (lane >> 4) * 8;
    const int frow = lane & 15;
    short* awp = &As[arow * LDS_S + acol];
    short* bwp = &Bs[arow * LDS_S + acol];

    const int nt = K / BK;
    for (int t = 0; t < nt; ++t) {
#pragma unroll
        for (int i = 0; i < NR; ++i) *(bf16x8*)(awp + i * 8) = pa[i];
#pragma unroll
        for (int i = 0; i < NR; ++i) *(bf16x8*)(bwp + i * 8) = pb[i];
        __syncthreads();

        if (t + 1 < nt) {
            const unsigned short* An = Abase + (size_t)(t + 1) * BK;
            const unsigned short* Bn = Bbase + (size_t)(t + 1) * BK;
#pragma unroll
            for (int i = 0; i < NR; ++i) pa[i] = *(const bf16x8*)(An + 8 * i);
#pragma unroll
            for (int i = 0; i < NR; ++i) pb[i] = *(const bf16x8*)(Bn + 8 * i);
        }

#pragma unroll
        for (int ks = 0; ks < BK / 32; ++ks) {
            bf16x8 af[FM], bfr[FN];
#pragma unroll
            for (int i = 0; i < FM; ++i)
                af[i] = *(const bf16x8*)&As[(wr * WM + i * 16 + frow) * LDS_S + ks * 32 + fk];
#pragma unroll
            for (int j = 0; j < FN; ++j)
                bfr[j] = *(const bf16x8*)&Bs[(wc * WN + j * 16 + frow) * LDS_S + ks * 32 + fk];
#pragma unroll
            for (int i = 0; i < FM; ++i)
#pragma unroll
                for (int j = 0; j < FN; ++j)
                    acc[i][j] = __builtin_amdgcn_mfma_f32_16x16x32_bf16(
                        af[i], bfr[j], acc[i][j], 0, 0, 0);
        }
        __syncthreads();
    }

#pragma unroll
    for (int i = 0; i < FM; ++i) {
#pragma unroll
        for (int j = 0; j < FN; ++j) {
            const int n = n0 + wc * WN + j * 16 + (lane & 15);
            float bv = 0.f;
            if constexpr (MODE == 0 || MODE == 1) bv = bias[n];
#pragma unroll
            for (int r = 0; r < 4; ++r) {
                const int m = m0 + wr * WM + i * 16 + (lane >> 4) * 4 + r;
                float v = acc[i][j][r] + bv;
                if constexpr (MODE == 1)
                    v = 0.5f * v * (1.f + erff(v * 0.70710678118654752f));
                if constexpr (CBF)
                    ((unsigned short*)Cp)[(size_t)m * ldc + n] = f2bs(v);
                else
                    ((float*)Cp)[(size_t)z * sCz + (size_t)m * ldc + n] = v;
            }
        }
    }
}

// ---------------- residual + split-K partial sum + bias + LayerNorm --------
__global__ __launch_bounds__(256) void k_addln(
        const float* __restrict__ xin,
        const float* __restrict__ yp, long long ystride, int nsplit,
        const float* __restrict__ biasv,
        const float* __restrict__ g, const float* __restrict__ bb,
        float* __restrict__ xout, unsigned short* __restrict__ xbf) {
    const int row = blockIdx.x;
    const int tid = threadIdx.x;
    const size_t base = (size_t)row * En;
    float v0 = xin[base + tid] + biasv[tid];
    float v1 = xin[base + tid + 256] + biasv[tid + 256];
    for (int s = 0; s < nsplit; ++s) {
        v0 += yp[(size_t)s * ystride + base + tid];
        v1 += yp[(size_t)s * ystride + base + tid + 256];
    }
    float s1 = v0 + v1;
    float s2 = v0 * v0 + v1 * v1;
#pragma unroll
    for (int o = 32; o; o >>= 1) {
        s1 += __shfl_xor(s1, o);
        s2 += __shfl_xor(s2, o);
    }
    __shared__ float ws1[4], ws2[4];
    int w = tid >> 6;
    if ((tid & 63) == 0) { ws1[w] = s1; ws2[w] = s2; }
    __syncthreads();
    s1 = (ws1[0] + ws1[1]) + (ws1[2] + ws1[3]);
    s2 = (ws2[0] + ws2[1]) + (ws2[2] + ws2[3]);
    const float rE = 1.f / (float)En;
    float mean = s1 * rE;
    float var = s2 * rE - mean * mean;
    float inv = rsqrtf(var + 1e-5f);
    float o0 = (v0 - mean) * inv * g[tid] + bb[tid];
    float o1 = (v1 - mean) * inv * g[tid + 256] + bb[tid + 256];
    xout[base + tid]       = o0;
    xout[base + tid + 256] = o1;
    xbf[base + tid]        = f2bs(o0);
    xbf[base + tid + 256]  = f2bs(o1);
}

// ---------------- final: fp32 x ++ fp32 pad_mask ----------------
__global__ __launch_bounds__(256) void k_out(const float* __restrict__ x,
                                             const int* __restrict__ tok,
                                             float* __restrict__ out) {
    int i = blockIdx.x * 256 + threadIdx.x;
    const int total = Mn * En + Mn;
    if (i >= total) return;
    if (i < Mn * En) {
        out[i] = x[i];
    } else {
        int m = i - Mn * En;
        out[i] = (tok[m] == 0) ? 1.f : 0.f;
    }
}

// ---------------------------------------------------------------------------
extern "C" void kernel_launch(void* const* d_in, const int* in_sizes, int n_in,
                              void* d_out, int out_size, void* d_ws, size_t ws_size,
                              hipStream_t stream) {
    const int*   tok   = (const int*)  d_in[0];
    const float* dist  = (const float*)d_in[2];
    const float* emb   = (const float*)d_in[4];
    const float* dp_w1 = (const float*)d_in[5];
    const float* dp_b1 = (const float*)d_in[6];
    const float* dp_w2 = (const float*)d_in[7];
    const float* dp_b2 = (const float*)d_in[8];
    const float* Wqkv  = (const float*)d_in[9];
    const float* bqkv  = (const float*)d_in[10];
    const float* Wo    = (const float*)d_in[11];
    const float* bo    = (const float*)d_in[12];
    const float* ln1g  = (const float*)d_in[13];
    const float* ln1b  = (const float*)d_in[14];
    const float* W1    = (const float*)d_in[15];
    const float* b1    = (const float*)d_in[16];
    const float* W2    = (const float*)d_in[17];
    const float* b2    = (const float*)d_in[18];
    const float* ln2g  = (const float*)d_in[19];
    const float* ln2b  = (const float*)d_in[20];

    char* p = (char*)d_ws;
    float*          biasmat = (float*)p;          p += (size_t)Bn*Nn*Nn*4;    // 2 MB
    float*          x       = (float*)p;          p += (size_t)Mn*En*4;       // 4 MB
    unsigned short* xb      = (unsigned short*)p; p += (size_t)Mn*En*2;       // 2 MB
    unsigned short* qkvb    = (unsigned short*)p; p += (size_t)Mn*QKV_LD*2;   // 6 MB
    unsigned short* Sffb    = (unsigned short*)p; p += (size_t)Mn*FFn*2;      // 8 MB
    unsigned short* attnb   = (unsigned short*)p; p += (size_t)Mn*En*2;       // 2 MB
    float*          yp      = (float*)p;          p += (size_t)4*Mn*En*4;     // 16 MB
    unsigned short* vTb     = (unsigned short*)p; p += (size_t)Bn*Hn*DHn*Nn*2;// 2 MB
    float*          lut     = (float*)p;          p += (size_t)(LUT_N+8)*4;
    unsigned short* wqkvb   = (unsigned short*)p; p += (size_t)Ln*QKV_LD*En*2;// 6.3 MB
    unsigned short* wob     = (unsigned short*)p; p += (size_t)Ln*En*En*2;    // 2.1 MB
    unsigned short* w1b     = (unsigned short*)p; p += (size_t)Ln*FFn*En*2;   // 8.4 MB
    unsigned short* w2b     = (unsigned short*)p; p += (size_t)Ln*En*FFn*2;   // 8.4 MB

    // one-time weight conversion fp32 -> bf16
    k_cvt<<<(Ln*QKV_LD*En/4 + 255)/256, 256, 0, stream>>>(Wqkv, wqkvb, Ln*QKV_LD*En/4);
    k_cvt<<<(Ln*En*En/4   + 255)/256, 256, 0, stream>>>(Wo,   wob,   Ln*En*En/4);
    k_cvt<<<(Ln*FFn*En/4  + 255)/256, 256, 0, stream>>>(W1,   w1b,   Ln*FFn*En/4);
    k_cvt<<<(Ln*En*FFn/4  + 255)/256, 256, 0, stream>>>(W2,   w2b,   Ln*En*FFn/4);

    k_embed<<<Mn * En / 256, 256, 0, stream>>>(tok, emb, x, xb);
    k_lutbuild<<<(LUT_N + 256) / 256, 256, 0, stream>>>(dp_w1, dp_b1, dp_w2, lut);
    k_distbias_lut<<<Bn * Nn * Nn / 256, 256, 0, stream>>>(dist, tok, lut, dp_b2,
                                                           biasmat);

    const long long yps = (long long)Mn * En;
    for (int l = 0; l < Ln; ++l) {
        const unsigned short* Wqkv_l = wqkvb + (size_t)l * QKV_LD * En;
        const float*          bqkv_l = bqkv  + (size_t)l * QKV_LD;
        const unsigned short* Wo_l   = wob   + (size_t)l * En * En;
        const unsigned short* W1_l   = w1b   + (size_t)l * FFn * En;
        const float*          b1_l   = b1    + (size_t)l * FFn;
        const unsigned short* W2_l   = w2b   + (size_t)l * En * FFn;

        // QKV: [2048,512] x [1536,512]^T -> bf16 [2048,1536]  (768 blocks)
        k_gemm<64, 64, 128, 0, 1>
            <<<dim3(Mn / 64, QKV_LD / 64), 256, 0, stream>>>(
            xb, En, Wqkv_l, En, bqkv_l, qkvb, QKV_LD, 0, En);

        // V^T per head (bf16)
        k_vt<<<dim3(Nn / 64, Bn * Hn), 256, 0, stream>>>(qkvb, vTb);

        // fused attention -> attnb
        k_attn<<<dim3(Nn / 64, Bn * Hn), 256, 0, stream>>>(qkvb, vTb, biasmat, attnb);

        // O projection, split-K x2 -> fp32 partials (512 blocks)
        k_gemm<64, 64, 128, 3, 0>
            <<<dim3(Mn / 64, En / 64, 2), 256, 0, stream>>>(
            attnb, En, Wo_l, En, nullptr, yp, En, yps, En / 2);
        k_addln<<<Mn, 256, 0, stream>>>(x, yp, yps, 2,
                                        bo + (size_t)l * En,
                                        ln1g + (size_t)l * En, ln1b + (size_t)l * En,
                                        x, xb);

        // FF1 + GELU: [2048,512] x [2048,512]^T -> bf16 (1024 blocks)
        k_gemm<64, 64, 128, 1, 1>
            <<<dim3(Mn / 64, FFn / 64), 256, 0, stream>>>(
            xb, En, W1_l, En, b1_l, Sffb, FFn, 0, En);

        // FF2, split-K x4 -> fp32 partials (1024 blocks)
        k_gemm<64, 64, 128, 3, 0>
            <<<dim3(Mn / 64, En / 64, 4), 256, 0, stream>>>(
            Sffb, FFn, W2_l, FFn, nullptr, yp, En, yps, FFn / 4);
        k_addln<<<Mn, 256, 0, stream>>>(x, yp, yps, 4,
                                        b2 + (size_t)l * En,
                                        ln2g + (size_t)l * En, ln2b + (size_t)l * En,
                                        x, xb);
    }

    k_out<<<(Mn * En + Mn + 255) / 256, 256, 0, stream>>>(x, tok, (float*)d_out);
}

// Round 12
// 315.973 us; speedup vs baseline: 7.9989x; 1.0678x over previous
//
#include <hip/hip_runtime.h>
#include <hip/hip_bf16.h>

// ---------------------------------------------------------------------------
// SimpleGeoFormerModel: 4-layer transformer encoder. FP32 in/out; bf16
// activations + pre-converted bf16 weights; bf16 MFMA (fp32 accumulate).
// B=8 N=256 E=512 V=512 L=4 H=8 FF=2048, dh=64.
// Round 12: launch trim — V^T fold into k_attn, single cvt, embed+lut merge,
// k_out fused into final addln. GEMM/attn math unchanged from round 11.
// ---------------------------------------------------------------------------

namespace {
constexpr int Bn  = 8;
constexpr int Nn  = 256;
constexpr int En  = 512;
constexpr int Ln  = 4;
constexpr int Hn  = 8;
constexpr int FFn = 2048;
constexpr int DHn = 64;
constexpr int Mn  = Bn * Nn;        // 2048 rows
constexpr int QKV_LD = 3 * En;      // 1536
constexpr int LUT_N = 4096;
}

typedef float f32x4 __attribute__((ext_vector_type(4)));
typedef short bf16x8 __attribute__((ext_vector_type(8)));

// fp32 -> bf16 round-to-nearest-even (finite inputs)
__device__ __forceinline__ unsigned short f2bs(float f) {
    union { float f; unsigned u; } v; v.f = f;
    unsigned r = v.u + 0x7FFFu + ((v.u >> 16) & 1u);
    return (unsigned short)(r >> 16);
}
__device__ __forceinline__ float bf2f(short s) {
    union { unsigned u; float f; } v;
    v.u = ((unsigned)(unsigned short)s) << 16;
    return v.f;
}

// swizzled byte address within a row-major bf16 LDS tile (16B-unit XOR)
__device__ __forceinline__ int swz(int row, int byte_in_row, int stride_b) {
    return row * stride_b + (byte_in_row ^ ((row & 7) << 4));
}

// ---------------- one-shot weight conversion (4 ranges, 1 launch) ----------
struct CvtArgs {
    const float* src[4];
    unsigned short* dst[4];
    int n4[4];
    int blkoff[5];
};
__global__ __launch_bounds__(256) void k_cvt(CvtArgs a) {
    int bid = blockIdx.x;
    int r = 0;
    if (bid >= a.blkoff[1]) r = 1;
    if (bid >= a.blkoff[2]) r = 2;
    if (bid >= a.blkoff[3]) r = 3;
    int i = (bid - a.blkoff[r]) * 256 + threadIdx.x;
    if (i >= a.n4[r]) return;
    f32x4 v = *(const f32x4*)(a.src[r] + (size_t)i * 4);
    unsigned short o[4] = {f2bs(v[0]), f2bs(v[1]), f2bs(v[2]), f2bs(v[3])};
    *(unsigned long long*)(a.dst[r] + (size_t)i * 4) = *(unsigned long long*)o;
}

// ---------------- embed (blocks 0..Mn*En/256) + LUT build (rest) -----------
__global__ __launch_bounds__(256) void k_embed_lut(const int* __restrict__ tok,
                                                   const float* __restrict__ emb,
                                                   float* __restrict__ x,
                                                   unsigned short* __restrict__ xb,
                                                   const float* __restrict__ w1,
                                                   const float* __restrict__ b1,
                                                   const float* __restrict__ w2,
                                                   float* __restrict__ lut) {
    constexpr int EMB_BLOCKS = Mn * En / 256;
    if (blockIdx.x < EMB_BLOCKS) {
        int i = blockIdx.x * 256 + threadIdx.x;
        int m = i >> 9;
        int e = i & 511;
        float v = emb[tok[m] * En + e];
        x[i] = v;
        xb[i] = f2bs(v);
        return;
    }
    __shared__ float sw1[En], sb1[En], sw2[En];
    for (int e = threadIdx.x; e < En; e += 256) {
        sw1[e] = w1[e]; sb1[e] = b1[e]; sw2[e] = w2[e];
    }
    __syncthreads();
    int i = (blockIdx.x - EMB_BLOCKS) * 256 + threadIdx.x;
    if (i > LUT_N) return;
    float d = (float)i * (10.0f / (float)LUT_N);
    float acc = 0.f;
#pragma unroll 4
    for (int e = 0; e < En; ++e) {
        float s = fmaf(d, sw1[e], sb1[e]);
        float t = 1.f - 2.f / (__expf(2.f * s) + 1.f);
        acc = fmaf(t, sw2[e], acc);
    }
    lut[i] = acc;
}

// ---------------- distance bias via LUT ----------------
__global__ __launch_bounds__(256) void k_distbias_lut(const float* __restrict__ dist,
                                                      const int* __restrict__ tok,
                                                      const float* __restrict__ lut,
                                                      const float* __restrict__ b2,
                                                      float* __restrict__ biasmat) {
    int i = blockIdx.x * 256 + threadIdx.x;
    float d = dist[i];
    float idx = d * ((float)LUT_N / 10.0f);
    int ii = (int)idx;
    ii = ii < 0 ? 0 : (ii > LUT_N - 1 ? LUT_N - 1 : ii);
    float frac = idx - (float)ii;
    float v0 = lut[ii], v1 = lut[ii + 1];
    float acc = fmaf(v1 - v0, frac, v0) + b2[0];
    int k = i & (Nn - 1);
    int q = (i >> 8) & (Nn - 1);
    int b = i >> 16;
    bool pad = (tok[b * Nn + k] == 0) || (tok[b * Nn + q] == 0);
    biasmat[i] = pad ? -1e30f : acc;
}

// ---------------- fused attention (V^T staged in-kernel from qkv) ----------
__global__ __launch_bounds__(256, 1) void k_attn(
        const unsigned short* __restrict__ qkvb,
        const float* __restrict__ biasmat,
        unsigned short* __restrict__ attnb) {
    __shared__ short Qs[64 * 64];     // [q][d], stride 128B, swizzled
    __shared__ short Ks[256 * 64];    // [k][d], stride 128B, swizzled
    __shared__ short Vs[64 * 256];    // [d][k] (V^T), stride 512B, swizzled
    __shared__ short Ps[64 * 256];    // [q][k], stride 512B, swizzled

    const int tid = threadIdx.x;
    const int lane = tid & 63;
    const int wv = tid >> 6;
    const int q0 = blockIdx.x * 64;
    const int bh = blockIdx.y;
    const int b = bh >> 3, h = bh & 7;

    const unsigned short* Qg = qkvb + ((size_t)(b * Nn + q0)) * QKV_LD + h * DHn;
    const unsigned short* Kg = qkvb + ((size_t)(b * Nn)) * QKV_LD + En + h * DHn;
    const unsigned short* VgR = qkvb + ((size_t)(b * Nn)) * QKV_LD + 2 * En + h * DHn;

    // ---- stage K: 256 rows x 128B; thread -> one row
    {
        const char* src = (const char*)(Kg + (size_t)tid * QKV_LD);
#pragma unroll
        for (int c = 0; c < 8; ++c)
            *(bf16x8*)((char*)Ks + swz(tid, c * 16, 128)) =
                *(const bf16x8*)(src + c * 16);
    }
    // ---- stage V^T via scatter: thread = V row k; write Vs[d][k]
    {
        const char* src = (const char*)(VgR + (size_t)tid * QKV_LD);
#pragma unroll
        for (int c = 0; c < 8; ++c) {
            bf16x8 v = *(const bf16x8*)(src + c * 16);
#pragma unroll
            for (int j = 0; j < 8; ++j) {
                int d = c * 8 + j;
                *(short*)((char*)Vs + (d * 512 + ((tid * 2) ^ ((d & 7) << 4)))) = v[j];
            }
        }
    }
    // ---- stage Q scaled by 0.125 (exact)
    {
        int r = tid & 63;
        const char* src = (const char*)(Qg + (size_t)r * QKV_LD);
#pragma unroll
        for (int i = 0; i < 2; ++i) {
            int cb = ((tid >> 6) * 2 + i) * 16;
            bf16x8 v = *(const bf16x8*)(src + cb);
            bf16x8 o;
#pragma unroll
            for (int j = 0; j < 8; ++j) o[j] = (short)f2bs(bf2f(v[j]) * 0.125f);
            *(bf16x8*)((char*)Qs + swz(r, cb, 128)) = o;
        }
    }

    // ---- bias preload into accumulator (C-init)
    const int qw = wv * 16;
    const int g  = lane >> 4;
    const int c  = lane & 15;
    f32x4 acc[16];
    {
        const float* bb = biasmat + ((size_t)b * Nn + (q0 + qw + g * 4)) * Nn;
#pragma unroll
        for (int f = 0; f < 16; ++f)
#pragma unroll
            for (int r = 0; r < 4; ++r)
                acc[f][r] = bb[(size_t)r * Nn + f * 16 + c];
    }

    __syncthreads();

    // ---- S = 0.125*Q.K^T + bias
    bf16x8 qa[2];
#pragma unroll
    for (int ks = 0; ks < 2; ++ks)
        qa[ks] = *(const bf16x8*)((const char*)Qs + swz(qw + c, ks * 64 + g * 16, 128));
#pragma unroll
    for (int f = 0; f < 16; ++f) {
#pragma unroll
        for (int ks = 0; ks < 2; ++ks) {
            bf16x8 kb = *(const bf16x8*)((const char*)Ks +
                         swz(f * 16 + c, ks * 64 + g * 16, 128));
            acc[f] = __builtin_amdgcn_mfma_f32_16x16x32_bf16(qa[ks], kb, acc[f], 0, 0, 0);
        }
    }

    // ---- in-register softmax (16-lane group owns each row)
    float rcp[4];
#pragma unroll
    for (int r = 0; r < 4; ++r) {
        float m = acc[0][r];
#pragma unroll
        for (int f = 1; f < 16; ++f) m = fmaxf(m, acc[f][r]);
#pragma unroll
        for (int o = 1; o < 16; o <<= 1) m = fmaxf(m, __shfl_xor(m, o));
        float s = 0.f;
#pragma unroll
        for (int f = 0; f < 16; ++f) {
            float e = __expf(acc[f][r] - m);
            acc[f][r] = e;
            s += e;
        }
#pragma unroll
        for (int o = 1; o < 16; o <<= 1) s += __shfl_xor(s, o);
        rcp[r] = 1.f / s;
    }

    // ---- P -> bf16 LDS (each wave writes its own 16 rows)
#pragma unroll
    for (int f = 0; f < 16; ++f)
#pragma unroll
        for (int r = 0; r < 4; ++r) {
            int q = qw + g * 4 + r;
            int kx = f * 16 + c;
            *(unsigned short*)((char*)Ps + (q * 512 + ((kx * 2) ^ ((q & 7) << 4)))) =
                f2bs(acc[f][r] * rcp[r]);
        }

    // ---- PV (reads own rows only; no barrier needed)
    f32x4 acc2[4];
#pragma unroll
    for (int fd = 0; fd < 4; ++fd) acc2[fd] = {0.f, 0.f, 0.f, 0.f};
#pragma unroll
    for (int ks2 = 0; ks2 < 8; ++ks2) {
        bf16x8 pa = *(const bf16x8*)((const char*)Ps +
                      swz(qw + c, ks2 * 64 + g * 16, 512));
#pragma unroll
        for (int fd = 0; fd < 4; ++fd) {
            bf16x8 vb = *(const bf16x8*)((const char*)Vs +
                          swz(fd * 16 + c, ks2 * 64 + g * 16, 512));
            acc2[fd] = __builtin_amdgcn_mfma_f32_16x16x32_bf16(pa, vb, acc2[fd], 0, 0, 0);
        }
    }

    unsigned short* Cg = attnb + ((size_t)(b * Nn + q0 + qw)) * En + h * DHn;
#pragma unroll
    for (int fd = 0; fd < 4; ++fd)
#pragma unroll
        for (int r = 0; r < 4; ++r)
            Cg[(size_t)(g * 4 + r) * En + fd * 16 + c] = f2bs(acc2[fd][r]);
}

// ---------------- MFMA GEMM, all-bf16 operands (unchanged round 11) --------
template <int BM, int BN, int BK, int MODE, int CBF>
__global__ __launch_bounds__(256) void k_gemm(
        const unsigned short* __restrict__ A, int lda,
        const unsigned short* __restrict__ Bw, int ldb,
        const float* __restrict__ bias,
        void* __restrict__ Cp, int ldc, long long sCz,
        int K) {
    static_assert(BM == BN, "square tiles only");
    constexpr int LDS_S = BK + 8;
    constexpr int WM = BM / 2, WN = BN / 2;
    constexpr int FM = WM / 16, FN = WN / 16;
    constexpr int GR = 256 / BM;
    constexpr int TC = BK / GR;
    constexpr int NR = TC / 8;

    __shared__ short As[BM * LDS_S];
    __shared__ short Bs[BM * LDS_S];

    const int tid  = threadIdx.x;
    const int lane = tid & 63;
    const int wv   = tid >> 6;
    const int wr   = wv >> 1, wc = wv & 1;
    const int m0 = blockIdx.x * BM, n0 = blockIdx.y * BN;
    const int z  = blockIdx.z;

    const int arow = tid / GR;
    const int acol = (tid % GR) * TC;

    const unsigned short* Abase = A  + (size_t)(m0 + arow) * lda + (size_t)z * K + acol;
    const unsigned short* Bbase = Bw + (size_t)(n0 + arow) * ldb + (size_t)z * K + acol;

    bf16x8 pa[NR], pb[NR];
#pragma unroll
    for (int i = 0; i < NR; ++i) pa[i] = *(const bf16x8*)(Abase + 8 * i);
#pragma unroll
    for (int i = 0; i < NR; ++i) pb[i] = *(const bf16x8*)(Bbase + 8 * i);

    f32x4 acc[FM][FN];
#pragma unroll
    for (int i = 0; i < FM; ++i)
#pragma unroll
        for (int j = 0; j < FN; ++j) acc[i][j] = {0.f, 0.f, 0.f, 0.f};

    const int fk   = (lane >> 4) * 8;
    const int frow = lane & 15;
    short* awp = &As[arow * LDS_S + acol];
    short* bwp = &Bs[arow * LDS_S + acol];

    const int nt = K / BK;
    for (int t = 0; t < nt; ++t) {
#pragma unroll
        for (int i = 0; i < NR; ++i) *(bf16x8*)(awp + i * 8) = pa[i];
#pragma unroll
        for (int i = 0; i < NR; ++i) *(bf16x8*)(bwp + i * 8) = pb[i];
        __syncthreads();

        if (t + 1 < nt) {
            const unsigned short* An = Abase + (size_t)(t + 1) * BK;
            const unsigned short* Bn = Bbase + (size_t)(t + 1) * BK;
#pragma unroll
            for (int i = 0; i < NR; ++i) pa[i] = *(const bf16x8*)(An + 8 * i);
#pragma unroll
            for (int i = 0; i < NR; ++i) pb[i] = *(const bf16x8*)(Bn + 8 * i);
        }

#pragma unroll
        for (int ks = 0; ks < BK / 32; ++ks) {
            bf16x8 af[FM], bfr[FN];
#pragma unroll
            for (int i = 0; i < FM; ++i)
                af[i] = *(const bf16x8*)&As[(wr * WM + i * 16 + frow) * LDS_S + ks * 32 + fk];
#pragma unroll
            for (int j = 0; j < FN; ++j)
                bfr[j] = *(const bf16x8*)&Bs[(wc * WN + j * 16 + frow) * LDS_S + ks * 32 + fk];
#pragma unroll
            for (int i = 0; i < FM; ++i)
#pragma unroll
                for (int j = 0; j < FN; ++j)
                    acc[i][j] = __builtin_amdgcn_mfma_f32_16x16x32_bf16(
                        af[i], bfr[j], acc[i][j], 0, 0, 0);
        }
        __syncthreads();
    }

#pragma unroll
    for (int i = 0; i < FM; ++i) {
#pragma unroll
        for (int j = 0; j < FN; ++j) {
            const int n = n0 + wc * WN + j * 16 + (lane & 15);
            float bv = 0.f;
            if constexpr (MODE == 0 || MODE == 1) bv = bias[n];
#pragma unroll
            for (int r = 0; r < 4; ++r) {
                const int m = m0 + wr * WM + i * 16 + (lane >> 4) * 4 + r;
                float v = acc[i][j][r] + bv;
                if constexpr (MODE == 1)
                    v = 0.5f * v * (1.f + erff(v * 0.70710678118654752f));
                if constexpr (CBF)
                    ((unsigned short*)Cp)[(size_t)m * ldc + n] = f2bs(v);
                else
                    ((float*)Cp)[(size_t)z * sCz + (size_t)m * ldc + n] = v;
            }
        }
    }
}

// ---------------- residual + split-K sum + bias + LayerNorm (+final out) ---
template <int FINAL>
__global__ __launch_bounds__(256) void k_addln(
        const float* __restrict__ xin,
        const float* __restrict__ yp, long long ystride, int nsplit,
        const float* __restrict__ biasv,
        const float* __restrict__ g, const float* __restrict__ bb,
        float* __restrict__ xout, unsigned short* __restrict__ xbf,
        const int* __restrict__ tok) {
    const int row = blockIdx.x;
    const int tid = threadIdx.x;
    const size_t base = (size_t)row * En;
    float v0 = xin[base + tid] + biasv[tid];
    float v1 = xin[base + tid + 256] + biasv[tid + 256];
    for (int s = 0; s < nsplit; ++s) {
        v0 += yp[(size_t)s * ystride + base + tid];
        v1 += yp[(size_t)s * ystride + base + tid + 256];
    }
    float s1 = v0 + v1;
    float s2 = v0 * v0 + v1 * v1;
#pragma unroll
    for (int o = 32; o; o >>= 1) {
        s1 += __shfl_xor(s1, o);
        s2 += __shfl_xor(s2, o);
    }
    __shared__ float ws1[4], ws2[4];
    int w = tid >> 6;
    if ((tid & 63) == 0) { ws1[w] = s1; ws2[w] = s2; }
    __syncthreads();
    s1 = (ws1[0] + ws1[1]) + (ws1[2] + ws1[3]);
    s2 = (ws2[0] + ws2[1]) + (ws2[2] + ws2[3]);
    const float rE = 1.f / (float)En;
    float mean = s1 * rE;
    float var = s2 * rE - mean * mean;
    float inv = rsqrtf(var + 1e-5f);
    float o0 = (v0 - mean) * inv * g[tid] + bb[tid];
    float o1 = (v1 - mean) * inv * g[tid + 256] + bb[tid + 256];
    xout[base + tid]       = o0;
    xout[base + tid + 256] = o1;
    if constexpr (FINAL) {
        if (tid == 0)
            xout[(size_t)Mn * En + row] = (tok[row] == 0) ? 1.f : 0.f;
    } else {
        xbf[base + tid]       = f2bs(o0);
        xbf[base + tid + 256] = f2bs(o1);
    }
}

// ---------------------------------------------------------------------------
extern "C" void kernel_launch(void* const* d_in, const int* in_sizes, int n_in,
                              void* d_out, int out_size, void* d_ws, size_t ws_size,
                              hipStream_t stream) {
    const int*   tok   = (const int*)  d_in[0];
    const float* dist  = (const float*)d_in[2];
    const float* emb   = (const float*)d_in[4];
    const float* dp_w1 = (const float*)d_in[5];
    const float* dp_b1 = (const float*)d_in[6];
    const float* dp_w2 = (const float*)d_in[7];
    const float* dp_b2 = (const float*)d_in[8];
    const float* Wqkv  = (const float*)d_in[9];
    const float* bqkv  = (const float*)d_in[10];
    const float* Wo    = (const float*)d_in[11];
    const float* bo    = (const float*)d_in[12];
    const float* ln1g  = (const float*)d_in[13];
    const float* ln1b  = (const float*)d_in[14];
    const float* W1    = (const float*)d_in[15];
    const float* b1    = (const float*)d_in[16];
    const float* W2    = (const float*)d_in[17];
    const float* b2    = (const float*)d_in[18];
    const float* ln2g  = (const float*)d_in[19];
    const float* ln2b  = (const float*)d_in[20];

    char* p = (char*)d_ws;
    float*          biasmat = (float*)p;          p += (size_t)Bn*Nn*Nn*4;    // 2 MB
    float*          x       = (float*)p;          p += (size_t)Mn*En*4;       // 4 MB
    unsigned short* xb      = (unsigned short*)p; p += (size_t)Mn*En*2;       // 2 MB
    unsigned short* qkvb    = (unsigned short*)p; p += (size_t)Mn*QKV_LD*2;   // 6 MB
    unsigned short* Sffb    = (unsigned short*)p; p += (size_t)Mn*FFn*2;      // 8 MB
    unsigned short* attnb   = (unsigned short*)p; p += (size_t)Mn*En*2;       // 2 MB
    float*          yp      = (float*)p;          p += (size_t)4*Mn*En*4;     // 16 MB
    float*          lut     = (float*)p;          p += (size_t)(LUT_N+8)*4;
    unsigned short* wqkvb   = (unsigned short*)p; p += (size_t)Ln*QKV_LD*En*2;// 6.3 MB
    unsigned short* wob     = (unsigned short*)p; p += (size_t)Ln*En*En*2;    // 2.1 MB
    unsigned short* w1b     = (unsigned short*)p; p += (size_t)Ln*FFn*En*2;   // 8.4 MB
    unsigned short* w2b     = (unsigned short*)p; p += (size_t)Ln*En*FFn*2;   // 8.4 MB

    // one-shot weight conversion (single launch, 4 ranges)
    {
        CvtArgs a;
        a.src[0] = Wqkv; a.dst[0] = wqkvb; a.n4[0] = Ln * QKV_LD * En / 4;
        a.src[1] = Wo;   a.dst[1] = wob;   a.n4[1] = Ln * En * En / 4;
        a.src[2] = W1;   a.dst[2] = w1b;   a.n4[2] = Ln * FFn * En / 4;
        a.src[3] = W2;   a.dst[3] = w2b;   a.n4[3] = Ln * En * FFn / 4;
        a.blkoff[0] = 0;
        for (int i = 0; i < 4; ++i)
            a.blkoff[i + 1] = a.blkoff[i] + (a.n4[i] + 255) / 256;
        k_cvt<<<a.blkoff[4], 256, 0, stream>>>(a);
    }

    // embed + LUT build (single launch)
    k_embed_lut<<<Mn * En / 256 + (LUT_N + 256) / 256, 256, 0, stream>>>(
        tok, emb, x, xb, dp_w1, dp_b1, dp_w2, lut);
    k_distbias_lut<<<Bn * Nn * Nn / 256, 256, 0, stream>>>(dist, tok, lut, dp_b2,
                                                           biasmat);

    const long long yps = (long long)Mn * En;
    for (int l = 0; l < Ln; ++l) {
        const unsigned short* Wqkv_l = wqkvb + (size_t)l * QKV_LD * En;
        const float*          bqkv_l = bqkv  + (size_t)l * QKV_LD;
        const unsigned short* Wo_l   = wob   + (size_t)l * En * En;
        const unsigned short* W1_l   = w1b   + (size_t)l * FFn * En;
        const float*          b1_l   = b1    + (size_t)l * FFn;
        const unsigned short* W2_l   = w2b   + (size_t)l * En * FFn;

        // QKV: [2048,512] x [1536,512]^T -> bf16 [2048,1536]
        k_gemm<64, 64, 128, 0, 1>
            <<<dim3(Mn / 64, QKV_LD / 64), 256, 0, stream>>>(
            xb, En, Wqkv_l, En, bqkv_l, qkvb, QKV_LD, 0, En);

        // fused attention (V^T staged in-kernel) -> attnb
        k_attn<<<dim3(Nn / 64, Bn * Hn), 256, 0, stream>>>(qkvb, biasmat, attnb);

        // O projection, split-K x2 -> fp32 partials
        k_gemm<64, 64, 128, 3, 0>
            <<<dim3(Mn / 64, En / 64, 2), 256, 0, stream>>>(
            attnb, En, Wo_l, En, nullptr, yp, En, yps, En / 2);
        k_addln<0><<<Mn, 256, 0, stream>>>(x, yp, yps, 2,
                                           bo + (size_t)l * En,
                                           ln1g + (size_t)l * En, ln1b + (size_t)l * En,
                                           x, xb, tok);

        // FF1 + GELU
        k_gemm<64, 64, 128, 1, 1>
            <<<dim3(Mn / 64, FFn / 64), 256, 0, stream>>>(
            xb, En, W1_l, En, b1_l, Sffb, FFn, 0, En);

        // FF2, split-K x4 -> fp32 partials
        k_gemm<64, 64, 128, 3, 0>
            <<<dim3(Mn / 64, En / 64, 4), 256, 0, stream>>>(
            Sffb, FFn, W2_l, FFn, nullptr, yp, En, yps, FFn / 4);

        if (l < Ln - 1) {
            k_addln<0><<<Mn, 256, 0, stream>>>(x, yp, yps, 4,
                                               b2 + (size_t)l * En,
                                               ln2g + (size_t)l * En, ln2b + (size_t)l * En,
                                               x, xb, tok);
        } else {
            // final layer: write LN output + pad mask straight to d_out
            k_addln<1><<<Mn, 256, 0, stream>>>(x, yp, yps, 4,
                                               b2 + (size_t)l * En,
                                               ln2g + (size_t)l * En, ln2b + (size_t)l * En,
                                               (float*)d_out, nullptr, tok);
        }
    }
}

// Round 13
// 295.553 us; speedup vs baseline: 8.5515x; 1.0691x over previous
//
#include <hip/hip_runtime.h>
#include <hip/hip_bf16.h>

// ---------------------------------------------------------------------------
// SimpleGeoFormerModel: 4-layer transformer encoder. FP32 in/out; bf16
// activations + pre-converted bf16 weights; bf16 MFMA (fp32 accumulate).
// B=8 N=256 E=512 V=512 L=4 H=8 FF=2048, dh=64.
// Round 13: k_gemm staging via global_load_lds (width 16), linear LDS +
// inverse-swizzled global source + swizzled frag reads (pattern 21).
// ---------------------------------------------------------------------------

namespace {
constexpr int Bn  = 8;
constexpr int Nn  = 256;
constexpr int En  = 512;
constexpr int Ln  = 4;
constexpr int Hn  = 8;
constexpr int FFn = 2048;
constexpr int DHn = 64;
constexpr int Mn  = Bn * Nn;        // 2048 rows
constexpr int QKV_LD = 3 * En;      // 1536
constexpr int LUT_N = 4096;
}

typedef float f32x4 __attribute__((ext_vector_type(4)));
typedef short bf16x8 __attribute__((ext_vector_type(8)));

// fp32 -> bf16 round-to-nearest-even (finite inputs)
__device__ __forceinline__ unsigned short f2bs(float f) {
    union { float f; unsigned u; } v; v.f = f;
    unsigned r = v.u + 0x7FFFu + ((v.u >> 16) & 1u);
    return (unsigned short)(r >> 16);
}
__device__ __forceinline__ float bf2f(short s) {
    union { unsigned u; float f; } v;
    v.u = ((unsigned)(unsigned short)s) << 16;
    return v.f;
}

// swizzled byte address within a row-major bf16 LDS tile (16B-unit XOR)
__device__ __forceinline__ int swz(int row, int byte_in_row, int stride_b) {
    return row * stride_b + (byte_in_row ^ ((row & 7) << 4));
}

// async global->LDS, 16B per lane; LDS dest = wave-uniform base + lane*16
__device__ __forceinline__ void gload_lds16(const void* g, void* l) {
    __builtin_amdgcn_global_load_lds(
        (const __attribute__((address_space(1))) unsigned int*)g,
        (__attribute__((address_space(3))) unsigned int*)l,
        16, 0, 0);
}

// ---------------- one-shot weight conversion (4 ranges, 1 launch) ----------
struct CvtArgs {
    const float* src[4];
    unsigned short* dst[4];
    int n4[4];
    int blkoff[5];
};
__global__ __launch_bounds__(256) void k_cvt(CvtArgs a) {
    int bid = blockIdx.x;
    int r = 0;
    if (bid >= a.blkoff[1]) r = 1;
    if (bid >= a.blkoff[2]) r = 2;
    if (bid >= a.blkoff[3]) r = 3;
    int i = (bid - a.blkoff[r]) * 256 + threadIdx.x;
    if (i >= a.n4[r]) return;
    f32x4 v = *(const f32x4*)(a.src[r] + (size_t)i * 4);
    unsigned short o[4] = {f2bs(v[0]), f2bs(v[1]), f2bs(v[2]), f2bs(v[3])};
    *(unsigned long long*)(a.dst[r] + (size_t)i * 4) = *(unsigned long long*)o;
}

// ---------------- embed (blocks 0..Mn*En/256) + LUT build (rest) -----------
__global__ __launch_bounds__(256) void k_embed_lut(const int* __restrict__ tok,
                                                   const float* __restrict__ emb,
                                                   float* __restrict__ x,
                                                   unsigned short* __restrict__ xb,
                                                   const float* __restrict__ w1,
                                                   const float* __restrict__ b1,
                                                   const float* __restrict__ w2,
                                                   float* __restrict__ lut) {
    constexpr int EMB_BLOCKS = Mn * En / 256;
    if (blockIdx.x < EMB_BLOCKS) {
        int i = blockIdx.x * 256 + threadIdx.x;
        int m = i >> 9;
        int e = i & 511;
        float v = emb[tok[m] * En + e];
        x[i] = v;
        xb[i] = f2bs(v);
        return;
    }
    __shared__ float sw1[En], sb1[En], sw2[En];
    for (int e = threadIdx.x; e < En; e += 256) {
        sw1[e] = w1[e]; sb1[e] = b1[e]; sw2[e] = w2[e];
    }
    __syncthreads();
    int i = (blockIdx.x - EMB_BLOCKS) * 256 + threadIdx.x;
    if (i > LUT_N) return;
    float d = (float)i * (10.0f / (float)LUT_N);
    float acc = 0.f;
#pragma unroll 4
    for (int e = 0; e < En; ++e) {
        float s = fmaf(d, sw1[e], sb1[e]);
        float t = 1.f - 2.f / (__expf(2.f * s) + 1.f);
        acc = fmaf(t, sw2[e], acc);
    }
    lut[i] = acc;
}

// ---------------- distance bias via LUT ----------------
__global__ __launch_bounds__(256) void k_distbias_lut(const float* __restrict__ dist,
                                                      const int* __restrict__ tok,
                                                      const float* __restrict__ lut,
                                                      const float* __restrict__ b2,
                                                      float* __restrict__ biasmat) {
    int i = blockIdx.x * 256 + threadIdx.x;
    float d = dist[i];
    float idx = d * ((float)LUT_N / 10.0f);
    int ii = (int)idx;
    ii = ii < 0 ? 0 : (ii > LUT_N - 1 ? LUT_N - 1 : ii);
    float frac = idx - (float)ii;
    float v0 = lut[ii], v1 = lut[ii + 1];
    float acc = fmaf(v1 - v0, frac, v0) + b2[0];
    int k = i & (Nn - 1);
    int q = (i >> 8) & (Nn - 1);
    int b = i >> 16;
    bool pad = (tok[b * Nn + k] == 0) || (tok[b * Nn + q] == 0);
    biasmat[i] = pad ? -1e30f : acc;
}

// ---------------- fused attention (unchanged from round 12) ----------------
__global__ __launch_bounds__(256, 1) void k_attn(
        const unsigned short* __restrict__ qkvb,
        const float* __restrict__ biasmat,
        unsigned short* __restrict__ attnb) {
    __shared__ short Qs[64 * 64];
    __shared__ short Ks[256 * 64];
    __shared__ short Vs[64 * 256];
    __shared__ short Ps[64 * 256];

    const int tid = threadIdx.x;
    const int lane = tid & 63;
    const int wv = tid >> 6;
    const int q0 = blockIdx.x * 64;
    const int bh = blockIdx.y;
    const int b = bh >> 3, h = bh & 7;

    const unsigned short* Qg = qkvb + ((size_t)(b * Nn + q0)) * QKV_LD + h * DHn;
    const unsigned short* Kg = qkvb + ((size_t)(b * Nn)) * QKV_LD + En + h * DHn;
    const unsigned short* VgR = qkvb + ((size_t)(b * Nn)) * QKV_LD + 2 * En + h * DHn;

    {
        const char* src = (const char*)(Kg + (size_t)tid * QKV_LD);
#pragma unroll
        for (int c = 0; c < 8; ++c)
            *(bf16x8*)((char*)Ks + swz(tid, c * 16, 128)) =
                *(const bf16x8*)(src + c * 16);
    }
    {
        const char* src = (const char*)(VgR + (size_t)tid * QKV_LD);
#pragma unroll
        for (int c = 0; c < 8; ++c) {
            bf16x8 v = *(const bf16x8*)(src + c * 16);
#pragma unroll
            for (int j = 0; j < 8; ++j) {
                int d = c * 8 + j;
                *(short*)((char*)Vs + (d * 512 + ((tid * 2) ^ ((d & 7) << 4)))) = v[j];
            }
        }
    }
    {
        int r = tid & 63;
        const char* src = (const char*)(Qg + (size_t)r * QKV_LD);
#pragma unroll
        for (int i = 0; i < 2; ++i) {
            int cb = ((tid >> 6) * 2 + i) * 16;
            bf16x8 v = *(const bf16x8*)(src + cb);
            bf16x8 o;
#pragma unroll
            for (int j = 0; j < 8; ++j) o[j] = (short)f2bs(bf2f(v[j]) * 0.125f);
            *(bf16x8*)((char*)Qs + swz(r, cb, 128)) = o;
        }
    }

    const int qw = wv * 16;
    const int g  = lane >> 4;
    const int c  = lane & 15;
    f32x4 acc[16];
    {
        const float* bb = biasmat + ((size_t)b * Nn + (q0 + qw + g * 4)) * Nn;
#pragma unroll
        for (int f = 0; f < 16; ++f)
#pragma unroll
            for (int r = 0; r < 4; ++r)
                acc[f][r] = bb[(size_t)r * Nn + f * 16 + c];
    }

    __syncthreads();

    bf16x8 qa[2];
#pragma unroll
    for (int ks = 0; ks < 2; ++ks)
        qa[ks] = *(const bf16x8*)((const char*)Qs + swz(qw + c, ks * 64 + g * 16, 128));
#pragma unroll
    for (int f = 0; f < 16; ++f) {
#pragma unroll
        for (int ks = 0; ks < 2; ++ks) {
            bf16x8 kb = *(const bf16x8*)((const char*)Ks +
                         swz(f * 16 + c, ks * 64 + g * 16, 128));
            acc[f] = __builtin_amdgcn_mfma_f32_16x16x32_bf16(qa[ks], kb, acc[f], 0, 0, 0);
        }
    }

    float rcp[4];
#pragma unroll
    for (int r = 0; r < 4; ++r) {
        float m = acc[0][r];
#pragma unroll
        for (int f = 1; f < 16; ++f) m = fmaxf(m, acc[f][r]);
#pragma unroll
        for (int o = 1; o < 16; o <<= 1) m = fmaxf(m, __shfl_xor(m, o));
        float s = 0.f;
#pragma unroll
        for (int f = 0; f < 16; ++f) {
            float e = __expf(acc[f][r] - m);
            acc[f][r] = e;
            s += e;
        }
#pragma unroll
        for (int o = 1; o < 16; o <<= 1) s += __shfl_xor(s, o);
        rcp[r] = 1.f / s;
    }

#pragma unroll
    for (int f = 0; f < 16; ++f)
#pragma unroll
        for (int r = 0; r < 4; ++r) {
            int q = qw + g * 4 + r;
            int kx = f * 16 + c;
            *(unsigned short*)((char*)Ps + (q * 512 + ((kx * 2) ^ ((q & 7) << 4)))) =
                f2bs(acc[f][r] * rcp[r]);
        }

    f32x4 acc2[4];
#pragma unroll
    for (int fd = 0; fd < 4; ++fd) acc2[fd] = {0.f, 0.f, 0.f, 0.f};
#pragma unroll
    for (int ks2 = 0; ks2 < 8; ++ks2) {
        bf16x8 pa = *(const bf16x8*)((const char*)Ps +
                      swz(qw + c, ks2 * 64 + g * 16, 512));
#pragma unroll
        for (int fd = 0; fd < 4; ++fd) {
            bf16x8 vb = *(const bf16x8*)((const char*)Vs +
                          swz(fd * 16 + c, ks2 * 64 + g * 16, 512));
            acc2[fd] = __builtin_amdgcn_mfma_f32_16x16x32_bf16(pa, vb, acc2[fd], 0, 0, 0);
        }
    }

    unsigned short* Cg = attnb + ((size_t)(b * Nn + q0 + qw)) * En + h * DHn;
#pragma unroll
    for (int fd = 0; fd < 4; ++fd)
#pragma unroll
        for (int r = 0; r < 4; ++r)
            Cg[(size_t)(g * 4 + r) * En + fd * 16 + c] = f2bs(acc2[fd][r]);
}

// ---------------- MFMA GEMM, bf16 operands, global_load_lds staging --------
// C = A*B^T (+epilogue). MODE 0: +bias[n]; 1: gelu(+bias[n]); 3: raw fp32
// partial (split-K via blockIdx.z). CBF: bf16 output. 64x64 tile, BK=128.
// LDS linear [64][128]; global source chunk-XOR'd so swizzled reads are
// conflict-free (pattern: linear dest + inverse-swz source + swz read).
template <int BM, int BN, int BK, int MODE, int CBF>
__global__ __launch_bounds__(256) void k_gemm(
        const unsigned short* __restrict__ A, int lda,
        const unsigned short* __restrict__ Bw, int ldb,
        const float* __restrict__ bias,
        void* __restrict__ Cp, int ldc, long long sCz,
        int K) {
    static_assert(BM == 64 && BN == 64 && BK == 128, "fixed geometry");
    __shared__ short As[64 * 128];   // 16 KB, 256 B/row, linear
    __shared__ short Bs[64 * 128];

    const int tid  = threadIdx.x;
    const int lane = tid & 63;
    const int wv   = tid >> 6;
    const int wr   = wv >> 1, wc = wv & 1;      // 2x2 wave grid, 32x32/wave
    const int m0 = blockIdx.x * BM, n0 = blockIdx.y * BN;
    const int z  = blockIdx.z;

    // staging: wave wv covers rows [wv*16, wv*16+16), 4 rows per instruction
    const int r_in = lane >> 4;                 // row within 4-row group
    const int ch   = lane & 15;                 // 16B chunk within 256B row

    f32x4 acc[2][2];
#pragma unroll
    for (int i = 0; i < 2; ++i)
#pragma unroll
        for (int j = 0; j < 2; ++j) acc[i][j] = {0.f, 0.f, 0.f, 0.f};

    const int fkb  = (lane >> 4) * 16;          // frag k byte offset
    const int frow = lane & 15;

    const size_t koff = (size_t)z * K;          // split-K slice (elements)
    const int nt = K / BK;
    for (int t = 0; t < nt; ++t) {
        const size_t cb = (koff + (size_t)t * BK) * 2;   // col byte base
#pragma unroll
        for (int i = 0; i < 4; ++i) {
            const int tr = wv * 16 + i * 4 + r_in;       // tile-local row
            const char* ga = (const char*)A +
                (size_t)(m0 + tr) * lda * 2 + cb + ((ch ^ (tr & 7)) << 4);
            gload_lds16(ga, &As[(wv * 16 + i * 4) * 128]);
        }
#pragma unroll
        for (int i = 0; i < 4; ++i) {
            const int tr = wv * 16 + i * 4 + r_in;
            const char* gb = (const char*)Bw +
                (size_t)(n0 + tr) * ldb * 2 + cb + ((ch ^ (tr & 7)) << 4);
            gload_lds16(gb, &Bs[(wv * 16 + i * 4) * 128]);
        }
        __syncthreads();   // drains vmcnt (loads landed) before reads

#pragma unroll
        for (int ks = 0; ks < 4; ++ks) {
            bf16x8 af[2], bfr[2];
#pragma unroll
            for (int i = 0; i < 2; ++i)
                af[i] = *(const bf16x8*)((const char*)As +
                         swz(wr * 32 + i * 16 + frow, ks * 64 + fkb, 256));
#pragma unroll
            for (int j = 0; j < 2; ++j)
                bfr[j] = *(const bf16x8*)((const char*)Bs +
                          swz(wc * 32 + j * 16 + frow, ks * 64 + fkb, 256));
#pragma unroll
            for (int i = 0; i < 2; ++i)
#pragma unroll
                for (int j = 0; j < 2; ++j)
                    acc[i][j] = __builtin_amdgcn_mfma_f32_16x16x32_bf16(
                        af[i], bfr[j], acc[i][j], 0, 0, 0);
        }
        __syncthreads();   // reads done before next tile's DMA writes
    }

#pragma unroll
    for (int i = 0; i < 2; ++i) {
#pragma unroll
        for (int j = 0; j < 2; ++j) {
            const int n = n0 + wc * 32 + j * 16 + (lane & 15);
            float bv = 0.f;
            if constexpr (MODE == 0 || MODE == 1) bv = bias[n];
#pragma unroll
            for (int r = 0; r < 4; ++r) {
                const int m = m0 + wr * 32 + i * 16 + (lane >> 4) * 4 + r;
                float v = acc[i][j][r] + bv;
                if constexpr (MODE == 1)
                    v = 0.5f * v * (1.f + erff(v * 0.70710678118654752f));
                if constexpr (CBF)
                    ((unsigned short*)Cp)[(size_t)m * ldc + n] = f2bs(v);
                else
                    ((float*)Cp)[(size_t)z * sCz + (size_t)m * ldc + n] = v;
            }
        }
    }
}

// ---------------- residual + split-K sum + bias + LayerNorm (+final out) ---
template <int FINAL>
__global__ __launch_bounds__(256) void k_addln(
        const float* __restrict__ xin,
        const float* __restrict__ yp, long long ystride, int nsplit,
        const float* __restrict__ biasv,
        const float* __restrict__ g, const float* __restrict__ bb,
        float* __restrict__ xout, unsigned short* __restrict__ xbf,
        const int* __restrict__ tok) {
    const int row = blockIdx.x;
    const int tid = threadIdx.x;
    const size_t base = (size_t)row * En;
    float v0 = xin[base + tid] + biasv[tid];
    float v1 = xin[base + tid + 256] + biasv[tid + 256];
    for (int s = 0; s < nsplit; ++s) {
        v0 += yp[(size_t)s * ystride + base + tid];
        v1 += yp[(size_t)s * ystride + base + tid + 256];
    }
    float s1 = v0 + v1;
    float s2 = v0 * v0 + v1 * v1;
#pragma unroll
    for (int o = 32; o; o >>= 1) {
        s1 += __shfl_xor(s1, o);
        s2 += __shfl_xor(s2, o);
    }
    __shared__ float ws1[4], ws2[4];
    int w = tid >> 6;
    if ((tid & 63) == 0) { ws1[w] = s1; ws2[w] = s2; }
    __syncthreads();
    s1 = (ws1[0] + ws1[1]) + (ws1[2] + ws1[3]);
    s2 = (ws2[0] + ws2[1]) + (ws2[2] + ws2[3]);
    const float rE = 1.f / (float)En;
    float mean = s1 * rE;
    float var = s2 * rE - mean * mean;
    float inv = rsqrtf(var + 1e-5f);
    float o0 = (v0 - mean) * inv * g[tid] + bb[tid];
    float o1 = (v1 - mean) * inv * g[tid + 256] + bb[tid + 256];
    xout[base + tid]       = o0;
    xout[base + tid + 256] = o1;
    if constexpr (FINAL) {
        if (tid == 0)
            xout[(size_t)Mn * En + row] = (tok[row] == 0) ? 1.f : 0.f;
    } else {
        xbf[base + tid]       = f2bs(o0);
        xbf[base + tid + 256] = f2bs(o1);
    }
}

// ---------------------------------------------------------------------------
extern "C" void kernel_launch(void* const* d_in, const int* in_sizes, int n_in,
                              void* d_out, int out_size, void* d_ws, size_t ws_size,
                              hipStream_t stream) {
    const int*   tok   = (const int*)  d_in[0];
    const float* dist  = (const float*)d_in[2];
    const float* emb   = (const float*)d_in[4];
    const float* dp_w1 = (const float*)d_in[5];
    const float* dp_b1 = (const float*)d_in[6];
    const float* dp_w2 = (const float*)d_in[7];
    const float* dp_b2 = (const float*)d_in[8];
    const float* Wqkv  = (const float*)d_in[9];
    const float* bqkv  = (const float*)d_in[10];
    const float* Wo    = (const float*)d_in[11];
    const float* bo    = (const float*)d_in[12];
    const float* ln1g  = (const float*)d_in[13];
    const float* ln1b  = (const float*)d_in[14];
    const float* W1    = (const float*)d_in[15];
    const float* b1    = (const float*)d_in[16];
    const float* W2    = (const float*)d_in[17];
    const float* b2    = (const float*)d_in[18];
    const float* ln2g  = (const float*)d_in[19];
    const float* ln2b  = (const float*)d_in[20];

    char* p = (char*)d_ws;
    float*          biasmat = (float*)p;          p += (size_t)Bn*Nn*Nn*4;    // 2 MB
    float*          x       = (float*)p;          p += (size_t)Mn*En*4;       // 4 MB
    unsigned short* xb      = (unsigned short*)p; p += (size_t)Mn*En*2;       // 2 MB
    unsigned short* qkvb    = (unsigned short*)p; p += (size_t)Mn*QKV_LD*2;   // 6 MB
    unsigned short* Sffb    = (unsigned short*)p; p += (size_t)Mn*FFn*2;      // 8 MB
    unsigned short* attnb   = (unsigned short*)p; p += (size_t)Mn*En*2;       // 2 MB
    float*          yp      = (float*)p;          p += (size_t)4*Mn*En*4;     // 16 MB
    float*          lut     = (float*)p;          p += (size_t)(LUT_N+8)*4;
    unsigned short* wqkvb   = (unsigned short*)p; p += (size_t)Ln*QKV_LD*En*2;// 6.3 MB
    unsigned short* wob     = (unsigned short*)p; p += (size_t)Ln*En*En*2;    // 2.1 MB
    unsigned short* w1b     = (unsigned short*)p; p += (size_t)Ln*FFn*En*2;   // 8.4 MB
    unsigned short* w2b     = (unsigned short*)p; p += (size_t)Ln*En*FFn*2;   // 8.4 MB

    // one-shot weight conversion (single launch, 4 ranges)
    {
        CvtArgs a;
        a.src[0] = Wqkv; a.dst[0] = wqkvb; a.n4[0] = Ln * QKV_LD * En / 4;
        a.src[1] = Wo;   a.dst[1] = wob;   a.n4[1] = Ln * En * En / 4;
        a.src[2] = W1;   a.dst[2] = w1b;   a.n4[2] = Ln * FFn * En / 4;
        a.src[3] = W2;   a.dst[3] = w2b;   a.n4[3] = Ln * En * FFn / 4;
        a.blkoff[0] = 0;
        for (int i = 0; i < 4; ++i)
            a.blkoff[i + 1] = a.blkoff[i] + (a.n4[i] + 255) / 256;
        k_cvt<<<a.blkoff[4], 256, 0, stream>>>(a);
    }

    // embed + LUT build (single launch)
    k_embed_lut<<<Mn * En / 256 + (LUT_N + 256) / 256, 256, 0, stream>>>(
        tok, emb, x, xb, dp_w1, dp_b1, dp_w2, lut);
    k_distbias_lut<<<Bn * Nn * Nn / 256, 256, 0, stream>>>(dist, tok, lut, dp_b2,
                                                           biasmat);

    const long long yps = (long long)Mn * En;
    for (int l = 0; l < Ln; ++l) {
        const unsigned short* Wqkv_l = wqkvb + (size_t)l * QKV_LD * En;
        const float*          bqkv_l = bqkv  + (size_t)l * QKV_LD;
        const unsigned short* Wo_l   = wob   + (size_t)l * En * En;
        const unsigned short* W1_l   = w1b   + (size_t)l * FFn * En;
        const float*          b1_l   = b1    + (size_t)l * FFn;
        const unsigned short* W2_l   = w2b   + (size_t)l * En * FFn;

        // QKV: [2048,512] x [1536,512]^T -> bf16 [2048,1536]
        k_gemm<64, 64, 128, 0, 1>
            <<<dim3(Mn / 64, QKV_LD / 64), 256, 0, stream>>>(
            xb, En, Wqkv_l, En, bqkv_l, qkvb, QKV_LD, 0, En);

        // fused attention (V^T staged in-kernel) -> attnb
        k_attn<<<dim3(Nn / 64, Bn * Hn), 256, 0, stream>>>(qkvb, biasmat, attnb);

        // O projection, split-K x2 -> fp32 partials
        k_gemm<64, 64, 128, 3, 0>
            <<<dim3(Mn / 64, En / 64, 2), 256, 0, stream>>>(
            attnb, En, Wo_l, En, nullptr, yp, En, yps, En / 2);
        k_addln<0><<<Mn, 256, 0, stream>>>(x, yp, yps, 2,
                                           bo + (size_t)l * En,
                                           ln1g + (size_t)l * En, ln1b + (size_t)l * En,
                                           x, xb, tok);

        // FF1 + GELU
        k_gemm<64, 64, 128, 1, 1>
            <<<dim3(Mn / 64, FFn / 64), 256, 0, stream>>>(
            xb, En, W1_l, En, b1_l, Sffb, FFn, 0, En);

        // FF2, split-K x4 -> fp32 partials
        k_gemm<64, 64, 128, 3, 0>
            <<<dim3(Mn / 64, En / 64, 4), 256, 0, stream>>>(
            Sffb, FFn, W2_l, FFn, nullptr, yp, En, yps, FFn / 4);

        if (l < Ln - 1) {
            k_addln<0><<<Mn, 256, 0, stream>>>(x, yp, yps, 4,
                                               b2 + (size_t)l * En,
                                               ln2g + (size_t)l * En, ln2b + (size_t)l * En,
                                               x, xb, tok);
        } else {
            // final layer: write LN output + pad mask straight to d_out
            k_addln<1><<<Mn, 256, 0, stream>>>(x, yp, yps, 4,
                                               b2 + (size_t)l * En,
                                               ln2g + (size_t)l * En, ln2b + (size_t)l * En,
                                               (float*)d_out, nullptr, tok);
        }
    }
}

// Round 14
// 294.131 us; speedup vs baseline: 8.5929x; 1.0048x over previous
//
#include <hip/hip_runtime.h>
#include <hip/hip_bf16.h>

// ---------------------------------------------------------------------------
// SimpleGeoFormerModel: 4-layer transformer encoder. FP32 in/out; bf16
// activations + pre-converted bf16 weights; bf16 MFMA (fp32 accumulate).
// B=8 N=256 E=512 V=512 L=4 H=8 FF=2048, dh=64.
// Round 14: k_gemm -> 2-phase double-buffered global_load_lds pipeline
// (BK=64, early stage issue, one barrier per K-step). Rest unchanged.
// ---------------------------------------------------------------------------

namespace {
constexpr int Bn  = 8;
constexpr int Nn  = 256;
constexpr int En  = 512;
constexpr int Ln  = 4;
constexpr int Hn  = 8;
constexpr int FFn = 2048;
constexpr int DHn = 64;
constexpr int Mn  = Bn * Nn;        // 2048 rows
constexpr int QKV_LD = 3 * En;      // 1536
constexpr int LUT_N = 4096;
}

typedef float f32x4 __attribute__((ext_vector_type(4)));
typedef short bf16x8 __attribute__((ext_vector_type(8)));

// fp32 -> bf16 round-to-nearest-even (finite inputs)
__device__ __forceinline__ unsigned short f2bs(float f) {
    union { float f; unsigned u; } v; v.f = f;
    unsigned r = v.u + 0x7FFFu + ((v.u >> 16) & 1u);
    return (unsigned short)(r >> 16);
}
__device__ __forceinline__ float bf2f(short s) {
    union { unsigned u; float f; } v;
    v.u = ((unsigned)(unsigned short)s) << 16;
    return v.f;
}

// swizzled byte address within a row-major bf16 LDS tile (16B-unit XOR)
__device__ __forceinline__ int swz(int row, int byte_in_row, int stride_b) {
    return row * stride_b + (byte_in_row ^ ((row & 7) << 4));
}

// async global->LDS, 16B per lane; LDS dest = wave-uniform base + lane*16
__device__ __forceinline__ void gload_lds16(const void* g, void* l) {
    __builtin_amdgcn_global_load_lds(
        (const __attribute__((address_space(1))) unsigned int*)g,
        (__attribute__((address_space(3))) unsigned int*)l,
        16, 0, 0);
}

// ---------------- one-shot weight conversion (4 ranges, 1 launch) ----------
struct CvtArgs {
    const float* src[4];
    unsigned short* dst[4];
    int n4[4];
    int blkoff[5];
};
__global__ __launch_bounds__(256) void k_cvt(CvtArgs a) {
    int bid = blockIdx.x;
    int r = 0;
    if (bid >= a.blkoff[1]) r = 1;
    if (bid >= a.blkoff[2]) r = 2;
    if (bid >= a.blkoff[3]) r = 3;
    int i = (bid - a.blkoff[r]) * 256 + threadIdx.x;
    if (i >= a.n4[r]) return;
    f32x4 v = *(const f32x4*)(a.src[r] + (size_t)i * 4);
    unsigned short o[4] = {f2bs(v[0]), f2bs(v[1]), f2bs(v[2]), f2bs(v[3])};
    *(unsigned long long*)(a.dst[r] + (size_t)i * 4) = *(unsigned long long*)o;
}

// ---------------- embed (blocks 0..Mn*En/256) + LUT build (rest) -----------
__global__ __launch_bounds__(256) void k_embed_lut(const int* __restrict__ tok,
                                                   const float* __restrict__ emb,
                                                   float* __restrict__ x,
                                                   unsigned short* __restrict__ xb,
                                                   const float* __restrict__ w1,
                                                   const float* __restrict__ b1,
                                                   const float* __restrict__ w2,
                                                   float* __restrict__ lut) {
    constexpr int EMB_BLOCKS = Mn * En / 256;
    if (blockIdx.x < EMB_BLOCKS) {
        int i = blockIdx.x * 256 + threadIdx.x;
        int m = i >> 9;
        int e = i & 511;
        float v = emb[tok[m] * En + e];
        x[i] = v;
        xb[i] = f2bs(v);
        return;
    }
    __shared__ float sw1[En], sb1[En], sw2[En];
    for (int e = threadIdx.x; e < En; e += 256) {
        sw1[e] = w1[e]; sb1[e] = b1[e]; sw2[e] = w2[e];
    }
    __syncthreads();
    int i = (blockIdx.x - EMB_BLOCKS) * 256 + threadIdx.x;
    if (i > LUT_N) return;
    float d = (float)i * (10.0f / (float)LUT_N);
    float acc = 0.f;
#pragma unroll 4
    for (int e = 0; e < En; ++e) {
        float s = fmaf(d, sw1[e], sb1[e]);
        float t = 1.f - 2.f / (__expf(2.f * s) + 1.f);
        acc = fmaf(t, sw2[e], acc);
    }
    lut[i] = acc;
}

// ---------------- distance bias via LUT ----------------
__global__ __launch_bounds__(256) void k_distbias_lut(const float* __restrict__ dist,
                                                      const int* __restrict__ tok,
                                                      const float* __restrict__ lut,
                                                      const float* __restrict__ b2,
                                                      float* __restrict__ biasmat) {
    int i = blockIdx.x * 256 + threadIdx.x;
    float d = dist[i];
    float idx = d * ((float)LUT_N / 10.0f);
    int ii = (int)idx;
    ii = ii < 0 ? 0 : (ii > LUT_N - 1 ? LUT_N - 1 : ii);
    float frac = idx - (float)ii;
    float v0 = lut[ii], v1 = lut[ii + 1];
    float acc = fmaf(v1 - v0, frac, v0) + b2[0];
    int k = i & (Nn - 1);
    int q = (i >> 8) & (Nn - 1);
    int b = i >> 16;
    bool pad = (tok[b * Nn + k] == 0) || (tok[b * Nn + q] == 0);
    biasmat[i] = pad ? -1e30f : acc;
}

// ---------------- fused attention (unchanged from round 12) ----------------
__global__ __launch_bounds__(256, 1) void k_attn(
        const unsigned short* __restrict__ qkvb,
        const float* __restrict__ biasmat,
        unsigned short* __restrict__ attnb) {
    __shared__ short Qs[64 * 64];
    __shared__ short Ks[256 * 64];
    __shared__ short Vs[64 * 256];
    __shared__ short Ps[64 * 256];

    const int tid = threadIdx.x;
    const int lane = tid & 63;
    const int wv = tid >> 6;
    const int q0 = blockIdx.x * 64;
    const int bh = blockIdx.y;
    const int b = bh >> 3, h = bh & 7;

    const unsigned short* Qg = qkvb + ((size_t)(b * Nn + q0)) * QKV_LD + h * DHn;
    const unsigned short* Kg = qkvb + ((size_t)(b * Nn)) * QKV_LD + En + h * DHn;
    const unsigned short* VgR = qkvb + ((size_t)(b * Nn)) * QKV_LD + 2 * En + h * DHn;

    {
        const char* src = (const char*)(Kg + (size_t)tid * QKV_LD);
#pragma unroll
        for (int c = 0; c < 8; ++c)
            *(bf16x8*)((char*)Ks + swz(tid, c * 16, 128)) =
                *(const bf16x8*)(src + c * 16);
    }
    {
        const char* src = (const char*)(VgR + (size_t)tid * QKV_LD);
#pragma unroll
        for (int c = 0; c < 8; ++c) {
            bf16x8 v = *(const bf16x8*)(src + c * 16);
#pragma unroll
            for (int j = 0; j < 8; ++j) {
                int d = c * 8 + j;
                *(short*)((char*)Vs + (d * 512 + ((tid * 2) ^ ((d & 7) << 4)))) = v[j];
            }
        }
    }
    {
        int r = tid & 63;
        const char* src = (const char*)(Qg + (size_t)r * QKV_LD);
#pragma unroll
        for (int i = 0; i < 2; ++i) {
            int cb = ((tid >> 6) * 2 + i) * 16;
            bf16x8 v = *(const bf16x8*)(src + cb);
            bf16x8 o;
#pragma unroll
            for (int j = 0; j < 8; ++j) o[j] = (short)f2bs(bf2f(v[j]) * 0.125f);
            *(bf16x8*)((char*)Qs + swz(r, cb, 128)) = o;
        }
    }

    const int qw = wv * 16;
    const int g  = lane >> 4;
    const int c  = lane & 15;
    f32x4 acc[16];
    {
        const float* bb = biasmat + ((size_t)b * Nn + (q0 + qw + g * 4)) * Nn;
#pragma unroll
        for (int f = 0; f < 16; ++f)
#pragma unroll
            for (int r = 0; r < 4; ++r)
                acc[f][r] = bb[(size_t)r * Nn + f * 16 + c];
    }

    __syncthreads();

    bf16x8 qa[2];
#pragma unroll
    for (int ks = 0; ks < 2; ++ks)
        qa[ks] = *(const bf16x8*)((const char*)Qs + swz(qw + c, ks * 64 + g * 16, 128));
#pragma unroll
    for (int f = 0; f < 16; ++f) {
#pragma unroll
        for (int ks = 0; ks < 2; ++ks) {
            bf16x8 kb = *(const bf16x8*)((const char*)Ks +
                         swz(f * 16 + c, ks * 64 + g * 16, 128));
            acc[f] = __builtin_amdgcn_mfma_f32_16x16x32_bf16(qa[ks], kb, acc[f], 0, 0, 0);
        }
    }

    float rcp[4];
#pragma unroll
    for (int r = 0; r < 4; ++r) {
        float m = acc[0][r];
#pragma unroll
        for (int f = 1; f < 16; ++f) m = fmaxf(m, acc[f][r]);
#pragma unroll
        for (int o = 1; o < 16; o <<= 1) m = fmaxf(m, __shfl_xor(m, o));
        float s = 0.f;
#pragma unroll
        for (int f = 0; f < 16; ++f) {
            float e = __expf(acc[f][r] - m);
            acc[f][r] = e;
            s += e;
        }
#pragma unroll
        for (int o = 1; o < 16; o <<= 1) s += __shfl_xor(s, o);
        rcp[r] = 1.f / s;
    }

#pragma unroll
    for (int f = 0; f < 16; ++f)
#pragma unroll
        for (int r = 0; r < 4; ++r) {
            int q = qw + g * 4 + r;
            int kx = f * 16 + c;
            *(unsigned short*)((char*)Ps + (q * 512 + ((kx * 2) ^ ((q & 7) << 4)))) =
                f2bs(acc[f][r] * rcp[r]);
        }

    f32x4 acc2[4];
#pragma unroll
    for (int fd = 0; fd < 4; ++fd) acc2[fd] = {0.f, 0.f, 0.f, 0.f};
#pragma unroll
    for (int ks2 = 0; ks2 < 8; ++ks2) {
        bf16x8 pa = *(const bf16x8*)((const char*)Ps +
                      swz(qw + c, ks2 * 64 + g * 16, 512));
#pragma unroll
        for (int fd = 0; fd < 4; ++fd) {
            bf16x8 vb = *(const bf16x8*)((const char*)Vs +
                          swz(fd * 16 + c, ks2 * 64 + g * 16, 512));
            acc2[fd] = __builtin_amdgcn_mfma_f32_16x16x32_bf16(pa, vb, acc2[fd], 0, 0, 0);
        }
    }

    unsigned short* Cg = attnb + ((size_t)(b * Nn + q0 + qw)) * En + h * DHn;
#pragma unroll
    for (int fd = 0; fd < 4; ++fd)
#pragma unroll
        for (int r = 0; r < 4; ++r)
            Cg[(size_t)(g * 4 + r) * En + fd * 16 + c] = f2bs(acc2[fd][r]);
}

// ---------------- MFMA GEMM: 2-phase dbuf global_load_lds pipeline ---------
// C = A*B^T (+epilogue). MODE 0: +bias[n]; 1: gelu(+bias[n]); 3: raw fp32
// partial (split-K via blockIdx.z). CBF: bf16 output. 64x64 tile, BK=64.
// LDS linear [64][128B] x2 buffers; inverse-swz global source + swz reads.
// Pipeline: stage(t+1, alt) issued BEFORE compute(t); ONE barrier per step
// (its implicit vmcnt(0)/lgkmcnt(0) drain orders both buffers).
template <int BM, int BN, int BK, int MODE, int CBF>
__global__ __launch_bounds__(256) void k_gemm(
        const unsigned short* __restrict__ A, int lda,
        const unsigned short* __restrict__ Bw, int ldb,
        const float* __restrict__ bias,
        void* __restrict__ Cp, int ldc, long long sCz,
        int K) {
    static_assert(BM == 64 && BN == 64 && BK == 64, "fixed geometry");
    __shared__ short As[2][64 * 64];   // 8 KB per buffer, 128 B/row, linear
    __shared__ short Bs[2][64 * 64];

    const int tid  = threadIdx.x;
    const int lane = tid & 63;
    const int wv   = tid >> 6;
    const int wr   = wv >> 1, wc = wv & 1;      // 2x2 wave grid, 32x32/wave
    const int m0 = blockIdx.x * BM, n0 = blockIdx.y * BN;
    const int z  = blockIdx.z;

    const int r_in = lane >> 3;                 // row within 8-row DMA group
    const int ch   = lane & 7;                  // 16B chunk within 128B row
    const size_t koff2 = (size_t)z * K * 2;     // split-K slice byte offset

    // stage one 64x64 bf16 tile pair into buffer d (4 gload_lds per wave)
    auto stage = [&](int t, int d) {
        const size_t cb = koff2 + (size_t)t * BK * 2;
#pragma unroll
        for (int q = 0; q < 2; ++q) {
            const int rb = q * 32 + wv * 8;               // wave's row base
            const char* ga = (const char*)A +
                (size_t)(m0 + rb + r_in) * lda * 2 + cb + ((ch ^ r_in) << 4);
            gload_lds16(ga, &As[d][rb * 64]);
        }
#pragma unroll
        for (int q = 0; q < 2; ++q) {
            const int rb = q * 32 + wv * 8;
            const char* gb = (const char*)Bw +
                (size_t)(n0 + rb + r_in) * ldb * 2 + cb + ((ch ^ r_in) << 4);
            gload_lds16(gb, &Bs[d][rb * 64]);
        }
    };

    f32x4 acc[2][2];
#pragma unroll
    for (int i = 0; i < 2; ++i)
#pragma unroll
        for (int j = 0; j < 2; ++j) acc[i][j] = {0.f, 0.f, 0.f, 0.f};

    const int fkb  = (lane >> 4) * 16;          // frag k byte offset
    const int frow = lane & 15;

    stage(0, 0);
    __syncthreads();                            // tile 0 landed

    int cur = 0;
    const int nt = K / BK;
    for (int t = 0; t < nt; ++t) {
        if (t + 1 < nt) stage(t + 1, cur ^ 1);  // issue BEFORE compute
#pragma unroll
        for (int ks = 0; ks < 2; ++ks) {
            bf16x8 af[2], bfr[2];
#pragma unroll
            for (int i = 0; i < 2; ++i)
                af[i] = *(const bf16x8*)((const char*)As[cur] +
                         swz(wr * 32 + i * 16 + frow, ks * 64 + fkb, 128));
#pragma unroll
            for (int j = 0; j < 2; ++j)
                bfr[j] = *(const bf16x8*)((const char*)Bs[cur] +
                          swz(wc * 32 + j * 16 + frow, ks * 64 + fkb, 128));
#pragma unroll
            for (int i = 0; i < 2; ++i)
#pragma unroll
                for (int j = 0; j < 2; ++j)
                    acc[i][j] = __builtin_amdgcn_mfma_f32_16x16x32_bf16(
                        af[i], bfr[j], acc[i][j], 0, 0, 0);
        }
        __syncthreads();   // reads of cur done + staged alt landed (vmcnt0)
        cur ^= 1;
    }

#pragma unroll
    for (int i = 0; i < 2; ++i) {
#pragma unroll
        for (int j = 0; j < 2; ++j) {
            const int n = n0 + wc * 32 + j * 16 + (lane & 15);
            float bv = 0.f;
            if constexpr (MODE == 0 || MODE == 1) bv = bias[n];
#pragma unroll
            for (int r = 0; r < 4; ++r) {
                const int m = m0 + wr * 32 + i * 16 + (lane >> 4) * 4 + r;
                float v = acc[i][j][r] + bv;
                if constexpr (MODE == 1)
                    v = 0.5f * v * (1.f + erff(v * 0.70710678118654752f));
                if constexpr (CBF)
                    ((unsigned short*)Cp)[(size_t)m * ldc + n] = f2bs(v);
                else
                    ((float*)Cp)[(size_t)z * sCz + (size_t)m * ldc + n] = v;
            }
        }
    }
}

// ---------------- residual + split-K sum + bias + LayerNorm (+final out) ---
template <int FINAL>
__global__ __launch_bounds__(256) void k_addln(
        const float* __restrict__ xin,
        const float* __restrict__ yp, long long ystride, int nsplit,
        const float* __restrict__ biasv,
        const float* __restrict__ g, const float* __restrict__ bb,
        float* __restrict__ xout, unsigned short* __restrict__ xbf,
        const int* __restrict__ tok) {
    const int row = blockIdx.x;
    const int tid = threadIdx.x;
    const size_t base = (size_t)row * En;
    float v0 = xin[base + tid] + biasv[tid];
    float v1 = xin[base + tid + 256] + biasv[tid + 256];
    for (int s = 0; s < nsplit; ++s) {
        v0 += yp[(size_t)s * ystride + base + tid];
        v1 += yp[(size_t)s * ystride + base + tid + 256];
    }
    float s1 = v0 + v1;
    float s2 = v0 * v0 + v1 * v1;
#pragma unroll
    for (int o = 32; o; o >>= 1) {
        s1 += __shfl_xor(s1, o);
        s2 += __shfl_xor(s2, o);
    }
    __shared__ float ws1[4], ws2[4];
    int w = tid >> 6;
    if ((tid & 63) == 0) { ws1[w] = s1; ws2[w] = s2; }
    __syncthreads();
    s1 = (ws1[0] + ws1[1]) + (ws1[2] + ws1[3]);
    s2 = (ws2[0] + ws2[1]) + (ws2[2] + ws2[3]);
    const float rE = 1.f / (float)En;
    float mean = s1 * rE;
    float var = s2 * rE - mean * mean;
    float inv = rsqrtf(var + 1e-5f);
    float o0 = (v0 - mean) * inv * g[tid] + bb[tid];
    float o1 = (v1 - mean) * inv * g[tid + 256] + bb[tid + 256];
    xout[base + tid]       = o0;
    xout[base + tid + 256] = o1;
    if constexpr (FINAL) {
        if (tid == 0)
            xout[(size_t)Mn * En + row] = (tok[row] == 0) ? 1.f : 0.f;
    } else {
        xbf[base + tid]       = f2bs(o0);
        xbf[base + tid + 256] = f2bs(o1);
    }
}

// ---------------------------------------------------------------------------
extern "C" void kernel_launch(void* const* d_in, const int* in_sizes, int n_in,
                              void* d_out, int out_size, void* d_ws, size_t ws_size,
                              hipStream_t stream) {
    const int*   tok   = (const int*)  d_in[0];
    const float* dist  = (const float*)d_in[2];
    const float* emb   = (const float*)d_in[4];
    const float* dp_w1 = (const float*)d_in[5];
    const float* dp_b1 = (const float*)d_in[6];
    const float* dp_w2 = (const float*)d_in[7];
    const float* dp_b2 = (const float*)d_in[8];
    const float* Wqkv  = (const float*)d_in[9];
    const float* bqkv  = (const float*)d_in[10];
    const float* Wo    = (const float*)d_in[11];
    const float* bo    = (const float*)d_in[12];
    const float* ln1g  = (const float*)d_in[13];
    const float* ln1b  = (const float*)d_in[14];
    const float* W1    = (const float*)d_in[15];
    const float* b1    = (const float*)d_in[16];
    const float* W2    = (const float*)d_in[17];
    const float* b2    = (const float*)d_in[18];
    const float* ln2g  = (const float*)d_in[19];
    const float* ln2b  = (const float*)d_in[20];

    char* p = (char*)d_ws;
    float*          biasmat = (float*)p;          p += (size_t)Bn*Nn*Nn*4;    // 2 MB
    float*          x       = (float*)p;          p += (size_t)Mn*En*4;       // 4 MB
    unsigned short* xb      = (unsigned short*)p; p += (size_t)Mn*En*2;       // 2 MB
    unsigned short* qkvb    = (unsigned short*)p; p += (size_t)Mn*QKV_LD*2;   // 6 MB
    unsigned short* Sffb    = (unsigned short*)p; p += (size_t)Mn*FFn*2;      // 8 MB
    unsigned short* attnb   = (unsigned short*)p; p += (size_t)Mn*En*2;       // 2 MB
    float*          yp      = (float*)p;          p += (size_t)4*Mn*En*4;     // 16 MB
    float*          lut     = (float*)p;          p += (size_t)(LUT_N+8)*4;
    unsigned short* wqkvb   = (unsigned short*)p; p += (size_t)Ln*QKV_LD*En*2;// 6.3 MB
    unsigned short* wob     = (unsigned short*)p; p += (size_t)Ln*En*En*2;    // 2.1 MB
    unsigned short* w1b     = (unsigned short*)p; p += (size_t)Ln*FFn*En*2;   // 8.4 MB
    unsigned short* w2b     = (unsigned short*)p; p += (size_t)Ln*En*FFn*2;   // 8.4 MB

    // one-shot weight conversion (single launch, 4 ranges)
    {
        CvtArgs a;
        a.src[0] = Wqkv; a.dst[0] = wqkvb; a.n4[0] = Ln * QKV_LD * En / 4;
        a.src[1] = Wo;   a.dst[1] = wob;   a.n4[1] = Ln * En * En / 4;
        a.src[2] = W1;   a.dst[2] = w1b;   a.n4[2] = Ln * FFn * En / 4;
        a.src[3] = W2;   a.dst[3] = w2b;   a.n4[3] = Ln * En * FFn / 4;
        a.blkoff[0] = 0;
        for (int i = 0; i < 4; ++i)
            a.blkoff[i + 1] = a.blkoff[i] + (a.n4[i] + 255) / 256;
        k_cvt<<<a.blkoff[4], 256, 0, stream>>>(a);
    }

    // embed + LUT build (single launch)
    k_embed_lut<<<Mn * En / 256 + (LUT_N + 256) / 256, 256, 0, stream>>>(
        tok, emb, x, xb, dp_w1, dp_b1, dp_w2, lut);
    k_distbias_lut<<<Bn * Nn * Nn / 256, 256, 0, stream>>>(dist, tok, lut, dp_b2,
                                                           biasmat);

    const long long yps = (long long)Mn * En;
    for (int l = 0; l < Ln; ++l) {
        const unsigned short* Wqkv_l = wqkvb + (size_t)l * QKV_LD * En;
        const float*          bqkv_l = bqkv  + (size_t)l * QKV_LD;
        const unsigned short* Wo_l   = wob   + (size_t)l * En * En;
        const unsigned short* W1_l   = w1b   + (size_t)l * FFn * En;
        const float*          b1_l   = b1    + (size_t)l * FFn;
        const unsigned short* W2_l   = w2b   + (size_t)l * En * FFn;

        // QKV: [2048,512] x [1536,512]^T -> bf16 [2048,1536]
        k_gemm<64, 64, 64, 0, 1>
            <<<dim3(Mn / 64, QKV_LD / 64), 256, 0, stream>>>(
            xb, En, Wqkv_l, En, bqkv_l, qkvb, QKV_LD, 0, En);

        // fused attention (V^T staged in-kernel) -> attnb
        k_attn<<<dim3(Nn / 64, Bn * Hn), 256, 0, stream>>>(qkvb, biasmat, attnb);

        // O projection, split-K x2 -> fp32 partials
        k_gemm<64, 64, 64, 3, 0>
            <<<dim3(Mn / 64, En / 64, 2), 256, 0, stream>>>(
            attnb, En, Wo_l, En, nullptr, yp, En, yps, En / 2);
        k_addln<0><<<Mn, 256, 0, stream>>>(x, yp, yps, 2,
                                           bo + (size_t)l * En,
                                           ln1g + (size_t)l * En, ln1b + (size_t)l * En,
                                           x, xb, tok);

        // FF1 + GELU
        k_gemm<64, 64, 64, 1, 1>
            <<<dim3(Mn / 64, FFn / 64), 256, 0, stream>>>(
            xb, En, W1_l, En, b1_l, Sffb, FFn, 0, En);

        // FF2, split-K x4 -> fp32 partials
        k_gemm<64, 64, 64, 3, 0>
            <<<dim3(Mn / 64, En / 64, 4), 256, 0, stream>>>(
            Sffb, FFn, W2_l, FFn, nullptr, yp, En, yps, FFn / 4);

        if (l < Ln - 1) {
            k_addln<0><<<Mn, 256, 0, stream>>>(x, yp, yps, 4,
                                               b2 + (size_t)l * En,
                                               ln2g + (size_t)l * En, ln2b + (size_t)l * En,
                                               x, xb, tok);
        } else {
            // final layer: write LN output + pad mask straight to d_out
            k_addln<1><<<Mn, 256, 0, stream>>>(x, yp, yps, 4,
                                               b2 + (size_t)l * En,
                                               ln2g + (size_t)l * En, ln2b + (size_t)l * En,
                                               (float*)d_out, nullptr, tok);
        }
    }
}

// Round 15
// 278.087 us; speedup vs baseline: 9.0887x; 1.0577x over previous
//
#include <hip/hip_runtime.h>
#include <hip/hip_bf16.h>

// ---------------------------------------------------------------------------
// SimpleGeoFormerModel: 4-layer transformer encoder. FP32 out; bf16
// activations, weights, residual chain, and split-K partials; MFMA fp32 acc.
// B=8 N=256 E=512 V=512 L=4 H=8 FF=2048, dh=64.
// Round 15: glue-traffic trim — bf16 split-K partials, bf16 residual chain
// (fp32 x dropped), bf16 biasmat, vectorized addln. GEMM/attn math unchanged.
// ---------------------------------------------------------------------------

namespace {
constexpr int Bn  = 8;
constexpr int Nn  = 256;
constexpr int En  = 512;
constexpr int Ln  = 4;
constexpr int Hn  = 8;
constexpr int FFn = 2048;
constexpr int DHn = 64;
constexpr int Mn  = Bn * Nn;        // 2048 rows
constexpr int QKV_LD = 3 * En;      // 1536
constexpr int LUT_N = 4096;
}

typedef float f32x4 __attribute__((ext_vector_type(4)));
typedef short bf16x8 __attribute__((ext_vector_type(8)));

// fp32 -> bf16 round-to-nearest-even (finite inputs)
__device__ __forceinline__ unsigned short f2bs(float f) {
    union { float f; unsigned u; } v; v.f = f;
    unsigned r = v.u + 0x7FFFu + ((v.u >> 16) & 1u);
    return (unsigned short)(r >> 16);
}
__device__ __forceinline__ float bf2f(unsigned short s) {
    union { unsigned u; float f; } v;
    v.u = ((unsigned)s) << 16;
    return v.f;
}

// swizzled byte address within a row-major bf16 LDS tile (16B-unit XOR)
__device__ __forceinline__ int swz(int row, int byte_in_row, int stride_b) {
    return row * stride_b + (byte_in_row ^ ((row & 7) << 4));
}

// async global->LDS, 16B per lane; LDS dest = wave-uniform base + lane*16
__device__ __forceinline__ void gload_lds16(const void* g, void* l) {
    __builtin_amdgcn_global_load_lds(
        (const __attribute__((address_space(1))) unsigned int*)g,
        (__attribute__((address_space(3))) unsigned int*)l,
        16, 0, 0);
}

// ---------------- one-shot weight conversion (4 ranges, 1 launch) ----------
struct CvtArgs {
    const float* src[4];
    unsigned short* dst[4];
    int n4[4];
    int blkoff[5];
};
__global__ __launch_bounds__(256) void k_cvt(CvtArgs a) {
    int bid = blockIdx.x;
    int r = 0;
    if (bid >= a.blkoff[1]) r = 1;
    if (bid >= a.blkoff[2]) r = 2;
    if (bid >= a.blkoff[3]) r = 3;
    int i = (bid - a.blkoff[r]) * 256 + threadIdx.x;
    if (i >= a.n4[r]) return;
    f32x4 v = *(const f32x4*)(a.src[r] + (size_t)i * 4);
    unsigned short o[4] = {f2bs(v[0]), f2bs(v[1]), f2bs(v[2]), f2bs(v[3])};
    *(unsigned long long*)(a.dst[r] + (size_t)i * 4) = *(unsigned long long*)o;
}

// ---------------- embed (blocks 0..Mn*En/256) + LUT build (rest) -----------
__global__ __launch_bounds__(256) void k_embed_lut(const int* __restrict__ tok,
                                                   const float* __restrict__ emb,
                                                   unsigned short* __restrict__ xb,
                                                   const float* __restrict__ w1,
                                                   const float* __restrict__ b1,
                                                   const float* __restrict__ w2,
                                                   float* __restrict__ lut) {
    constexpr int EMB_BLOCKS = Mn * En / 256;
    if (blockIdx.x < EMB_BLOCKS) {
        int i = blockIdx.x * 256 + threadIdx.x;
        int m = i >> 9;
        int e = i & 511;
        xb[i] = f2bs(emb[tok[m] * En + e]);
        return;
    }
    __shared__ float sw1[En], sb1[En], sw2[En];
    for (int e = threadIdx.x; e < En; e += 256) {
        sw1[e] = w1[e]; sb1[e] = b1[e]; sw2[e] = w2[e];
    }
    __syncthreads();
    int i = (blockIdx.x - EMB_BLOCKS) * 256 + threadIdx.x;
    if (i > LUT_N) return;
    float d = (float)i * (10.0f / (float)LUT_N);
    float acc = 0.f;
#pragma unroll 4
    for (int e = 0; e < En; ++e) {
        float s = fmaf(d, sw1[e], sb1[e]);
        float t = 1.f - 2.f / (__expf(2.f * s) + 1.f);
        acc = fmaf(t, sw2[e], acc);
    }
    lut[i] = acc;
}

// ---------------- distance bias via LUT (bf16 out) ----------------
__global__ __launch_bounds__(256) void k_distbias_lut(const float* __restrict__ dist,
                                                      const int* __restrict__ tok,
                                                      const float* __restrict__ lut,
                                                      const float* __restrict__ b2,
                                                      unsigned short* __restrict__ biasmat) {
    int i = blockIdx.x * 256 + threadIdx.x;
    float d = dist[i];
    float idx = d * ((float)LUT_N / 10.0f);
    int ii = (int)idx;
    ii = ii < 0 ? 0 : (ii > LUT_N - 1 ? LUT_N - 1 : ii);
    float frac = idx - (float)ii;
    float v0 = lut[ii], v1 = lut[ii + 1];
    float acc = fmaf(v1 - v0, frac, v0) + b2[0];
    int k = i & (Nn - 1);
    int q = (i >> 8) & (Nn - 1);
    int b = i >> 16;
    bool pad = (tok[b * Nn + k] == 0) || (tok[b * Nn + q] == 0);
    biasmat[i] = f2bs(pad ? -1e30f : acc);
}

// ---------------- fused attention (bias preload now bf16) ------------------
__global__ __launch_bounds__(256, 1) void k_attn(
        const unsigned short* __restrict__ qkvb,
        const unsigned short* __restrict__ biasmat,
        unsigned short* __restrict__ attnb) {
    __shared__ short Qs[64 * 64];
    __shared__ short Ks[256 * 64];
    __shared__ short Vs[64 * 256];
    __shared__ short Ps[64 * 256];

    const int tid = threadIdx.x;
    const int lane = tid & 63;
    const int wv = tid >> 6;
    const int q0 = blockIdx.x * 64;
    const int bh = blockIdx.y;
    const int b = bh >> 3, h = bh & 7;

    const unsigned short* Qg = qkvb + ((size_t)(b * Nn + q0)) * QKV_LD + h * DHn;
    const unsigned short* Kg = qkvb + ((size_t)(b * Nn)) * QKV_LD + En + h * DHn;
    const unsigned short* VgR = qkvb + ((size_t)(b * Nn)) * QKV_LD + 2 * En + h * DHn;

    {
        const char* src = (const char*)(Kg + (size_t)tid * QKV_LD);
#pragma unroll
        for (int c = 0; c < 8; ++c)
            *(bf16x8*)((char*)Ks + swz(tid, c * 16, 128)) =
                *(const bf16x8*)(src + c * 16);
    }
    {
        const char* src = (const char*)(VgR + (size_t)tid * QKV_LD);
#pragma unroll
        for (int c = 0; c < 8; ++c) {
            bf16x8 v = *(const bf16x8*)(src + c * 16);
#pragma unroll
            for (int j = 0; j < 8; ++j) {
                int d = c * 8 + j;
                *(short*)((char*)Vs + (d * 512 + ((tid * 2) ^ ((d & 7) << 4)))) = v[j];
            }
        }
    }
    {
        int r = tid & 63;
        const char* src = (const char*)(Qg + (size_t)r * QKV_LD);
#pragma unroll
        for (int i = 0; i < 2; ++i) {
            int cb = ((tid >> 6) * 2 + i) * 16;
            bf16x8 v = *(const bf16x8*)(src + cb);
            bf16x8 o;
#pragma unroll
            for (int j = 0; j < 8; ++j) o[j] = (short)f2bs(bf2f((unsigned short)v[j]) * 0.125f);
            *(bf16x8*)((char*)Qs + swz(r, cb, 128)) = o;
        }
    }

    const int qw = wv * 16;
    const int g  = lane >> 4;
    const int c  = lane & 15;
    f32x4 acc[16];
    {
        const unsigned short* bb = biasmat + ((size_t)b * Nn + (q0 + qw + g * 4)) * Nn;
#pragma unroll
        for (int f = 0; f < 16; ++f)
#pragma unroll
            for (int r = 0; r < 4; ++r)
                acc[f][r] = bf2f(bb[(size_t)r * Nn + f * 16 + c]);
    }

    __syncthreads();

    bf16x8 qa[2];
#pragma unroll
    for (int ks = 0; ks < 2; ++ks)
        qa[ks] = *(const bf16x8*)((const char*)Qs + swz(qw + c, ks * 64 + g * 16, 128));
#pragma unroll
    for (int f = 0; f < 16; ++f) {
#pragma unroll
        for (int ks = 0; ks < 2; ++ks) {
            bf16x8 kb = *(const bf16x8*)((const char*)Ks +
                         swz(f * 16 + c, ks * 64 + g * 16, 128));
            acc[f] = __builtin_amdgcn_mfma_f32_16x16x32_bf16(qa[ks], kb, acc[f], 0, 0, 0);
        }
    }

    float rcp[4];
#pragma unroll
    for (int r = 0; r < 4; ++r) {
        float m = acc[0][r];
#pragma unroll
        for (int f = 1; f < 16; ++f) m = fmaxf(m, acc[f][r]);
#pragma unroll
        for (int o = 1; o < 16; o <<= 1) m = fmaxf(m, __shfl_xor(m, o));
        float s = 0.f;
#pragma unroll
        for (int f = 0; f < 16; ++f) {
            float e = __expf(acc[f][r] - m);
            acc[f][r] = e;
            s += e;
        }
#pragma unroll
        for (int o = 1; o < 16; o <<= 1) s += __shfl_xor(s, o);
        rcp[r] = 1.f / s;
    }

#pragma unroll
    for (int f = 0; f < 16; ++f)
#pragma unroll
        for (int r = 0; r < 4; ++r) {
            int q = qw + g * 4 + r;
            int kx = f * 16 + c;
            *(unsigned short*)((char*)Ps + (q * 512 + ((kx * 2) ^ ((q & 7) << 4)))) =
                f2bs(acc[f][r] * rcp[r]);
        }

    f32x4 acc2[4];
#pragma unroll
    for (int fd = 0; fd < 4; ++fd) acc2[fd] = {0.f, 0.f, 0.f, 0.f};
#pragma unroll
    for (int ks2 = 0; ks2 < 8; ++ks2) {
        bf16x8 pa = *(const bf16x8*)((const char*)Ps +
                      swz(qw + c, ks2 * 64 + g * 16, 512));
#pragma unroll
        for (int fd = 0; fd < 4; ++fd) {
            bf16x8 vb = *(const bf16x8*)((const char*)Vs +
                          swz(fd * 16 + c, ks2 * 64 + g * 16, 512));
            acc2[fd] = __builtin_amdgcn_mfma_f32_16x16x32_bf16(pa, vb, acc2[fd], 0, 0, 0);
        }
    }

    unsigned short* Cg = attnb + ((size_t)(b * Nn + q0 + qw)) * En + h * DHn;
#pragma unroll
    for (int fd = 0; fd < 4; ++fd)
#pragma unroll
        for (int r = 0; r < 4; ++r)
            Cg[(size_t)(g * 4 + r) * En + fd * 16 + c] = f2bs(acc2[fd][r]);
}

// ---------------- MFMA GEMM: 2-phase dbuf global_load_lds pipeline ---------
// C = A*B^T (+epilogue). MODE 0: +bias[n]; 1: gelu(+bias[n]); 3: raw bf16
// partial (split-K via blockIdx.z, stride sCz elements). Output always bf16
// except FINAL fp32 not used here. 64x64 tile, BK=64.
template <int BM, int BN, int BK, int MODE>
__global__ __launch_bounds__(256) void k_gemm(
        const unsigned short* __restrict__ A, int lda,
        const unsigned short* __restrict__ Bw, int ldb,
        const float* __restrict__ bias,
        unsigned short* __restrict__ Cp, int ldc, long long sCz,
        int K) {
    static_assert(BM == 64 && BN == 64 && BK == 64, "fixed geometry");
    __shared__ short As[2][64 * 64];
    __shared__ short Bs[2][64 * 64];

    const int tid  = threadIdx.x;
    const int lane = tid & 63;
    const int wv   = tid >> 6;
    const int wr   = wv >> 1, wc = wv & 1;
    const int m0 = blockIdx.x * BM, n0 = blockIdx.y * BN;
    const int z  = blockIdx.z;

    const int r_in = lane >> 3;
    const int ch   = lane & 7;
    const size_t koff2 = (size_t)z * K * 2;

    auto stage = [&](int t, int d) {
        const size_t cb = koff2 + (size_t)t * BK * 2;
#pragma unroll
        for (int q = 0; q < 2; ++q) {
            const int rb = q * 32 + wv * 8;
            const char* ga = (const char*)A +
                (size_t)(m0 + rb + r_in) * lda * 2 + cb + ((ch ^ r_in) << 4);
            gload_lds16(ga, &As[d][rb * 64]);
        }
#pragma unroll
        for (int q = 0; q < 2; ++q) {
            const int rb = q * 32 + wv * 8;
            const char* gb = (const char*)Bw +
                (size_t)(n0 + rb + r_in) * ldb * 2 + cb + ((ch ^ r_in) << 4);
            gload_lds16(gb, &Bs[d][rb * 64]);
        }
    };

    f32x4 acc[2][2];
#pragma unroll
    for (int i = 0; i < 2; ++i)
#pragma unroll
        for (int j = 0; j < 2; ++j) acc[i][j] = {0.f, 0.f, 0.f, 0.f};

    const int fkb  = (lane >> 4) * 16;
    const int frow = lane & 15;

    stage(0, 0);
    __syncthreads();

    int cur = 0;
    const int nt = K / BK;
    for (int t = 0; t < nt; ++t) {
        if (t + 1 < nt) stage(t + 1, cur ^ 1);
#pragma unroll
        for (int ks = 0; ks < 2; ++ks) {
            bf16x8 af[2], bfr[2];
#pragma unroll
            for (int i = 0; i < 2; ++i)
                af[i] = *(const bf16x8*)((const char*)As[cur] +
                         swz(wr * 32 + i * 16 + frow, ks * 64 + fkb, 128));
#pragma unroll
            for (int j = 0; j < 2; ++j)
                bfr[j] = *(const bf16x8*)((const char*)Bs[cur] +
                          swz(wc * 32 + j * 16 + frow, ks * 64 + fkb, 128));
#pragma unroll
            for (int i = 0; i < 2; ++i)
#pragma unroll
                for (int j = 0; j < 2; ++j)
                    acc[i][j] = __builtin_amdgcn_mfma_f32_16x16x32_bf16(
                        af[i], bfr[j], acc[i][j], 0, 0, 0);
        }
        __syncthreads();
        cur ^= 1;
    }

#pragma unroll
    for (int i = 0; i < 2; ++i) {
#pragma unroll
        for (int j = 0; j < 2; ++j) {
            const int n = n0 + wc * 32 + j * 16 + (lane & 15);
            float bv = 0.f;
            if constexpr (MODE == 0 || MODE == 1) bv = bias[n];
#pragma unroll
            for (int r = 0; r < 4; ++r) {
                const int m = m0 + wr * 32 + i * 16 + (lane >> 4) * 4 + r;
                float v = acc[i][j][r] + bv;
                if constexpr (MODE == 1)
                    v = 0.5f * v * (1.f + erff(v * 0.70710678118654752f));
                Cp[(size_t)z * sCz + (size_t)m * ldc + n] = f2bs(v);
            }
        }
    }
}

// ---------------- residual(bf16) + split-K bf16 partials + bias + LN -------
// FINAL: writes fp32 d_out (+pad mask); else writes bf16 xb (in-place OK).
template <int FINAL>
__global__ __launch_bounds__(256) void k_addln(
        const unsigned short* __restrict__ xin_b,
        const unsigned short* __restrict__ yp, long long ystride, int nsplit,
        const float* __restrict__ biasv,
        const float* __restrict__ g, const float* __restrict__ bb,
        unsigned short* __restrict__ xout_b, float* __restrict__ dout,
        const int* __restrict__ tok) {
    const int row = blockIdx.x;
    const int tid = threadIdx.x;
    const size_t base = (size_t)row * En;
    const int i0 = 2 * tid;

    unsigned xv = *(const unsigned*)(xin_b + base + i0);
    float2 bv = *(const float2*)(biasv + i0);
    float v0 = bf2f((unsigned short)(xv & 0xFFFFu)) + bv.x;
    float v1 = bf2f((unsigned short)(xv >> 16)) + bv.y;
    for (int s = 0; s < nsplit; ++s) {
        unsigned pv = *(const unsigned*)(yp + (size_t)s * ystride + base + i0);
        v0 += bf2f((unsigned short)(pv & 0xFFFFu));
        v1 += bf2f((unsigned short)(pv >> 16));
    }
    float s1 = v0 + v1;
    float s2 = v0 * v0 + v1 * v1;
#pragma unroll
    for (int o = 32; o; o >>= 1) {
        s1 += __shfl_xor(s1, o);
        s2 += __shfl_xor(s2, o);
    }
    __shared__ float ws1[4], ws2[4];
    int w = tid >> 6;
    if ((tid & 63) == 0) { ws1[w] = s1; ws2[w] = s2; }
    __syncthreads();
    s1 = (ws1[0] + ws1[1]) + (ws1[2] + ws1[3]);
    s2 = (ws2[0] + ws2[1]) + (ws2[2] + ws2[3]);
    const float rE = 1.f / (float)En;
    float mean = s1 * rE;
    float var = s2 * rE - mean * mean;
    float inv = rsqrtf(var + 1e-5f);
    float2 gv = *(const float2*)(g + i0);
    float2 bbv = *(const float2*)(bb + i0);
    float o0 = (v0 - mean) * inv * gv.x + bbv.x;
    float o1 = (v1 - mean) * inv * gv.y + bbv.y;
    if constexpr (FINAL) {
        *(float2*)(dout + base + i0) = make_float2(o0, o1);
        if (tid == 0)
            dout[(size_t)Mn * En + row] = (tok[row] == 0) ? 1.f : 0.f;
    } else {
        unsigned ov = (unsigned)f2bs(o0) | ((unsigned)f2bs(o1) << 16);
        *(unsigned*)(xout_b + base + i0) = ov;
    }
}

// ---------------------------------------------------------------------------
extern "C" void kernel_launch(void* const* d_in, const int* in_sizes, int n_in,
                              void* d_out, int out_size, void* d_ws, size_t ws_size,
                              hipStream_t stream) {
    const int*   tok   = (const int*)  d_in[0];
    const float* dist  = (const float*)d_in[2];
    const float* emb   = (const float*)d_in[4];
    const float* dp_w1 = (const float*)d_in[5];
    const float* dp_b1 = (const float*)d_in[6];
    const float* dp_w2 = (const float*)d_in[7];
    const float* dp_b2 = (const float*)d_in[8];
    const float* Wqkv  = (const float*)d_in[9];
    const float* bqkv  = (const float*)d_in[10];
    const float* Wo    = (const float*)d_in[11];
    const float* bo    = (const float*)d_in[12];
    const float* ln1g  = (const float*)d_in[13];
    const float* ln1b  = (const float*)d_in[14];
    const float* W1    = (const float*)d_in[15];
    const float* b1    = (const float*)d_in[16];
    const float* W2    = (const float*)d_in[17];
    const float* b2    = (const float*)d_in[18];
    const float* ln2g  = (const float*)d_in[19];
    const float* ln2b  = (const float*)d_in[20];

    char* p = (char*)d_ws;
    unsigned short* biasmat = (unsigned short*)p; p += (size_t)Bn*Nn*Nn*2;   // 1 MB
    unsigned short* xb      = (unsigned short*)p; p += (size_t)Mn*En*2;      // 2 MB
    unsigned short* qkvb    = (unsigned short*)p; p += (size_t)Mn*QKV_LD*2;  // 6 MB
    unsigned short* Sffb    = (unsigned short*)p; p += (size_t)Mn*FFn*2;     // 8 MB
    unsigned short* attnb   = (unsigned short*)p; p += (size_t)Mn*En*2;      // 2 MB
    unsigned short* yp      = (unsigned short*)p; p += (size_t)4*Mn*En*2;    // 8 MB
    float*          lut     = (float*)p;          p += (size_t)(LUT_N+8)*4;
    unsigned short* wqkvb   = (unsigned short*)p; p += (size_t)Ln*QKV_LD*En*2;
    unsigned short* wob     = (unsigned short*)p; p += (size_t)Ln*En*En*2;
    unsigned short* w1b     = (unsigned short*)p; p += (size_t)Ln*FFn*En*2;
    unsigned short* w2b     = (unsigned short*)p; p += (size_t)Ln*En*FFn*2;

    // one-shot weight conversion (single launch, 4 ranges)
    {
        CvtArgs a;
        a.src[0] = Wqkv; a.dst[0] = wqkvb; a.n4[0] = Ln * QKV_LD * En / 4;
        a.src[1] = Wo;   a.dst[1] = wob;   a.n4[1] = Ln * En * En / 4;
        a.src[2] = W1;   a.dst[2] = w1b;   a.n4[2] = Ln * FFn * En / 4;
        a.src[3] = W2;   a.dst[3] = w2b;   a.n4[3] = Ln * En * FFn / 4;
        a.blkoff[0] = 0;
        for (int i = 0; i < 4; ++i)
            a.blkoff[i + 1] = a.blkoff[i] + (a.n4[i] + 255) / 256;
        k_cvt<<<a.blkoff[4], 256, 0, stream>>>(a);
    }

    // embed + LUT build (single launch)
    k_embed_lut<<<Mn * En / 256 + (LUT_N + 256) / 256, 256, 0, stream>>>(
        tok, emb, xb, dp_w1, dp_b1, dp_w2, lut);
    k_distbias_lut<<<Bn * Nn * Nn / 256, 256, 0, stream>>>(dist, tok, lut, dp_b2,
                                                           biasmat);

    const long long yps = (long long)Mn * En;
    for (int l = 0; l < Ln; ++l) {
        const unsigned short* Wqkv_l = wqkvb + (size_t)l * QKV_LD * En;
        const float*          bqkv_l = bqkv  + (size_t)l * QKV_LD;
        const unsigned short* Wo_l   = wob   + (size_t)l * En * En;
        const unsigned short* W1_l   = w1b   + (size_t)l * FFn * En;
        const float*          b1_l   = b1    + (size_t)l * FFn;
        const unsigned short* W2_l   = w2b   + (size_t)l * En * FFn;

        // QKV: [2048,512] x [1536,512]^T -> bf16 [2048,1536]
        k_gemm<64, 64, 64, 0>
            <<<dim3(Mn / 64, QKV_LD / 64), 256, 0, stream>>>(
            xb, En, Wqkv_l, En, bqkv_l, qkvb, QKV_LD, 0, En);

        // fused attention -> attnb
        k_attn<<<dim3(Nn / 64, Bn * Hn), 256, 0, stream>>>(qkvb, biasmat, attnb);

        // O projection, split-K x2 -> bf16 partials
        k_gemm<64, 64, 64, 3>
            <<<dim3(Mn / 64, En / 64, 2), 256, 0, stream>>>(
            attnb, En, Wo_l, En, nullptr, yp, En, yps, En / 2);
        k_addln<0><<<Mn, 256, 0, stream>>>(xb, yp, yps, 2,
                                           bo + (size_t)l * En,
                                           ln1g + (size_t)l * En, ln1b + (size_t)l * En,
                                           xb, nullptr, tok);

        // FF1 + GELU
        k_gemm<64, 64, 64, 1>
            <<<dim3(Mn / 64, FFn / 64), 256, 0, stream>>>(
            xb, En, W1_l, En, b1_l, Sffb, FFn, 0, En);

        // FF2, split-K x4 -> bf16 partials
        k_gemm<64, 64, 64, 3>
            <<<dim3(Mn / 64, En / 64, 4), 256, 0, stream>>>(
            Sffb, FFn, W2_l, FFn, nullptr, yp, En, yps, FFn / 4);

        if (l < Ln - 1) {
            k_addln<0><<<Mn, 256, 0, stream>>>(xb, yp, yps, 4,
                                               b2 + (size_t)l * En,
                                               ln2g + (size_t)l * En, ln2b + (size_t)l * En,
                                               xb, nullptr, tok);
        } else {
            // final layer: LN output (fp32) + pad mask straight to d_out
            k_addln<1><<<Mn, 256, 0, stream>>>(xb, yp, yps, 4,
                                               b2 + (size_t)l * En,
                                               ln2g + (size_t)l * En, ln2b + (size_t)l * En,
                                               nullptr, (float*)d_out, tok);
        }
    }
}